// Round 2
// baseline (17308.144 us; speedup 1.0000x reference)
//
#include <hip/hip_runtime.h>
#include <hip/hip_bf16.h>
#include <math.h>
#include <stdint.h>

#define FRAME 960
#define NFFT  3840
#define NWIN  1024
#define NFREQ 1921
#define NB    8
#define LF    200
#define LW    192000
#define LPADW 195840
#define CIN   450
#define CI    512
#define HID   1536
#define NL    6
#define NCH   188   // ceil(192000/1024)

// ---------------- threefry (JAX partitionable variant) ----------------
__device__ __forceinline__ uint32_t rotl32(uint32_t v, int r) { return (v << r) | (v >> (32 - r)); }

__device__ __forceinline__ void threefry2x32(uint32_t k0, uint32_t k1, uint32_t& x0, uint32_t& x1) {
  uint32_t ks2 = k0 ^ k1 ^ 0x1BD11BDAu;
  x0 += k0; x1 += k1;
#define TFR(r) { x0 += x1; x1 = rotl32(x1, r); x1 ^= x0; }
  TFR(13) TFR(15) TFR(26) TFR(6)  x0 += k1;  x1 += ks2 + 1u;
  TFR(17) TFR(29) TFR(16) TFR(24) x0 += ks2; x1 += k0 + 2u;
  TFR(13) TFR(15) TFR(26) TFR(6)  x0 += k0;  x1 += k1 + 3u;
  TFR(17) TFR(29) TFR(16) TFR(24) x0 += k1;  x1 += ks2 + 4u;
  TFR(13) TFR(15) TFR(26) TFR(6)  x0 += ks2; x1 += k0 + 5u;
#undef TFR
}

__device__ __forceinline__ float winf(int j) {
  return 0.5f - 0.5f * cosf((6.283185307179586f * (float)j) / 3840.0f);
}
// bank swizzle for twiddle tables (bijective within each 32-run)
__device__ __forceinline__ int swz(int m) { return (m & ~31) | ((m ^ (m >> 5)) & 31); }

// ---------------- xin ----------------
__global__ void build_xin(const float* __restrict__ content, const float* __restrict__ f0,
                          const float* __restrict__ energy, const float* __restrict__ spk,
                          float* __restrict__ xin) {
  int idx = blockIdx.x * 256 + threadIdx.x;
  if (idx >= NB * CIN * LF) return;
  int b = idx / (CIN * LF);
  int r = idx % (CIN * LF);
  int c = r / LF, l = r % LF;
  float v;
  if (c < 192)       v = content[((size_t)b * 192 + c) * LF + l];
  else if (c < 448)  v = spk[b * 256 + (c - 192)];
  else if (c == 448) v = logf(fmaxf(f0[b * LF + l], 0.0f) + 1e-6f);
  else               v = energy[b * LF + l];
  xin[idx] = v;
}

// ---------------- generic tiled GEMM: out[b,o,l] = act(sum_c W[o,c]*X[b,c,l] + bias[o]) (+res) ----------------
__global__ __launch_bounds__(256) void gemm_act(
    const float* __restrict__ W, const float* __restrict__ X,
    const float* __restrict__ bias, const float* __restrict__ res,
    float* __restrict__ out, int O, int K, int L, int act,
    long long oSB, long long oSO, long long oSL)
{
  __shared__ float Ws[64][16];
  __shared__ float Xs[16][64];
  int b  = blockIdx.z;
  int o0 = blockIdx.y * 64;
  int l0 = blockIdx.x * 64;
  int tid = threadIdx.x;
  int tx = tid & 15, ty = tid >> 4;
  const float* Xb = X + (long long)b * K * L;
  float acc[4][4] = {{0.f}};
  for (int k0 = 0; k0 < K; k0 += 16) {
    for (int i = tid; i < 64 * 16; i += 256) {
      int oo = i >> 4, kk = i & 15;
      int o = o0 + oo, k = k0 + kk;
      Ws[oo][kk] = (o < O && k < K) ? W[(long long)o * K + k] : 0.f;
    }
    for (int i = tid; i < 16 * 64; i += 256) {
      int kk = i >> 6, ll = i & 63;
      int k = k0 + kk, l = l0 + ll;
      Xs[kk][ll] = (k < K && l < L) ? Xb[(long long)k * L + l] : 0.f;
    }
    __syncthreads();
#pragma unroll
    for (int kk = 0; kk < 16; ++kk) {
      float a[4], bb[4];
#pragma unroll
      for (int i = 0; i < 4; ++i) a[i] = Ws[ty + 16 * i][kk];
#pragma unroll
      for (int j = 0; j < 4; ++j) bb[j] = Xs[kk][tx + 16 * j];
#pragma unroll
      for (int i = 0; i < 4; ++i)
#pragma unroll
        for (int j = 0; j < 4; ++j)
          acc[i][j] = fmaf(a[i], bb[j], acc[i][j]);
    }
    __syncthreads();
  }
  for (int i = 0; i < 4; ++i) {
    int o = o0 + ty + 16 * i;
    if (o >= O) continue;
    float bv = bias ? bias[o] : 0.f;
    for (int j = 0; j < 4; ++j) {
      int l = l0 + tx + 16 * j;
      if (l >= L) continue;
      float v = acc[i][j] + bv;
      if (act == 1)      v = 0.5f * v * (1.0f + erff(v * 0.7071067811865475f));  // exact gelu
      else if (act == 2) v = (v > 0.f ? v : expm1f(v)) + 1.0f;                   // elu + 1
      if (res) v += res[((long long)b * O + o) * L + l];
      out[(long long)b * oSB + (long long)o * oSO + (long long)l * oSL] = v;
    }
  }
}

// ---------------- channel LayerNorm (in-place) on (B,CI,LF) ----------------
__global__ __launch_bounds__(256) void ln_kernel(float* __restrict__ x, const float* __restrict__ g,
                                                 const float* __restrict__ bta) {
  int b = blockIdx.y;
  int lx = threadIdx.x & 63;
  int cy = threadIdx.x >> 6;
  int l = blockIdx.x * 64 + lx;
  bool valid = l < LF;
  float* xb = x + (size_t)b * CI * LF;
  __shared__ float red[4][64];
  float s = 0.f;
  if (valid) for (int c = cy; c < CI; c += 4) s += xb[c * LF + l];
  red[cy][lx] = s;
  __syncthreads();
  float mean = (red[0][lx] + red[1][lx] + red[2][lx] + red[3][lx]) * (1.0f / CI);
  __syncthreads();
  float s2 = 0.f;
  if (valid) for (int c = cy; c < CI; c += 4) { float d = xb[c * LF + l] - mean; s2 += d * d; }
  red[cy][lx] = s2;
  __syncthreads();
  float var = (red[0][lx] + red[1][lx] + red[2][lx] + red[3][lx]) * (1.0f / CI);
  float rs = rsqrtf(var + 1e-5f);
  if (valid) for (int c = cy; c < CI; c += 4)
    xb[c * LF + l] = (xb[c * LF + l] - mean) * rs * g[c] + bta[c];
}

// ---------------- depthwise conv K=7, zero pad same ----------------
__global__ void dwconv_kernel(const float* __restrict__ x, const float* __restrict__ w,
                              const float* __restrict__ bias, float* __restrict__ out) {
  int idx = blockIdx.x * 256 + threadIdx.x;
  if (idx >= NB * CI * LF) return;
  int b = idx / (CI * LF);
  int r = idx % (CI * LF);
  int c = r / LF, l = r % LF;
  float acc = bias[c];
#pragma unroll
  for (int tau = 0; tau < 7; ++tau) {
    int j = l + tau - 3;
    if (j >= 0 && j < LF) acc = fmaf(x[((size_t)b * CI + c) * LF + j], w[c * 7 + tau], acc);
  }
  out[idx] = acc;
}

// ---------------- amps head: elu(w.x+b)+1, O=1 ----------------
__global__ __launch_bounds__(256) void amps_kernel(const float* __restrict__ x, const float* __restrict__ w,
                                                   const float* __restrict__ bias, float* __restrict__ amps) {
  int b = blockIdx.x;
  __shared__ float ws[CI];
  for (int i = threadIdx.x; i < CI; i += 256) ws[i] = w[i];
  __syncthreads();
  int l = threadIdx.x;
  if (l < LF) {
    float acc = bias[0];
    for (int c = 0; c < CI; ++c) acc = fmaf(ws[c], x[((size_t)b * CI + c) * LF + l], acc);
    amps[b * LF + l] = (acc > 0.f ? acc : expm1f(acc)) + 1.0f;
  }
}

// ---------------- im2col for f_out conv (edge pad 3) ----------------
__global__ void im2col_kernel(const float* __restrict__ x, float* __restrict__ im) {
  int idx = blockIdx.x * 256 + threadIdx.x;
  if (idx >= NB * 3584 * LF) return;
  int b = idx / (3584 * LF);
  int r = idx % (3584 * LF);
  int k = r / LF, l = r % LF;
  int c = k / 7, tau = k % 7;
  int j = l + tau - 3;
  j = j < 0 ? 0 : (j > LF - 1 ? LF - 1 : j);
  im[idx] = x[((size_t)b * CI + c) * LF + j];
}

// ---------------- f0 linear interp to LW ----------------
__global__ void fs_kernel(const float* __restrict__ f0, float* __restrict__ fs) {
  int idx = blockIdx.x * 256 + threadIdx.x;
  if (idx >= NB * LW) return;
  int b = idx / LW, n = idx % LW;
  float pos = ((float)n + 0.5f) * (200.0f / 192000.0f) - 0.5f;
  pos = fminf(fmaxf(pos, 0.0f), 199.0f);
  int i0 = (int)pos;
  int i1 = min(i0 + 1, 199);
  float w = pos - (float)i0;
  fs[idx] = f0[b * LF + i0] * (1.0f - w) + f0[b * LF + i1] * w;
}

// ---------------- cumsum phase 1: per-chunk f64 sums ----------------
__global__ __launch_bounds__(256) void cumsum1(const float* __restrict__ fs, double* __restrict__ csum) {
  int b = blockIdx.y, ch = blockIdx.x;
  const float* fsb = fs + (size_t)b * LW;
  int base = ch * 1024;
  double s = 0.0;
  for (int q = 0; q < 4; ++q) {
    int n = base + threadIdx.x * 4 + q;
    if (n < LW) {
      float sm = (3.14159274101257324f * fsb[n]) / 48000.0f;
      s += (double)sm;
    }
  }
  __shared__ double sh[256];
  sh[threadIdx.x] = s;
  __syncthreads();
  for (int o2 = 128; o2 > 0; o2 >>= 1) {
    if (threadIdx.x < o2) sh[threadIdx.x] += sh[threadIdx.x + o2];
    __syncthreads();
  }
  if (threadIdx.x == 0) csum[b * NCH + ch] = sh[0];
}

// ---------------- cumsum phase 2: exclusive scan of chunk sums ----------------
__global__ void cumsum2(double* __restrict__ csum) {
  int b = blockIdx.x;
  if (threadIdx.x == 0) {
    double acc = 0.0;
    for (int ch = 0; ch < NCH; ++ch) {
      double v = csum[b * NCH + ch];
      csum[b * NCH + ch] = acc;
      acc += v;
    }
  }
}

// ---------------- harmonic source ----------------
__global__ __launch_bounds__(256) void harm_kernel(
    const float* __restrict__ fs, const double* __restrict__ csum,
    const float* __restrict__ f0, const float* __restrict__ amps,
    float* __restrict__ harm) {
  int b = blockIdx.y, ch = blockIdx.x;
  const float* fsb = fs + (size_t)b * LW;
  int base = ch * 1024;
  int tid = threadIdx.x;
  double p[4]; double s = 0.0;
  int n0 = base + tid * 4;
  for (int q = 0; q < 4; ++q) {
    int n = n0 + q; float sm = 0.f;
    if (n < LW) sm = (3.14159274101257324f * fsb[n]) / 48000.0f;
    s += (double)sm; p[q] = s;
  }
  __shared__ double sh[256];
  sh[tid] = s; __syncthreads();
  for (int o2 = 1; o2 < 256; o2 <<= 1) {
    double v = (tid >= o2) ? sh[tid - o2] : 0.0;
    __syncthreads();
    sh[tid] += v;
    __syncthreads();
  }
  double excl = csum[b * NCH + ch] + (tid > 0 ? sh[tid - 1] : 0.0);
  const double PID = (double)3.14159274101257324f;
  for (int q = 0; q < 4; ++q) {
    int n = n0 + q; if (n >= LW) break;
    double S = excl + p[q];
    float pixf = (float)fmod(S, PID);
    float fsv = fsb[n];
    float a = rintf(48000.0f / fmaxf(fsv, 20.0f) * 0.5f) * 2.0f + 1.0f;
    float D = (pixf < 1e-8f) ? 1.0f : (sinf(a * pixf) / (a * sinf(pixf)));
    int ui = n / 960;
    float uv = (f0[b * LF + ui] > 20.0f) ? 1.0f : 0.0f;
    float posA = ((float)n + 0.5f) * (200.0f / 192000.0f) - 0.5f;
    posA = fminf(fmaxf(posA, 0.0f), 199.0f);
    int i0 = (int)posA;
    int i1 = min(i0 + 1, 199);
    float w = posA - (float)i0;
    float ampI = amps[b * LF + i0] * (1.0f - w) + amps[b * LF + i1] * w;
    harm[(size_t)b * LW + n] = (D * uv) * ampI;
  }
}

// ---------------- noise, reflect-padded ----------------
__global__ void xp_kernel(float* __restrict__ xp) {
  int idx = blockIdx.x * 256 + threadIdx.x;
  if (idx >= NB * LPADW) return;
  int b = idx / LPADW, j = idx % LPADW;
  int m = j - 1920;
  if (m < 0) m = -m;
  if (m >= LW) m = 2 * LW - 2 - m;
  uint32_t i = (uint32_t)(b * LW + m);
  uint32_t x0 = 0u, x1 = i;
  threefry2x32(0u, 123u, x0, x1);
  uint32_t bits = x0 ^ x1;  // jax partitionable 32-bit combine
  xp[idx] = __uint_as_float((bits >> 9) | 0x3f800000u) - 1.0f;
}

// ---------------- forward DFT of windowed frames × kernels ----------------
__global__ __launch_bounds__(256) void dft_fwd(const float* __restrict__ xp,
                                               const float* __restrict__ ker,
                                               float* __restrict__ spec) {
  int tt = blockIdx.x;   // frame tt+1 (frame 0 dropped by reference)
  int b  = blockIdx.y;
  __shared__ float s[NFFT];
  __shared__ float twc[NFFT];
  __shared__ float tws[NFFT];
  const float* xb = xp + (size_t)b * LPADW + (size_t)(tt + 1) * FRAME;
  for (int j = threadIdx.x; j < NFFT; j += 256) {
    s[j] = xb[j] * winf(j);
    double ang = 6.283185307179586476925286766559 * (double)j / (double)NFFT;
    int sj = swz(j);
    twc[sj] = (float)cos(ang);
    tws[sj] = (float)sin(ang);
  }
  __syncthreads();
  for (int k = threadIdx.x; k < NFREQ; k += 256) {
    float re = 0.f, im = 0.f;
    int idx = 0;
    for (int j = 0; j < NFFT; ++j) {
      float v = s[j];
      int si = swz(idx);
      re = fmaf(v, twc[si], re);
      im = fmaf(-v, tws[si], im);
      idx += k; if (idx >= NFFT) idx -= NFFT;
    }
    float kv = ker[((size_t)b * NFREQ + k) * LF + tt];
    size_t o = (((size_t)b * LF + tt) * NFREQ + k) * 2;
    spec[o]     = re * kv;
    spec[o + 1] = im * kv;
  }
}

// ---------------- inverse rDFT × window ----------------
__global__ __launch_bounds__(256) void dft_inv(const float* __restrict__ spec,
                                               float* __restrict__ ft) {
  int tt = blockIdx.x;
  int b  = blockIdx.y;
  __shared__ float Xre[NFREQ], Xim[NFREQ];
  __shared__ float twc[NFFT], tws[NFFT];
  for (int j = threadIdx.x; j < NFFT; j += 256) {
    double ang = 6.283185307179586476925286766559 * (double)j / (double)NFFT;
    int sj = swz(j);
    twc[sj] = (float)cos(ang);
    tws[sj] = (float)sin(ang);
  }
  for (int k = threadIdx.x; k < NFREQ; k += 256) {
    size_t o = (((size_t)b * LF + tt) * NFREQ + k) * 2;
    float mult = (k == 0 || k == NFFT / 2) ? (1.0f / NFFT) : (2.0f / NFFT);
    Xre[k] = spec[o] * mult;
    Xim[k] = spec[o + 1] * mult;
  }
  __syncthreads();
  for (int j = threadIdx.x; j < NFFT; j += 256) {
    float acc = 0.f;
    int idx = 0;
    for (int k = 0; k < NFREQ; ++k) {
      int si = swz(idx);
      acc = fmaf(Xre[k], twc[si], acc);
      acc = fmaf(-Xim[k], tws[si], acc);
      idx += j; if (idx >= NFFT) idx -= NFFT;
    }
    ft[((size_t)b * LF + tt) * NFFT + j] = acc * winf(j);
  }
}

// ---------------- OLA + wn normalize + add harm (in place -> dsp) ----------------
__global__ void ola_kernel(const float* __restrict__ ft, float* __restrict__ dsp) {
  int idx = blockIdx.x * 256 + threadIdx.x;
  if (idx >= NB * LW) return;
  int b = idx / LW, n = idx % LW;
  int p = n + 1920;
  int t0 = (p > 3839) ? ((p - 2880) / 960) : 0;   // ceil((p-3839)/960)
  int t1 = p / FRAME; if (t1 > 200) t1 = 200;
  float y = 0.f, wn = 0.f;
  for (int t = t0; t <= t1; ++t) {
    int j = p - FRAME * t;
    float w = winf(j);
    wn += w * w;
    if (t >= 1) y += ft[((size_t)b * LF + (t - 1)) * NFFT + j];
  }
  float den = wn > 1e-11f ? wn : 1.0f;
  dsp[idx] = dsp[idx] + y / den;
}

// ---------------- per-frame 1024-tap correlation ----------------
__global__ __launch_bounds__(256) void fir_kernel(const float* __restrict__ dsp,
                                                  const float* __restrict__ filt,
                                                  float* __restrict__ outf) {
  int t = blockIdx.x, b = blockIdx.y;
  __shared__ float fr[FRAME];
  __shared__ float fl[NWIN];
  for (int i = threadIdx.x; i < FRAME; i += 256) fr[i] = dsp[(size_t)b * LW + (size_t)t * FRAME + i];
  for (int i = threadIdx.x; i < NWIN; i += 256)  fl[i] = filt[((size_t)b * LF + t) * NWIN + i];
  __syncthreads();
  for (int i = threadIdx.x; i < FRAME + NWIN; i += 256) {
    int m0 = i - NWIN;
    int tau0 = m0 < 0 ? -m0 : 0;
    int tau1 = FRAME - m0; if (tau1 > NWIN) tau1 = NWIN;
    float acc = 0.f;
    for (int tau = tau0; tau < tau1; ++tau) acc = fmaf(fr[m0 + tau], fl[tau], acc);
    outf[((size_t)b * LF + t) * (FRAME + NWIN) + i] = acc;
  }
}

// ---------------- fold frames (stride 960) into output ----------------
__global__ void fold_kernel(const float* __restrict__ outf, float* __restrict__ out) {
  int idx = blockIdx.x * 256 + threadIdx.x;
  if (idx >= NB * LW) return;
  int b = idx / LW, n = idx % LW;
  int t0 = (n >= 1984) ? ((n - 1024) / 960) : 0;
  int t1 = n / 960; if (t1 > 199) t1 = 199;
  float acc = 0.f;
  for (int t = t0; t <= t1; ++t)
    acc += outf[((size_t)b * LF + t) * (FRAME + NWIN) + (n - 960 * t)];
  out[idx] = acc;
}

extern "C" void kernel_launch(void* const* d_in, const int* in_sizes, int n_in,
                              void* d_out, int out_size, void* d_ws, size_t ws_size,
                              hipStream_t stream) {
  const float* content    = (const float*)d_in[0];
  const float* f0         = (const float*)d_in[1];
  const float* energy     = (const float*)d_in[2];
  const float* spk        = (const float*)d_in[3];
  const float* s_in_w     = (const float*)d_in[4];
  const float* s_in_b     = (const float*)d_in[5];
  const float* s_dw_w     = (const float*)d_in[6];
  const float* s_dw_b     = (const float*)d_in[7];
  const float* s_ln       = (const float*)d_in[8];
  const float* s_pw1_w    = (const float*)d_in[9];
  const float* s_pw1_b    = (const float*)d_in[10];
  const float* s_pw2_w    = (const float*)d_in[11];
  const float* s_pw2_b    = (const float*)d_in[12];
  const float* s_out_norm = (const float*)d_in[13];
  const float* f_in_w     = (const float*)d_in[14];
  const float* f_in_b     = (const float*)d_in[15];
  const float* f_dw_w     = (const float*)d_in[16];
  const float* f_dw_b     = (const float*)d_in[17];
  const float* f_ln       = (const float*)d_in[18];
  const float* f_pw1_w    = (const float*)d_in[19];
  const float* f_pw1_b    = (const float*)d_in[20];
  const float* f_pw2_w    = (const float*)d_in[21];
  const float* f_pw2_b    = (const float*)d_in[22];
  const float* f_out_norm = (const float*)d_in[23];
  const float* s_in_norm  = (const float*)d_in[24];
  const float* s_amp_w    = (const float*)d_in[25];
  const float* s_amp_b    = (const float*)d_in[26];
  const float* s_ker_w    = (const float*)d_in[27];
  const float* s_ker_b    = (const float*)d_in[28];
  const float* f_out_w    = (const float*)d_in[29];
  const float* f_out_b    = (const float*)d_in[30];

  // ---- workspace layout (f64 csum first for alignment) ----
  double* CSUM = (double*)d_ws;
  float* FP   = (float*)((char*)d_ws + 12032);   // NB*NCH=1504 doubles
  float* XIN  = FP;                  // 720000
  float* XS   = XIN  + 720000;       // 819200
  float* T512 = XS   + 819200;       // 819200
  float* H15  = T512 + 819200;       // 2457600
  float* KER  = H15  + 2457600;      // 3073600
  float* AMPS = KER  + 3073600;      // 1600
  float* FILT = AMPS + 1600;         // 1638400  (B,200,1024)
  float* FS   = FILT + 1638400;      // 1536000
  float* HARM = FS   + 1536000;      // 1536000  (becomes dsp)
  float* XP   = HARM + 1536000;      // 1566720
  float* SPEC = XP   + 1566720;      // 6147200  (also im2col: 5734400)
  float* FT   = SPEC + 6147200;      // 6144000
  float* OUTF = FT   + 6144000;      // 3174400
  float* IM   = SPEC;                // im2col overlay (used before SPEC)

  (void)in_sizes; (void)n_in; (void)out_size; (void)ws_size;

  build_xin<<<dim3((NB * CIN * LF + 255) / 256), 256, 0, stream>>>(content, f0, energy, spk, XIN);

  auto run_trunk = [&](const float* in_w, const float* in_b, const float* in_norm,
                       const float* dw_w, const float* dw_b, const float* lnp,
                       const float* pw1_w, const float* pw1_b,
                       const float* pw2_w, const float* pw2_b,
                       const float* out_norm) {
    gemm_act<<<dim3(4, 8, NB), 256, 0, stream>>>(in_w, XIN, in_b, nullptr, XS,
        CI, CIN, LF, 0, (long long)CI * LF, LF, 1);
    if (in_norm)
      ln_kernel<<<dim3(4, NB), 256, 0, stream>>>(XS, in_norm, in_norm + CI);
    for (int i = 0; i < NL; ++i) {
      dwconv_kernel<<<dim3((NB * CI * LF + 255) / 256), 256, 0, stream>>>(
          XS, dw_w + (size_t)i * CI * 7, dw_b + (size_t)i * CI, T512);
      ln_kernel<<<dim3(4, NB), 256, 0, stream>>>(T512, lnp + (size_t)(i * 2) * CI, lnp + (size_t)(i * 2 + 1) * CI);
      gemm_act<<<dim3(4, HID / 64, NB), 256, 0, stream>>>(
          pw1_w + (size_t)i * HID * CI, T512, pw1_b + (size_t)i * HID, nullptr, H15,
          HID, CI, LF, 1, (long long)HID * LF, LF, 1);
      gemm_act<<<dim3(4, CI / 64, NB), 256, 0, stream>>>(
          pw2_w + (size_t)i * CI * HID, H15, pw2_b + (size_t)i * CI, XS, XS,
          CI, HID, LF, 0, (long long)CI * LF, LF, 1);
    }
    ln_kernel<<<dim3(4, NB), 256, 0, stream>>>(XS, out_norm, out_norm + CI);
  };

  // ---- source trunk ----
  run_trunk(s_in_w, s_in_b, s_in_norm, s_dw_w, s_dw_b, s_ln,
            s_pw1_w, s_pw1_b, s_pw2_w, s_pw2_b, s_out_norm);
  amps_kernel<<<dim3(NB), 256, 0, stream>>>(XS, s_amp_w, s_amp_b, AMPS);
  gemm_act<<<dim3(4, (NFREQ + 63) / 64, NB), 256, 0, stream>>>(
      s_ker_w, XS, s_ker_b, nullptr, KER, NFREQ, CI, LF, 2, (long long)NFREQ * LF, LF, 1);

  // ---- filter trunk (no input norm) ----
  run_trunk(f_in_w, f_in_b, nullptr, f_dw_w, f_dw_b, f_ln,
            f_pw1_w, f_pw1_b, f_pw2_w, f_pw2_b, f_out_norm);
  im2col_kernel<<<dim3((NB * 3584 * LF + 255) / 256), 256, 0, stream>>>(XS, IM);
  // filt: (B,1024,200) conv -> stored transposed as (B,200,1024)
  gemm_act<<<dim3(4, NWIN / 64, NB), 256, 0, stream>>>(
      f_out_w, IM, f_out_b, nullptr, FILT, NWIN, 3584, LF, 0,
      (long long)LF * NWIN, 1LL, (long long)NWIN);

  // ---- harmonic source ----
  fs_kernel<<<dim3((NB * LW + 255) / 256), 256, 0, stream>>>(f0, FS);
  cumsum1<<<dim3(NCH, NB), 256, 0, stream>>>(FS, CSUM);
  cumsum2<<<dim3(NB), 64, 0, stream>>>(CSUM);
  harm_kernel<<<dim3(NCH, NB), 256, 0, stream>>>(FS, CSUM, f0, AMPS, HARM);

  // ---- filtered noise ----
  xp_kernel<<<dim3((NB * LPADW + 255) / 256), 256, 0, stream>>>(XP);
  dft_fwd<<<dim3(LF, NB), 256, 0, stream>>>(XP, KER, SPEC);
  dft_inv<<<dim3(LF, NB), 256, 0, stream>>>(SPEC, FT);
  ola_kernel<<<dim3((NB * LW + 255) / 256), 256, 0, stream>>>(FT, HARM);  // HARM -> dsp

  // ---- time-varying FIR + fold ----
  fir_kernel<<<dim3(LF, NB), 256, 0, stream>>>(HARM, FILT, OUTF);
  fold_kernel<<<dim3((NB * LW + 255) / 256), 256, 0, stream>>>(OUTF, (float*)d_out);
}

// Round 3
// 9998.545 us; speedup vs baseline: 1.7311x; 1.7311x over previous
//
#include <hip/hip_runtime.h>
#include <hip/hip_bf16.h>
#include <math.h>
#include <stdint.h>

#define FRAME 960
#define NFFT  3840
#define NWIN  1024
#define NFREQ 1921
#define NB    8
#define LF    200
#define LW    192000
#define LPADW 195840
#define CIN   450
#define CI    512
#define HID   1536
#define NL    6
#define NCH   188   // ceil(192000/1024)

// ---------------- threefry (JAX partitionable variant) ----------------
__device__ __forceinline__ uint32_t rotl32(uint32_t v, int r) { return (v << r) | (v >> (32 - r)); }

__device__ __forceinline__ void threefry2x32(uint32_t k0, uint32_t k1, uint32_t& x0, uint32_t& x1) {
  uint32_t ks2 = k0 ^ k1 ^ 0x1BD11BDAu;
  x0 += k0; x1 += k1;
#define TFR(r) { x0 += x1; x1 = rotl32(x1, r); x1 ^= x0; }
  TFR(13) TFR(15) TFR(26) TFR(6)  x0 += k1;  x1 += ks2 + 1u;
  TFR(17) TFR(29) TFR(16) TFR(24) x0 += ks2; x1 += k0 + 2u;
  TFR(13) TFR(15) TFR(26) TFR(6)  x0 += k0;  x1 += k1 + 3u;
  TFR(17) TFR(29) TFR(16) TFR(24) x0 += k1;  x1 += ks2 + 4u;
  TFR(13) TFR(15) TFR(26) TFR(6)  x0 += ks2; x1 += k0 + 5u;
#undef TFR
}

__device__ __forceinline__ float winf(int j) {
  return 0.5f - 0.5f * cosf((6.283185307179586f * (float)j) / 3840.0f);
}

// ---------------- xin ----------------
__global__ void build_xin(const float* __restrict__ content, const float* __restrict__ f0,
                          const float* __restrict__ energy, const float* __restrict__ spk,
                          float* __restrict__ xin) {
  int idx = blockIdx.x * 256 + threadIdx.x;
  if (idx >= NB * CIN * LF) return;
  int b = idx / (CIN * LF);
  int r = idx % (CIN * LF);
  int c = r / LF, l = r % LF;
  float v;
  if (c < 192)       v = content[((size_t)b * 192 + c) * LF + l];
  else if (c < 448)  v = spk[b * 256 + (c - 192)];
  else if (c == 448) v = logf(fmaxf(f0[b * LF + l], 0.0f) + 1e-6f);
  else               v = energy[b * LF + l];
  xin[idx] = v;
}

// ---------------- generic tiled GEMM: out[b,o,l] = act(sum_c W[o,c]*X[b,c,l] + bias[o]) (+res) ----------------
__global__ __launch_bounds__(256) void gemm_act(
    const float* __restrict__ W, const float* __restrict__ X,
    const float* __restrict__ bias, const float* __restrict__ res,
    float* __restrict__ out, int O, int K, int L, int act,
    long long oSB, long long oSO, long long oSL)
{
  __shared__ float Ws[64][16];
  __shared__ float Xs[16][64];
  int b  = blockIdx.z;
  int o0 = blockIdx.y * 64;
  int l0 = blockIdx.x * 64;
  int tid = threadIdx.x;
  int tx = tid & 15, ty = tid >> 4;
  const float* Xb = X + (long long)b * K * L;
  float acc[4][4] = {{0.f}};
  for (int k0 = 0; k0 < K; k0 += 16) {
    for (int i = tid; i < 64 * 16; i += 256) {
      int oo = i >> 4, kk = i & 15;
      int o = o0 + oo, k = k0 + kk;
      Ws[oo][kk] = (o < O && k < K) ? W[(long long)o * K + k] : 0.f;
    }
    for (int i = tid; i < 16 * 64; i += 256) {
      int kk = i >> 6, ll = i & 63;
      int k = k0 + kk, l = l0 + ll;
      Xs[kk][ll] = (k < K && l < L) ? Xb[(long long)k * L + l] : 0.f;
    }
    __syncthreads();
#pragma unroll
    for (int kk = 0; kk < 16; ++kk) {
      float a[4], bb[4];
#pragma unroll
      for (int i = 0; i < 4; ++i) a[i] = Ws[ty + 16 * i][kk];
#pragma unroll
      for (int j = 0; j < 4; ++j) bb[j] = Xs[kk][tx + 16 * j];
#pragma unroll
      for (int i = 0; i < 4; ++i)
#pragma unroll
        for (int j = 0; j < 4; ++j)
          acc[i][j] = fmaf(a[i], bb[j], acc[i][j]);
    }
    __syncthreads();
  }
  for (int i = 0; i < 4; ++i) {
    int o = o0 + ty + 16 * i;
    if (o >= O) continue;
    float bv = bias ? bias[o] : 0.f;
    for (int j = 0; j < 4; ++j) {
      int l = l0 + tx + 16 * j;
      if (l >= L) continue;
      float v = acc[i][j] + bv;
      if (act == 1)      v = 0.5f * v * (1.0f + erff(v * 0.7071067811865475f));  // exact gelu
      else if (act == 2) v = (v > 0.f ? v : expm1f(v)) + 1.0f;                   // elu + 1
      if (res) v += res[((long long)b * O + o) * L + l];
      out[(long long)b * oSB + (long long)o * oSO + (long long)l * oSL] = v;
    }
  }
}

// ---------------- channel LayerNorm (in-place) on (B,CI,LF) ----------------
__global__ __launch_bounds__(256) void ln_kernel(float* __restrict__ x, const float* __restrict__ g,
                                                 const float* __restrict__ bta) {
  int b = blockIdx.y;
  int lx = threadIdx.x & 63;
  int cy = threadIdx.x >> 6;
  int l = blockIdx.x * 64 + lx;
  bool valid = l < LF;
  float* xb = x + (size_t)b * CI * LF;
  __shared__ float red[4][64];
  float s = 0.f;
  if (valid) for (int c = cy; c < CI; c += 4) s += xb[c * LF + l];
  red[cy][lx] = s;
  __syncthreads();
  float mean = (red[0][lx] + red[1][lx] + red[2][lx] + red[3][lx]) * (1.0f / CI);
  __syncthreads();
  float s2 = 0.f;
  if (valid) for (int c = cy; c < CI; c += 4) { float d = xb[c * LF + l] - mean; s2 += d * d; }
  red[cy][lx] = s2;
  __syncthreads();
  float var = (red[0][lx] + red[1][lx] + red[2][lx] + red[3][lx]) * (1.0f / CI);
  float rs = rsqrtf(var + 1e-5f);
  if (valid) for (int c = cy; c < CI; c += 4)
    xb[c * LF + l] = (xb[c * LF + l] - mean) * rs * g[c] + bta[c];
}

// ---------------- depthwise conv K=7, zero pad same ----------------
__global__ void dwconv_kernel(const float* __restrict__ x, const float* __restrict__ w,
                              const float* __restrict__ bias, float* __restrict__ out) {
  int idx = blockIdx.x * 256 + threadIdx.x;
  if (idx >= NB * CI * LF) return;
  int b = idx / (CI * LF);
  int r = idx % (CI * LF);
  int c = r / LF, l = r % LF;
  float acc = bias[c];
#pragma unroll
  for (int tau = 0; tau < 7; ++tau) {
    int j = l + tau - 3;
    if (j >= 0 && j < LF) acc = fmaf(x[((size_t)b * CI + c) * LF + j], w[c * 7 + tau], acc);
  }
  out[idx] = acc;
}

// ---------------- amps head: elu(w.x+b)+1, O=1 ----------------
__global__ __launch_bounds__(256) void amps_kernel(const float* __restrict__ x, const float* __restrict__ w,
                                                   const float* __restrict__ bias, float* __restrict__ amps) {
  int b = blockIdx.x;
  __shared__ float ws[CI];
  for (int i = threadIdx.x; i < CI; i += 256) ws[i] = w[i];
  __syncthreads();
  int l = threadIdx.x;
  if (l < LF) {
    float acc = bias[0];
    for (int c = 0; c < CI; ++c) acc = fmaf(ws[c], x[((size_t)b * CI + c) * LF + l], acc);
    amps[b * LF + l] = (acc > 0.f ? acc : expm1f(acc)) + 1.0f;
  }
}

// ---------------- im2col for f_out conv (edge pad 3) ----------------
__global__ void im2col_kernel(const float* __restrict__ x, float* __restrict__ im) {
  int idx = blockIdx.x * 256 + threadIdx.x;
  if (idx >= NB * 3584 * LF) return;
  int b = idx / (3584 * LF);
  int r = idx % (3584 * LF);
  int k = r / LF, l = r % LF;
  int c = k / 7, tau = k % 7;
  int j = l + tau - 3;
  j = j < 0 ? 0 : (j > LF - 1 ? LF - 1 : j);
  im[idx] = x[((size_t)b * CI + c) * LF + j];
}

// ---------------- f0 linear interp to LW ----------------
__global__ void fs_kernel(const float* __restrict__ f0, float* __restrict__ fs) {
  int idx = blockIdx.x * 256 + threadIdx.x;
  if (idx >= NB * LW) return;
  int b = idx / LW, n = idx % LW;
  float pos = ((float)n + 0.5f) * (200.0f / 192000.0f) - 0.5f;
  pos = fminf(fmaxf(pos, 0.0f), 199.0f);
  int i0 = (int)pos;
  int i1 = min(i0 + 1, 199);
  float w = pos - (float)i0;
  fs[idx] = f0[b * LF + i0] * (1.0f - w) + f0[b * LF + i1] * w;
}

// ---------------- cumsum phase 1: per-chunk f64 sums ----------------
__global__ __launch_bounds__(256) void cumsum1(const float* __restrict__ fs, double* __restrict__ csum) {
  int b = blockIdx.y, ch = blockIdx.x;
  const float* fsb = fs + (size_t)b * LW;
  int base = ch * 1024;
  double s = 0.0;
  for (int q = 0; q < 4; ++q) {
    int n = base + threadIdx.x * 4 + q;
    if (n < LW) {
      float sm = (3.14159274101257324f * fsb[n]) / 48000.0f;
      s += (double)sm;
    }
  }
  __shared__ double sh[256];
  sh[threadIdx.x] = s;
  __syncthreads();
  for (int o2 = 128; o2 > 0; o2 >>= 1) {
    if (threadIdx.x < o2) sh[threadIdx.x] += sh[threadIdx.x + o2];
    __syncthreads();
  }
  if (threadIdx.x == 0) csum[b * NCH + ch] = sh[0];
}

// ---------------- cumsum phase 2: exclusive scan of chunk sums ----------------
__global__ void cumsum2(double* __restrict__ csum) {
  int b = blockIdx.x;
  if (threadIdx.x == 0) {
    double acc = 0.0;
    for (int ch = 0; ch < NCH; ++ch) {
      double v = csum[b * NCH + ch];
      csum[b * NCH + ch] = acc;
      acc += v;
    }
  }
}

// ---------------- harmonic source ----------------
__global__ __launch_bounds__(256) void harm_kernel(
    const float* __restrict__ fs, const double* __restrict__ csum,
    const float* __restrict__ f0, const float* __restrict__ amps,
    float* __restrict__ harm) {
  int b = blockIdx.y, ch = blockIdx.x;
  const float* fsb = fs + (size_t)b * LW;
  int base = ch * 1024;
  int tid = threadIdx.x;
  double p[4]; double s = 0.0;
  int n0 = base + tid * 4;
  for (int q = 0; q < 4; ++q) {
    int n = n0 + q; float sm = 0.f;
    if (n < LW) sm = (3.14159274101257324f * fsb[n]) / 48000.0f;
    s += (double)sm; p[q] = s;
  }
  __shared__ double sh[256];
  sh[tid] = s; __syncthreads();
  for (int o2 = 1; o2 < 256; o2 <<= 1) {
    double v = (tid >= o2) ? sh[tid - o2] : 0.0;
    __syncthreads();
    sh[tid] += v;
    __syncthreads();
  }
  double excl = csum[b * NCH + ch] + (tid > 0 ? sh[tid - 1] : 0.0);
  const double PID = (double)3.14159274101257324f;
  for (int q = 0; q < 4; ++q) {
    int n = n0 + q; if (n >= LW) break;
    double S = excl + p[q];
    float pixf = (float)fmod(S, PID);
    float fsv = fsb[n];
    float a = rintf(48000.0f / fmaxf(fsv, 20.0f) * 0.5f) * 2.0f + 1.0f;
    float D = (pixf < 1e-8f) ? 1.0f : (sinf(a * pixf) / (a * sinf(pixf)));
    int ui = n / 960;
    float uv = (f0[b * LF + ui] > 20.0f) ? 1.0f : 0.0f;
    float posA = ((float)n + 0.5f) * (200.0f / 192000.0f) - 0.5f;
    posA = fminf(fmaxf(posA, 0.0f), 199.0f);
    int i0 = (int)posA;
    int i1 = min(i0 + 1, 199);
    float w = posA - (float)i0;
    float ampI = amps[b * LF + i0] * (1.0f - w) + amps[b * LF + i1] * w;
    harm[(size_t)b * LW + n] = (D * uv) * ampI;
  }
}

// ---------------- noise, reflect-padded ----------------
__global__ void xp_kernel(float* __restrict__ xp) {
  int idx = blockIdx.x * 256 + threadIdx.x;
  if (idx >= NB * LPADW) return;
  int b = idx / LPADW, j = idx % LPADW;
  int m = j - 1920;
  if (m < 0) m = -m;
  if (m >= LW) m = 2 * LW - 2 - m;
  uint32_t i = (uint32_t)(b * LW + m);
  uint32_t x0 = 0u, x1 = i;
  threefry2x32(0u, 123u, x0, x1);
  uint32_t bits = x0 ^ x1;  // jax partitionable 32-bit combine
  xp[idx] = __uint_as_float((bits >> 9) | 0x3f800000u) - 1.0f;
}

// ---------------- forward DFT via phase recurrence (no twiddle table) ----------------
// spec[k] = sum_j v_j * e^{-2pi i jk/N};  w_{j+1} = w_j * c,  c = e^{-2pi i k/N}.
// Only LDS access is s[j], same address across lanes -> broadcast, conflict-free.
__global__ __launch_bounds__(256) void dft_fwd(const float* __restrict__ xp,
                                               const float* __restrict__ ker,
                                               float* __restrict__ spec) {
  int tt = blockIdx.x;   // frame tt+1 (frame 0 dropped by reference)
  int b  = blockIdx.y;
  __shared__ float s[NFFT];
  const float* xb = xp + (size_t)b * LPADW + (size_t)(tt + 1) * FRAME;
  for (int j = threadIdx.x; j < NFFT; j += 256) s[j] = xb[j] * winf(j);
  __syncthreads();
  const int NC = 8;  // chains: k = tid + 256*c
  float wr[NC], wi[NC], cr[NC], ci[NC], re[NC], im[NC];
#pragma unroll
  for (int c = 0; c < NC; ++c) {
    int k = threadIdx.x + 256 * c;
    double th = -6.283185307179586476925286766559 * (double)k / (double)NFFT;
    cr[c] = (float)cos(th); ci[c] = (float)sin(th);
    wr[c] = 1.f; wi[c] = 0.f; re[c] = 0.f; im[c] = 0.f;
  }
  for (int j = 0; j < NFFT; ++j) {
    float v = s[j];
#pragma unroll
    for (int c = 0; c < NC; ++c) {
      re[c] = fmaf(v, wr[c], re[c]);
      im[c] = fmaf(v, wi[c], im[c]);
      float t = fmaf(wr[c], cr[c], -wi[c] * ci[c]);
      wi[c]   = fmaf(wr[c], ci[c],  wi[c] * cr[c]);
      wr[c] = t;
    }
  }
#pragma unroll
  for (int c = 0; c < NC; ++c) {
    int k = threadIdx.x + 256 * c;
    if (k < NFREQ) {
      float kv = ker[((size_t)b * NFREQ + k) * LF + tt];
      size_t o = (((size_t)b * LF + tt) * NFREQ + k) * 2;
      spec[o]     = re[c] * kv;
      spec[o + 1] = im[c] * kv;
    }
  }
}

// ---------------- inverse rDFT via phase recurrence, x window ----------------
__global__ __launch_bounds__(256) void dft_inv(const float* __restrict__ spec,
                                               float* __restrict__ ft) {
  int tt = blockIdx.x;
  int b  = blockIdx.y;
  __shared__ float Xre[NFREQ], Xim[NFREQ];
  for (int k = threadIdx.x; k < NFREQ; k += 256) {
    size_t o = (((size_t)b * LF + tt) * NFREQ + k) * 2;
    bool edge = (k == 0 || k == NFFT / 2);
    float mult = edge ? (1.0f / NFFT) : (2.0f / NFFT);
    Xre[k] = spec[o] * mult;
    Xim[k] = edge ? 0.f : spec[o + 1] * mult;   // numpy c2r ignores DC/Nyquist imag
  }
  __syncthreads();
  const int NC = 15;  // chains: j = tid + 256*c  (256*15 == 3840 exactly)
  float wr[NC], wi[NC], cr[NC], ci[NC], acc[NC];
#pragma unroll
  for (int c = 0; c < NC; ++c) {
    int j = threadIdx.x + 256 * c;
    double th = 6.283185307179586476925286766559 * (double)j / (double)NFFT;
    cr[c] = (float)cos(th); ci[c] = (float)sin(th);
    wr[c] = 1.f; wi[c] = 0.f; acc[c] = 0.f;
  }
  for (int k = 0; k < NFREQ; ++k) {
    float xr = Xre[k], xi = Xim[k];
#pragma unroll
    for (int c = 0; c < NC; ++c) {
      acc[c] = fmaf(xr, wr[c], acc[c]);
      acc[c] = fmaf(-xi, wi[c], acc[c]);
      float t = fmaf(wr[c], cr[c], -wi[c] * ci[c]);
      wi[c]   = fmaf(wr[c], ci[c],  wi[c] * cr[c]);
      wr[c] = t;
    }
  }
#pragma unroll
  for (int c = 0; c < NC; ++c) {
    int j = threadIdx.x + 256 * c;
    ft[((size_t)b * LF + tt) * NFFT + j] = acc[c] * winf(j);
  }
}

// ---------------- OLA + wn normalize + add harm (in place -> dsp) ----------------
__global__ void ola_kernel(const float* __restrict__ ft, float* __restrict__ dsp) {
  int idx = blockIdx.x * 256 + threadIdx.x;
  if (idx >= NB * LW) return;
  int b = idx / LW, n = idx % LW;
  int p = n + 1920;
  int t0 = (p > 3839) ? ((p - 2880) / 960) : 0;   // ceil((p-3839)/960)
  int t1 = p / FRAME; if (t1 > 200) t1 = 200;
  float y = 0.f, wn = 0.f;
  for (int t = t0; t <= t1; ++t) {
    int j = p - FRAME * t;
    float w = winf(j);
    wn += w * w;
    if (t >= 1) y += ft[((size_t)b * LF + (t - 1)) * NFFT + j];
  }
  float den = wn > 1e-11f ? wn : 1.0f;
  dsp[idx] = dsp[idx] + y / den;
}

// ---------------- per-frame 1024-tap correlation ----------------
__global__ __launch_bounds__(256) void fir_kernel(const float* __restrict__ dsp,
                                                  const float* __restrict__ filt,
                                                  float* __restrict__ outf) {
  int t = blockIdx.x, b = blockIdx.y;
  __shared__ float fr[FRAME];
  __shared__ float fl[NWIN];
  for (int i = threadIdx.x; i < FRAME; i += 256) fr[i] = dsp[(size_t)b * LW + (size_t)t * FRAME + i];
  for (int i = threadIdx.x; i < NWIN; i += 256)  fl[i] = filt[((size_t)b * LF + t) * NWIN + i];
  __syncthreads();
  for (int i = threadIdx.x; i < FRAME + NWIN; i += 256) {
    int m0 = i - NWIN;
    int tau0 = m0 < 0 ? -m0 : 0;
    int tau1 = FRAME - m0; if (tau1 > NWIN) tau1 = NWIN;
    float acc = 0.f;
    for (int tau = tau0; tau < tau1; ++tau) acc = fmaf(fr[m0 + tau], fl[tau], acc);
    outf[((size_t)b * LF + t) * (FRAME + NWIN) + i] = acc;
  }
}

// ---------------- fold frames (stride 960) into output ----------------
__global__ void fold_kernel(const float* __restrict__ outf, float* __restrict__ out) {
  int idx = blockIdx.x * 256 + threadIdx.x;
  if (idx >= NB * LW) return;
  int b = idx / LW, n = idx % LW;
  int t0 = (n >= 1984) ? ((n - 1024) / 960) : 0;
  int t1 = n / 960; if (t1 > 199) t1 = 199;
  float acc = 0.f;
  for (int t = t0; t <= t1; ++t)
    acc += outf[((size_t)b * LF + t) * (FRAME + NWIN) + (n - 960 * t)];
  out[idx] = acc;
}

extern "C" void kernel_launch(void* const* d_in, const int* in_sizes, int n_in,
                              void* d_out, int out_size, void* d_ws, size_t ws_size,
                              hipStream_t stream) {
  const float* content    = (const float*)d_in[0];
  const float* f0         = (const float*)d_in[1];
  const float* energy     = (const float*)d_in[2];
  const float* spk        = (const float*)d_in[3];
  const float* s_in_w     = (const float*)d_in[4];
  const float* s_in_b     = (const float*)d_in[5];
  const float* s_dw_w     = (const float*)d_in[6];
  const float* s_dw_b     = (const float*)d_in[7];
  const float* s_ln       = (const float*)d_in[8];
  const float* s_pw1_w    = (const float*)d_in[9];
  const float* s_pw1_b    = (const float*)d_in[10];
  const float* s_pw2_w    = (const float*)d_in[11];
  const float* s_pw2_b    = (const float*)d_in[12];
  const float* s_out_norm = (const float*)d_in[13];
  const float* f_in_w     = (const float*)d_in[14];
  const float* f_in_b     = (const float*)d_in[15];
  const float* f_dw_w     = (const float*)d_in[16];
  const float* f_dw_b     = (const float*)d_in[17];
  const float* f_ln       = (const float*)d_in[18];
  const float* f_pw1_w    = (const float*)d_in[19];
  const float* f_pw1_b    = (const float*)d_in[20];
  const float* f_pw2_w    = (const float*)d_in[21];
  const float* f_pw2_b    = (const float*)d_in[22];
  const float* f_out_norm = (const float*)d_in[23];
  const float* s_in_norm  = (const float*)d_in[24];
  const float* s_amp_w    = (const float*)d_in[25];
  const float* s_amp_b    = (const float*)d_in[26];
  const float* s_ker_w    = (const float*)d_in[27];
  const float* s_ker_b    = (const float*)d_in[28];
  const float* f_out_w    = (const float*)d_in[29];
  const float* f_out_b    = (const float*)d_in[30];

  // ---- workspace layout (f64 csum first for alignment) ----
  double* CSUM = (double*)d_ws;
  float* FP   = (float*)((char*)d_ws + 12032);   // NB*NCH=1504 doubles
  float* XIN  = FP;                  // 720000
  float* XS   = XIN  + 720000;       // 819200
  float* T512 = XS   + 819200;       // 819200
  float* H15  = T512 + 819200;       // 2457600
  float* KER  = H15  + 2457600;      // 3073600
  float* AMPS = KER  + 3073600;      // 1600
  float* FILT = AMPS + 1600;         // 1638400  (B,200,1024)
  float* FS   = FILT + 1638400;      // 1536000
  float* HARM = FS   + 1536000;      // 1536000  (becomes dsp)
  float* XP   = HARM + 1536000;      // 1566720
  float* SPEC = XP   + 1566720;      // 6147200  (also im2col: 5734400)
  float* FT   = SPEC + 6147200;      // 6144000
  float* OUTF = FT   + 6144000;      // 3174400
  float* IM   = SPEC;                // im2col overlay (used before SPEC)

  (void)in_sizes; (void)n_in; (void)out_size; (void)ws_size;

  build_xin<<<dim3((NB * CIN * LF + 255) / 256), 256, 0, stream>>>(content, f0, energy, spk, XIN);

  auto run_trunk = [&](const float* in_w, const float* in_b, const float* in_norm,
                       const float* dw_w, const float* dw_b, const float* lnp,
                       const float* pw1_w, const float* pw1_b,
                       const float* pw2_w, const float* pw2_b,
                       const float* out_norm) {
    gemm_act<<<dim3(4, 8, NB), 256, 0, stream>>>(in_w, XIN, in_b, nullptr, XS,
        CI, CIN, LF, 0, (long long)CI * LF, LF, 1);
    if (in_norm)
      ln_kernel<<<dim3(4, NB), 256, 0, stream>>>(XS, in_norm, in_norm + CI);
    for (int i = 0; i < NL; ++i) {
      dwconv_kernel<<<dim3((NB * CI * LF + 255) / 256), 256, 0, stream>>>(
          XS, dw_w + (size_t)i * CI * 7, dw_b + (size_t)i * CI, T512);
      ln_kernel<<<dim3(4, NB), 256, 0, stream>>>(T512, lnp + (size_t)(i * 2) * CI, lnp + (size_t)(i * 2 + 1) * CI);
      gemm_act<<<dim3(4, HID / 64, NB), 256, 0, stream>>>(
          pw1_w + (size_t)i * HID * CI, T512, pw1_b + (size_t)i * HID, nullptr, H15,
          HID, CI, LF, 1, (long long)HID * LF, LF, 1);
      gemm_act<<<dim3(4, CI / 64, NB), 256, 0, stream>>>(
          pw2_w + (size_t)i * CI * HID, H15, pw2_b + (size_t)i * CI, XS, XS,
          CI, HID, LF, 0, (long long)CI * LF, LF, 1);
    }
    ln_kernel<<<dim3(4, NB), 256, 0, stream>>>(XS, out_norm, out_norm + CI);
  };

  // ---- source trunk ----
  run_trunk(s_in_w, s_in_b, s_in_norm, s_dw_w, s_dw_b, s_ln,
            s_pw1_w, s_pw1_b, s_pw2_w, s_pw2_b, s_out_norm);
  amps_kernel<<<dim3(NB), 256, 0, stream>>>(XS, s_amp_w, s_amp_b, AMPS);
  gemm_act<<<dim3(4, (NFREQ + 63) / 64, NB), 256, 0, stream>>>(
      s_ker_w, XS, s_ker_b, nullptr, KER, NFREQ, CI, LF, 2, (long long)NFREQ * LF, LF, 1);

  // ---- filter trunk (no input norm) ----
  run_trunk(f_in_w, f_in_b, nullptr, f_dw_w, f_dw_b, f_ln,
            f_pw1_w, f_pw1_b, f_pw2_w, f_pw2_b, f_out_norm);
  im2col_kernel<<<dim3((NB * 3584 * LF + 255) / 256), 256, 0, stream>>>(XS, IM);
  // filt: (B,1024,200) conv -> stored transposed as (B,200,1024)
  gemm_act<<<dim3(4, NWIN / 64, NB), 256, 0, stream>>>(
      f_out_w, IM, f_out_b, nullptr, FILT, NWIN, 3584, LF, 0,
      (long long)LF * NWIN, 1LL, (long long)NWIN);

  // ---- harmonic source ----
  fs_kernel<<<dim3((NB * LW + 255) / 256), 256, 0, stream>>>(f0, FS);
  cumsum1<<<dim3(NCH, NB), 256, 0, stream>>>(FS, CSUM);
  cumsum2<<<dim3(NB), 64, 0, stream>>>(CSUM);
  harm_kernel<<<dim3(NCH, NB), 256, 0, stream>>>(FS, CSUM, f0, AMPS, HARM);

  // ---- filtered noise ----
  xp_kernel<<<dim3((NB * LPADW + 255) / 256), 256, 0, stream>>>(XP);
  dft_fwd<<<dim3(LF, NB), 256, 0, stream>>>(XP, KER, SPEC);
  dft_inv<<<dim3(LF, NB), 256, 0, stream>>>(SPEC, FT);
  ola_kernel<<<dim3((NB * LW + 255) / 256), 256, 0, stream>>>(FT, HARM);  // HARM -> dsp

  // ---- time-varying FIR + fold ----
  fir_kernel<<<dim3(LF, NB), 256, 0, stream>>>(HARM, FILT, OUTF);
  fold_kernel<<<dim3((NB * LW + 255) / 256), 256, 0, stream>>>(OUTF, (float*)d_out);
}

// Round 4
// 8064.095 us; speedup vs baseline: 2.1463x; 1.2399x over previous
//
#include <hip/hip_runtime.h>
#include <hip/hip_bf16.h>
#include <math.h>
#include <stdint.h>

#define FRAME 960
#define NFFT  3840
#define NWIN  1024
#define NFREQ 1921
#define NB    8
#define LF    200
#define LW    192000
#define LPADW 195840
#define CIN   450
#define CI    512
#define HID   1536
#define NL    6
#define NCH   188   // ceil(192000/1024)
#define NK2   3842  // 2*NFREQ columns (re/im interleaved)
#define MTOT  1600  // NB*LF frames

typedef __attribute__((ext_vector_type(8))) short short8v;
typedef __attribute__((ext_vector_type(4))) float f32x4;

// ---------------- threefry (JAX partitionable variant) ----------------
__device__ __forceinline__ uint32_t rotl32(uint32_t v, int r) { return (v << r) | (v >> (32 - r)); }

__device__ __forceinline__ void threefry2x32(uint32_t k0, uint32_t k1, uint32_t& x0, uint32_t& x1) {
  uint32_t ks2 = k0 ^ k1 ^ 0x1BD11BDAu;
  x0 += k0; x1 += k1;
#define TFR(r) { x0 += x1; x1 = rotl32(x1, r); x1 ^= x0; }
  TFR(13) TFR(15) TFR(26) TFR(6)  x0 += k1;  x1 += ks2 + 1u;
  TFR(17) TFR(29) TFR(16) TFR(24) x0 += ks2; x1 += k0 + 2u;
  TFR(13) TFR(15) TFR(26) TFR(6)  x0 += k0;  x1 += k1 + 3u;
  TFR(17) TFR(29) TFR(16) TFR(24) x0 += k1;  x1 += ks2 + 4u;
  TFR(13) TFR(15) TFR(26) TFR(6)  x0 += ks2; x1 += k0 + 5u;
#undef TFR
}

__device__ __forceinline__ float winf(int j) {
  return 0.5f - 0.5f * cosf((6.283185307179586f * (float)j) / 3840.0f);
}

// bf16 round-to-nearest-even helpers
__device__ __forceinline__ unsigned short f2bf(float v) {
  uint32_t b = __float_as_uint(v);
  return (unsigned short)((b + 0x7FFFu + ((b >> 16) & 1u)) >> 16);
}
__device__ __forceinline__ float bf2f(unsigned short h) {
  return __uint_as_float(((uint32_t)h) << 16);
}

// ---------------- xin ----------------
__global__ void build_xin(const float* __restrict__ content, const float* __restrict__ f0,
                          const float* __restrict__ energy, const float* __restrict__ spk,
                          float* __restrict__ xin) {
  int idx = blockIdx.x * 256 + threadIdx.x;
  if (idx >= NB * CIN * LF) return;
  int b = idx / (CIN * LF);
  int r = idx % (CIN * LF);
  int c = r / LF, l = r % LF;
  float v;
  if (c < 192)       v = content[((size_t)b * 192 + c) * LF + l];
  else if (c < 448)  v = spk[b * 256 + (c - 192)];
  else if (c == 448) v = logf(fmaxf(f0[b * LF + l], 0.0f) + 1e-6f);
  else               v = energy[b * LF + l];
  xin[idx] = v;
}

// ---------------- generic tiled GEMM: out[b,o,l] = act(sum_c W[o,c]*X[b,c,l] + bias[o]) (+res) ----------------
__global__ __launch_bounds__(256) void gemm_act(
    const float* __restrict__ W, const float* __restrict__ X,
    const float* __restrict__ bias, const float* __restrict__ res,
    float* __restrict__ out, int O, int K, int L, int act,
    long long oSB, long long oSO, long long oSL)
{
  __shared__ float Ws[64][16];
  __shared__ float Xs[16][64];
  int b  = blockIdx.z;
  int o0 = blockIdx.y * 64;
  int l0 = blockIdx.x * 64;
  int tid = threadIdx.x;
  int tx = tid & 15, ty = tid >> 4;
  const float* Xb = X + (long long)b * K * L;
  float acc[4][4] = {{0.f}};
  for (int k0 = 0; k0 < K; k0 += 16) {
    for (int i = tid; i < 64 * 16; i += 256) {
      int oo = i >> 4, kk = i & 15;
      int o = o0 + oo, k = k0 + kk;
      Ws[oo][kk] = (o < O && k < K) ? W[(long long)o * K + k] : 0.f;
    }
    for (int i = tid; i < 16 * 64; i += 256) {
      int kk = i >> 6, ll = i & 63;
      int k = k0 + kk, l = l0 + ll;
      Xs[kk][ll] = (k < K && l < L) ? Xb[(long long)k * L + l] : 0.f;
    }
    __syncthreads();
#pragma unroll
    for (int kk = 0; kk < 16; ++kk) {
      float a[4], bb[4];
#pragma unroll
      for (int i = 0; i < 4; ++i) a[i] = Ws[ty + 16 * i][kk];
#pragma unroll
      for (int j = 0; j < 4; ++j) bb[j] = Xs[kk][tx + 16 * j];
#pragma unroll
      for (int i = 0; i < 4; ++i)
#pragma unroll
        for (int j = 0; j < 4; ++j)
          acc[i][j] = fmaf(a[i], bb[j], acc[i][j]);
    }
    __syncthreads();
  }
  for (int i = 0; i < 4; ++i) {
    int o = o0 + ty + 16 * i;
    if (o >= O) continue;
    float bv = bias ? bias[o] : 0.f;
    for (int j = 0; j < 4; ++j) {
      int l = l0 + tx + 16 * j;
      if (l >= L) continue;
      float v = acc[i][j] + bv;
      if (act == 1)      v = 0.5f * v * (1.0f + erff(v * 0.7071067811865475f));  // exact gelu
      else if (act == 2) v = (v > 0.f ? v : expm1f(v)) + 1.0f;                   // elu + 1
      if (res) v += res[((long long)b * O + o) * L + l];
      out[(long long)b * oSB + (long long)o * oSO + (long long)l * oSL] = v;
    }
  }
}

// ---------------- channel LayerNorm (in-place) on (B,CI,LF) ----------------
__global__ __launch_bounds__(256) void ln_kernel(float* __restrict__ x, const float* __restrict__ g,
                                                 const float* __restrict__ bta) {
  int b = blockIdx.y;
  int lx = threadIdx.x & 63;
  int cy = threadIdx.x >> 6;
  int l = blockIdx.x * 64 + lx;
  bool valid = l < LF;
  float* xb = x + (size_t)b * CI * LF;
  __shared__ float red[4][64];
  float s = 0.f;
  if (valid) for (int c = cy; c < CI; c += 4) s += xb[c * LF + l];
  red[cy][lx] = s;
  __syncthreads();
  float mean = (red[0][lx] + red[1][lx] + red[2][lx] + red[3][lx]) * (1.0f / CI);
  __syncthreads();
  float s2 = 0.f;
  if (valid) for (int c = cy; c < CI; c += 4) { float d = xb[c * LF + l] - mean; s2 += d * d; }
  red[cy][lx] = s2;
  __syncthreads();
  float var = (red[0][lx] + red[1][lx] + red[2][lx] + red[3][lx]) * (1.0f / CI);
  float rs = rsqrtf(var + 1e-5f);
  if (valid) for (int c = cy; c < CI; c += 4)
    xb[c * LF + l] = (xb[c * LF + l] - mean) * rs * g[c] + bta[c];
}

// ---------------- depthwise conv K=7, zero pad same ----------------
__global__ void dwconv_kernel(const float* __restrict__ x, const float* __restrict__ w,
                              const float* __restrict__ bias, float* __restrict__ out) {
  int idx = blockIdx.x * 256 + threadIdx.x;
  if (idx >= NB * CI * LF) return;
  int b = idx / (CI * LF);
  int r = idx % (CI * LF);
  int c = r / LF, l = r % LF;
  float acc = bias[c];
#pragma unroll
  for (int tau = 0; tau < 7; ++tau) {
    int j = l + tau - 3;
    if (j >= 0 && j < LF) acc = fmaf(x[((size_t)b * CI + c) * LF + j], w[c * 7 + tau], acc);
  }
  out[idx] = acc;
}

// ---------------- amps head: elu(w.x+b)+1, O=1 ----------------
__global__ __launch_bounds__(256) void amps_kernel(const float* __restrict__ x, const float* __restrict__ w,
                                                   const float* __restrict__ bias, float* __restrict__ amps) {
  int b = blockIdx.x;
  __shared__ float ws[CI];
  for (int i = threadIdx.x; i < CI; i += 256) ws[i] = w[i];
  __syncthreads();
  int l = threadIdx.x;
  if (l < LF) {
    float acc = bias[0];
    for (int c = 0; c < CI; ++c) acc = fmaf(ws[c], x[((size_t)b * CI + c) * LF + l], acc);
    amps[b * LF + l] = (acc > 0.f ? acc : expm1f(acc)) + 1.0f;
  }
}

// ---------------- im2col for f_out conv (edge pad 3) ----------------
__global__ void im2col_kernel(const float* __restrict__ x, float* __restrict__ im) {
  int idx = blockIdx.x * 256 + threadIdx.x;
  if (idx >= NB * 3584 * LF) return;
  int b = idx / (3584 * LF);
  int r = idx % (3584 * LF);
  int k = r / LF, l = r % LF;
  int c = k / 7, tau = k % 7;
  int j = l + tau - 3;
  j = j < 0 ? 0 : (j > LF - 1 ? LF - 1 : j);
  im[idx] = x[((size_t)b * CI + c) * LF + j];
}

// ---------------- f0 linear interp to LW ----------------
__global__ void fs_kernel(const float* __restrict__ f0, float* __restrict__ fs) {
  int idx = blockIdx.x * 256 + threadIdx.x;
  if (idx >= NB * LW) return;
  int b = idx / LW, n = idx % LW;
  float pos = ((float)n + 0.5f) * (200.0f / 192000.0f) - 0.5f;
  pos = fminf(fmaxf(pos, 0.0f), 199.0f);
  int i0 = (int)pos;
  int i1 = min(i0 + 1, 199);
  float w = pos - (float)i0;
  fs[idx] = f0[b * LF + i0] * (1.0f - w) + f0[b * LF + i1] * w;
}

// ---------------- cumsum phase 1: per-chunk f64 sums ----------------
__global__ __launch_bounds__(256) void cumsum1(const float* __restrict__ fs, double* __restrict__ csum) {
  int b = blockIdx.y, ch = blockIdx.x;
  const float* fsb = fs + (size_t)b * LW;
  int base = ch * 1024;
  double s = 0.0;
  for (int q = 0; q < 4; ++q) {
    int n = base + threadIdx.x * 4 + q;
    if (n < LW) {
      float sm = (3.14159274101257324f * fsb[n]) / 48000.0f;
      s += (double)sm;
    }
  }
  __shared__ double sh[256];
  sh[threadIdx.x] = s;
  __syncthreads();
  for (int o2 = 128; o2 > 0; o2 >>= 1) {
    if (threadIdx.x < o2) sh[threadIdx.x] += sh[threadIdx.x + o2];
    __syncthreads();
  }
  if (threadIdx.x == 0) csum[b * NCH + ch] = sh[0];
}

// ---------------- cumsum phase 2: exclusive scan of chunk sums ----------------
__global__ void cumsum2(double* __restrict__ csum) {
  int b = blockIdx.x;
  if (threadIdx.x == 0) {
    double acc = 0.0;
    for (int ch = 0; ch < NCH; ++ch) {
      double v = csum[b * NCH + ch];
      csum[b * NCH + ch] = acc;
      acc += v;
    }
  }
}

// ---------------- harmonic source ----------------
__global__ __launch_bounds__(256) void harm_kernel(
    const float* __restrict__ fs, const double* __restrict__ csum,
    const float* __restrict__ f0, const float* __restrict__ amps,
    float* __restrict__ harm) {
  int b = blockIdx.y, ch = blockIdx.x;
  const float* fsb = fs + (size_t)b * LW;
  int base = ch * 1024;
  int tid = threadIdx.x;
  double p[4]; double s = 0.0;
  int n0 = base + tid * 4;
  for (int q = 0; q < 4; ++q) {
    int n = n0 + q; float sm = 0.f;
    if (n < LW) sm = (3.14159274101257324f * fsb[n]) / 48000.0f;
    s += (double)sm; p[q] = s;
  }
  __shared__ double sh[256];
  sh[tid] = s; __syncthreads();
  for (int o2 = 1; o2 < 256; o2 <<= 1) {
    double v = (tid >= o2) ? sh[tid - o2] : 0.0;
    __syncthreads();
    sh[tid] += v;
    __syncthreads();
  }
  double excl = csum[b * NCH + ch] + (tid > 0 ? sh[tid - 1] : 0.0);
  const double PID = (double)3.14159274101257324f;
  for (int q = 0; q < 4; ++q) {
    int n = n0 + q; if (n >= LW) break;
    double S = excl + p[q];
    float pixf = (float)fmod(S, PID);
    float fsv = fsb[n];
    float a = rintf(48000.0f / fmaxf(fsv, 20.0f) * 0.5f) * 2.0f + 1.0f;
    float D = (pixf < 1e-8f) ? 1.0f : (sinf(a * pixf) / (a * sinf(pixf)));
    int ui = n / 960;
    float uv = (f0[b * LF + ui] > 20.0f) ? 1.0f : 0.0f;
    float posA = ((float)n + 0.5f) * (200.0f / 192000.0f) - 0.5f;
    posA = fminf(fmaxf(posA, 0.0f), 199.0f);
    int i0 = (int)posA;
    int i1 = min(i0 + 1, 199);
    float w = posA - (float)i0;
    float ampI = amps[b * LF + i0] * (1.0f - w) + amps[b * LF + i1] * w;
    harm[(size_t)b * LW + n] = (D * uv) * ampI;
  }
}

// ---------------- noise, reflect-padded ----------------
__global__ void xp_kernel(float* __restrict__ xp) {
  int idx = blockIdx.x * 256 + threadIdx.x;
  if (idx >= NB * LPADW) return;
  int b = idx / LPADW, j = idx % LPADW;
  int m = j - 1920;
  if (m < 0) m = -m;
  if (m >= LW) m = 2 * LW - 2 - m;
  uint32_t i = (uint32_t)(b * LW + m);
  uint32_t x0 = 0u, x1 = i;
  threefry2x32(0u, 123u, x0, x1);
  uint32_t bits = x0 ^ x1;  // jax partitionable 32-bit combine
  xp[idx] = __uint_as_float((bits >> 9) | 0x3f800000u) - 1.0f;
}

// ================= MFMA DFT path =================
// Twiddle table T32[k2][j]: low16 = bf16 hi of val, high16 = bf16 lo; val =
// (k2 even) cos(2pi*(j*k mod N)/N) else -sin(...), k = k2>>1.
__global__ void twfill(uint32_t* __restrict__ T32, float* __restrict__ WIN) {
  int j = blockIdx.x * 256 + threadIdx.x;   // < 3840 (grid 15 x 3842)
  int k2 = blockIdx.y;
  int k = k2 >> 1;
  int m = (j * k) % NFFT;
  float ang = (float)m * (6.283185307179586f / 3840.0f);
  float val = (k2 & 1) ? -sinf(ang) : cosf(ang);
  unsigned short h = f2bf(val);
  unsigned short l = f2bf(val - bf2f(h));
  T32[(size_t)k2 * NFFT + j] = (uint32_t)h | ((uint32_t)l << 16);
  if (k2 == 0) WIN[j] = winf(j);
}

// fwd NT-GEMM: spec[t,k2] = (sum_j A[t,j]*T[k2,j]) * ker;  A = xp*win (hi/lo split on the fly)
__global__ __launch_bounds__(256) void dft_fwd_mfma(const float* __restrict__ xp,
    const uint32_t* __restrict__ T32, const float* __restrict__ WIN,
    const float* __restrict__ ker, float* __restrict__ spec) {
  __shared__ short Ah[64][40], Al[64][40], Qh[64][40], Ql[64][40];
  int m0 = blockIdx.y * 64, n0 = blockIdx.x * 64;
  int tid = threadIdx.x;
  int lane = tid & 63, w = tid >> 6;
  int wm = w >> 1, wn = w & 1;
  f32x4 acc[2][2];
#pragma unroll
  for (int i = 0; i < 2; ++i)
#pragma unroll
    for (int j = 0; j < 2; ++j) acc[i][j] = (f32x4){0.f, 0.f, 0.f, 0.f};

  int arow = tid >> 2, kc = (tid & 3) * 8;       // 64 rows x 4 thr, 8 elems each
  int t = m0 + arow;
  int bb = t / 200, tt = t - bb * 200;
  const float* xbase = xp + (size_t)bb * LPADW + (size_t)(tt + 1) * FRAME;
  int k2g = n0 + arow;
  const uint32_t* trow = T32 + (size_t)k2g * NFFT;
  bool qv = (k2g < NK2);
  int fr = lane & 15, fk = (lane >> 4) * 8;

  for (int ks = 0; ks < 120; ++ks) {
    int j0 = ks * 32;
#pragma unroll
    for (int c = 0; c < 8; c += 2) {
      int j = j0 + kc + c;
      float v0 = xbase[j] * WIN[j];
      float v1 = xbase[j + 1] * WIN[j + 1];
      unsigned short h0 = f2bf(v0), h1 = f2bf(v1);
      unsigned short l0 = f2bf(v0 - bf2f(h0)), l1 = f2bf(v1 - bf2f(h1));
      *(uint32_t*)&Ah[arow][kc + c] = (uint32_t)h0 | ((uint32_t)h1 << 16);
      *(uint32_t*)&Al[arow][kc + c] = (uint32_t)l0 | ((uint32_t)l1 << 16);
      uint32_t p0 = qv ? trow[j] : 0u;
      uint32_t p1 = qv ? trow[j + 1] : 0u;
      *(uint32_t*)&Qh[arow][kc + c] = (p0 & 0xFFFFu) | ((p1 & 0xFFFFu) << 16);
      *(uint32_t*)&Ql[arow][kc + c] = (p0 >> 16) | ((p1 >> 16) << 16);
    }
    __syncthreads();
    short8v ah0 = *(const short8v*)&Ah[wm * 32 + fr][fk];
    short8v ah1 = *(const short8v*)&Ah[wm * 32 + 16 + fr][fk];
    short8v al0 = *(const short8v*)&Al[wm * 32 + fr][fk];
    short8v al1 = *(const short8v*)&Al[wm * 32 + 16 + fr][fk];
    short8v qh0 = *(const short8v*)&Qh[wn * 32 + fr][fk];
    short8v qh1 = *(const short8v*)&Qh[wn * 32 + 16 + fr][fk];
    short8v ql0 = *(const short8v*)&Ql[wn * 32 + fr][fk];
    short8v ql1 = *(const short8v*)&Ql[wn * 32 + 16 + fr][fk];
    acc[0][0] = __builtin_amdgcn_mfma_f32_16x16x32_bf16(ah0, qh0, acc[0][0], 0, 0, 0);
    acc[0][1] = __builtin_amdgcn_mfma_f32_16x16x32_bf16(ah0, qh1, acc[0][1], 0, 0, 0);
    acc[1][0] = __builtin_amdgcn_mfma_f32_16x16x32_bf16(ah1, qh0, acc[1][0], 0, 0, 0);
    acc[1][1] = __builtin_amdgcn_mfma_f32_16x16x32_bf16(ah1, qh1, acc[1][1], 0, 0, 0);
    acc[0][0] = __builtin_amdgcn_mfma_f32_16x16x32_bf16(ah0, ql0, acc[0][0], 0, 0, 0);
    acc[0][1] = __builtin_amdgcn_mfma_f32_16x16x32_bf16(ah0, ql1, acc[0][1], 0, 0, 0);
    acc[1][0] = __builtin_amdgcn_mfma_f32_16x16x32_bf16(ah1, ql0, acc[1][0], 0, 0, 0);
    acc[1][1] = __builtin_amdgcn_mfma_f32_16x16x32_bf16(ah1, ql1, acc[1][1], 0, 0, 0);
    acc[0][0] = __builtin_amdgcn_mfma_f32_16x16x32_bf16(al0, qh0, acc[0][0], 0, 0, 0);
    acc[0][1] = __builtin_amdgcn_mfma_f32_16x16x32_bf16(al0, qh1, acc[0][1], 0, 0, 0);
    acc[1][0] = __builtin_amdgcn_mfma_f32_16x16x32_bf16(al1, qh0, acc[1][0], 0, 0, 0);
    acc[1][1] = __builtin_amdgcn_mfma_f32_16x16x32_bf16(al1, qh1, acc[1][1], 0, 0, 0);
    __syncthreads();
  }
#pragma unroll
  for (int mi = 0; mi < 2; ++mi)
#pragma unroll
    for (int ni = 0; ni < 2; ++ni)
#pragma unroll
      for (int r = 0; r < 4; ++r) {
        int m = m0 + wm * 32 + mi * 16 + (lane >> 4) * 4 + r;
        int n = n0 + wn * 32 + ni * 16 + (lane & 15);
        if (n < NK2) {
          int k = n >> 1;
          int b2 = m / 200, t2 = m - b2 * 200;
          float kv = ker[((size_t)b2 * NFREQ + k) * LF + t2];
          spec[(size_t)m * NK2 + n] = acc[mi][ni][r] * kv;
        }
      }
}

// inv NN-GEMM: ft[t,j] = (sum_k2 S[t,k2]*T[k2,j]) * win[j];  S = spec * mult (edge imag zeroed)
__global__ __launch_bounds__(256) void dft_inv_mfma(const float* __restrict__ spec,
    const uint32_t* __restrict__ T32, const float* __restrict__ WIN,
    float* __restrict__ ft) {
  __shared__ short Sh[64][40], Sl[64][40];
  __shared__ short Qh[32][68], Ql[32][68];
  int m0 = blockIdx.y * 64, n0 = blockIdx.x * 64;  // n = j
  int tid = threadIdx.x;
  int lane = tid & 63, w = tid >> 6;
  int wm = w >> 1, wn = w & 1;
  f32x4 acc[2][2];
#pragma unroll
  for (int i = 0; i < 2; ++i)
#pragma unroll
    for (int j = 0; j < 2; ++j) acc[i][j] = (f32x4){0.f, 0.f, 0.f, 0.f};

  int srow = tid >> 2, skc = (tid & 3) * 8;  // S: 64 x 32
  int qrow = tid >> 3, qjc = (tid & 7) * 8;  // Q: 32 x 64
  const float* srcrow = spec + (size_t)(m0 + srow) * NK2;
  int fr = lane & 15, fk = (lane >> 4) * 8;

  for (int ks = 0; ks < 121; ++ks) {
    int k20 = ks * 32;
#pragma unroll
    for (int c = 0; c < 8; c += 2) {
      float v0 = 0.f, v1 = 0.f;
      int k2a = k20 + skc + c;
#pragma unroll
      for (int u = 0; u < 2; ++u) {
        int k2 = k2a + u;
        float v = 0.f;
        if (k2 < NK2) {
          int k = k2 >> 1;
          bool edge = (k == 0) || (k == 1920);
          float mult = edge ? (1.0f / NFFT) : (2.0f / NFFT);
          v = srcrow[k2] * mult;
          if ((k2 & 1) && edge) v = 0.f;
        }
        if (u == 0) v0 = v; else v1 = v;
      }
      unsigned short h0 = f2bf(v0), h1 = f2bf(v1);
      unsigned short l0 = f2bf(v0 - bf2f(h0)), l1 = f2bf(v1 - bf2f(h1));
      *(uint32_t*)&Sh[srow][skc + c] = (uint32_t)h0 | ((uint32_t)h1 << 16);
      *(uint32_t*)&Sl[srow][skc + c] = (uint32_t)l0 | ((uint32_t)l1 << 16);
    }
    {
      int k2 = k20 + qrow;
      bool qv = k2 < NK2;
      const uint32_t* trow = T32 + (size_t)k2 * NFFT + n0;
#pragma unroll
      for (int c = 0; c < 8; c += 2) {
        uint32_t p0 = qv ? trow[qjc + c] : 0u;
        uint32_t p1 = qv ? trow[qjc + c + 1] : 0u;
        *(uint32_t*)&Qh[qrow][qjc + c] = (p0 & 0xFFFFu) | ((p1 & 0xFFFFu) << 16);
        *(uint32_t*)&Ql[qrow][qjc + c] = (p0 >> 16) | ((p1 >> 16) << 16);
      }
    }
    __syncthreads();
    short8v sh0 = *(const short8v*)&Sh[wm * 32 + fr][fk];
    short8v sh1 = *(const short8v*)&Sh[wm * 32 + 16 + fr][fk];
    short8v sl0 = *(const short8v*)&Sl[wm * 32 + fr][fk];
    short8v sl1 = *(const short8v*)&Sl[wm * 32 + 16 + fr][fk];
    short8v qhf[2], qlf[2];
#pragma unroll
    for (int ni = 0; ni < 2; ++ni) {
      int ncol = wn * 32 + ni * 16 + fr;
      short8v qh, ql;
#pragma unroll
      for (int i = 0; i < 8; ++i) {
        qh[i] = Qh[fk + i][ncol];
        ql[i] = Ql[fk + i][ncol];
      }
      qhf[ni] = qh; qlf[ni] = ql;
    }
    acc[0][0] = __builtin_amdgcn_mfma_f32_16x16x32_bf16(sh0, qhf[0], acc[0][0], 0, 0, 0);
    acc[0][1] = __builtin_amdgcn_mfma_f32_16x16x32_bf16(sh0, qhf[1], acc[0][1], 0, 0, 0);
    acc[1][0] = __builtin_amdgcn_mfma_f32_16x16x32_bf16(sh1, qhf[0], acc[1][0], 0, 0, 0);
    acc[1][1] = __builtin_amdgcn_mfma_f32_16x16x32_bf16(sh1, qhf[1], acc[1][1], 0, 0, 0);
    acc[0][0] = __builtin_amdgcn_mfma_f32_16x16x32_bf16(sh0, qlf[0], acc[0][0], 0, 0, 0);
    acc[0][1] = __builtin_amdgcn_mfma_f32_16x16x32_bf16(sh0, qlf[1], acc[0][1], 0, 0, 0);
    acc[1][0] = __builtin_amdgcn_mfma_f32_16x16x32_bf16(sh1, qlf[0], acc[1][0], 0, 0, 0);
    acc[1][1] = __builtin_amdgcn_mfma_f32_16x16x32_bf16(sh1, qlf[1], acc[1][1], 0, 0, 0);
    acc[0][0] = __builtin_amdgcn_mfma_f32_16x16x32_bf16(sl0, qhf[0], acc[0][0], 0, 0, 0);
    acc[0][1] = __builtin_amdgcn_mfma_f32_16x16x32_bf16(sl0, qhf[1], acc[0][1], 0, 0, 0);
    acc[1][0] = __builtin_amdgcn_mfma_f32_16x16x32_bf16(sl1, qhf[0], acc[1][0], 0, 0, 0);
    acc[1][1] = __builtin_amdgcn_mfma_f32_16x16x32_bf16(sl1, qhf[1], acc[1][1], 0, 0, 0);
    __syncthreads();
  }
#pragma unroll
  for (int mi = 0; mi < 2; ++mi)
#pragma unroll
    for (int ni = 0; ni < 2; ++ni)
#pragma unroll
      for (int r = 0; r < 4; ++r) {
        int m = m0 + wm * 32 + mi * 16 + (lane >> 4) * 4 + r;
        int n = n0 + wn * 32 + ni * 16 + (lane & 15);
        ft[(size_t)m * NFFT + n] = acc[mi][ni][r] * WIN[n];
      }
}

// ---------------- OLD recurrence DFT (fallback when ws too small) ----------------
__global__ __launch_bounds__(256) void dft_fwd(const float* __restrict__ xp,
                                               const float* __restrict__ ker,
                                               float* __restrict__ spec) {
  int tt = blockIdx.x;
  int b  = blockIdx.y;
  __shared__ float s[NFFT];
  const float* xb = xp + (size_t)b * LPADW + (size_t)(tt + 1) * FRAME;
  for (int j = threadIdx.x; j < NFFT; j += 256) s[j] = xb[j] * winf(j);
  __syncthreads();
  const int NC = 8;
  float wr[NC], wi[NC], cr[NC], ci[NC], re[NC], im[NC];
#pragma unroll
  for (int c = 0; c < NC; ++c) {
    int k = threadIdx.x + 256 * c;
    double th = -6.283185307179586476925286766559 * (double)k / (double)NFFT;
    cr[c] = (float)cos(th); ci[c] = (float)sin(th);
    wr[c] = 1.f; wi[c] = 0.f; re[c] = 0.f; im[c] = 0.f;
  }
  for (int j = 0; j < NFFT; ++j) {
    float v = s[j];
#pragma unroll
    for (int c = 0; c < NC; ++c) {
      re[c] = fmaf(v, wr[c], re[c]);
      im[c] = fmaf(v, wi[c], im[c]);
      float t = fmaf(wr[c], cr[c], -wi[c] * ci[c]);
      wi[c]   = fmaf(wr[c], ci[c],  wi[c] * cr[c]);
      wr[c] = t;
    }
  }
#pragma unroll
  for (int c = 0; c < NC; ++c) {
    int k = threadIdx.x + 256 * c;
    if (k < NFREQ) {
      float kv = ker[((size_t)b * NFREQ + k) * LF + tt];
      size_t o = (((size_t)b * LF + tt) * NFREQ + k) * 2;
      spec[o]     = re[c] * kv;
      spec[o + 1] = im[c] * kv;
    }
  }
}

__global__ __launch_bounds__(256) void dft_inv(const float* __restrict__ spec,
                                               float* __restrict__ ft) {
  int tt = blockIdx.x;
  int b  = blockIdx.y;
  __shared__ float Xre[NFREQ], Xim[NFREQ];
  for (int k = threadIdx.x; k < NFREQ; k += 256) {
    size_t o = (((size_t)b * LF + tt) * NFREQ + k) * 2;
    bool edge = (k == 0 || k == NFFT / 2);
    float mult = edge ? (1.0f / NFFT) : (2.0f / NFFT);
    Xre[k] = spec[o] * mult;
    Xim[k] = edge ? 0.f : spec[o + 1] * mult;
  }
  __syncthreads();
  const int NC = 15;
  float wr[NC], wi[NC], cr[NC], ci[NC], acc[NC];
#pragma unroll
  for (int c = 0; c < NC; ++c) {
    int j = threadIdx.x + 256 * c;
    double th = 6.283185307179586476925286766559 * (double)j / (double)NFFT;
    cr[c] = (float)cos(th); ci[c] = (float)sin(th);
    wr[c] = 1.f; wi[c] = 0.f; acc[c] = 0.f;
  }
  for (int k = 0; k < NFREQ; ++k) {
    float xr = Xre[k], xi = Xim[k];
#pragma unroll
    for (int c = 0; c < NC; ++c) {
      acc[c] = fmaf(xr, wr[c], acc[c]);
      acc[c] = fmaf(-xi, wi[c], acc[c]);
      float t = fmaf(wr[c], cr[c], -wi[c] * ci[c]);
      wi[c]   = fmaf(wr[c], ci[c],  wi[c] * cr[c]);
      wr[c] = t;
    }
  }
#pragma unroll
  for (int c = 0; c < NC; ++c) {
    int j = threadIdx.x + 256 * c;
    ft[((size_t)b * LF + tt) * NFFT + j] = acc[c] * winf(j);
  }
}

// ---------------- OLA + wn normalize + add harm (in place -> dsp) ----------------
__global__ void ola_kernel(const float* __restrict__ ft, float* __restrict__ dsp) {
  int idx = blockIdx.x * 256 + threadIdx.x;
  if (idx >= NB * LW) return;
  int b = idx / LW, n = idx % LW;
  int p = n + 1920;
  int t0 = (p > 3839) ? ((p - 2880) / 960) : 0;
  int t1 = p / FRAME; if (t1 > 200) t1 = 200;
  float y = 0.f, wn = 0.f;
  for (int t = t0; t <= t1; ++t) {
    int j = p - FRAME * t;
    float w = winf(j);
    wn += w * w;
    if (t >= 1) y += ft[((size_t)b * LF + (t - 1)) * NFFT + j];
  }
  float den = wn > 1e-11f ? wn : 1.0f;
  dsp[idx] = dsp[idx] + y / den;
}

// ---------------- per-frame 1024-tap correlation ----------------
__global__ __launch_bounds__(256) void fir_kernel(const float* __restrict__ dsp,
                                                  const float* __restrict__ filt,
                                                  float* __restrict__ outf) {
  int t = blockIdx.x, b = blockIdx.y;
  __shared__ float fr[FRAME];
  __shared__ float fl[NWIN];
  for (int i = threadIdx.x; i < FRAME; i += 256) fr[i] = dsp[(size_t)b * LW + (size_t)t * FRAME + i];
  for (int i = threadIdx.x; i < NWIN; i += 256)  fl[i] = filt[((size_t)b * LF + t) * NWIN + i];
  __syncthreads();
  for (int i = threadIdx.x; i < FRAME + NWIN; i += 256) {
    int m0 = i - NWIN;
    int tau0 = m0 < 0 ? -m0 : 0;
    int tau1 = FRAME - m0; if (tau1 > NWIN) tau1 = NWIN;
    float acc = 0.f;
    for (int tau = tau0; tau < tau1; ++tau) acc = fmaf(fr[m0 + tau], fl[tau], acc);
    outf[((size_t)b * LF + t) * (FRAME + NWIN) + i] = acc;
  }
}

// ---------------- fold frames (stride 960) into output ----------------
__global__ void fold_kernel(const float* __restrict__ outf, float* __restrict__ out) {
  int idx = blockIdx.x * 256 + threadIdx.x;
  if (idx >= NB * LW) return;
  int b = idx / LW, n = idx % LW;
  int t0 = (n >= 1984) ? ((n - 1024) / 960) : 0;
  int t1 = n / 960; if (t1 > 199) t1 = 199;
  float acc = 0.f;
  for (int t = t0; t <= t1; ++t)
    acc += outf[((size_t)b * LF + t) * (FRAME + NWIN) + (n - 960 * t)];
  out[idx] = acc;
}

extern "C" void kernel_launch(void* const* d_in, const int* in_sizes, int n_in,
                              void* d_out, int out_size, void* d_ws, size_t ws_size,
                              hipStream_t stream) {
  const float* content    = (const float*)d_in[0];
  const float* f0         = (const float*)d_in[1];
  const float* energy     = (const float*)d_in[2];
  const float* spk        = (const float*)d_in[3];
  const float* s_in_w     = (const float*)d_in[4];
  const float* s_in_b     = (const float*)d_in[5];
  const float* s_dw_w     = (const float*)d_in[6];
  const float* s_dw_b     = (const float*)d_in[7];
  const float* s_ln       = (const float*)d_in[8];
  const float* s_pw1_w    = (const float*)d_in[9];
  const float* s_pw1_b    = (const float*)d_in[10];
  const float* s_pw2_w    = (const float*)d_in[11];
  const float* s_pw2_b    = (const float*)d_in[12];
  const float* s_out_norm = (const float*)d_in[13];
  const float* f_in_w     = (const float*)d_in[14];
  const float* f_in_b     = (const float*)d_in[15];
  const float* f_dw_w     = (const float*)d_in[16];
  const float* f_dw_b     = (const float*)d_in[17];
  const float* f_ln       = (const float*)d_in[18];
  const float* f_pw1_w    = (const float*)d_in[19];
  const float* f_pw1_b    = (const float*)d_in[20];
  const float* f_pw2_w    = (const float*)d_in[21];
  const float* f_pw2_b    = (const float*)d_in[22];
  const float* f_out_norm = (const float*)d_in[23];
  const float* s_in_norm  = (const float*)d_in[24];
  const float* s_amp_w    = (const float*)d_in[25];
  const float* s_amp_b    = (const float*)d_in[26];
  const float* s_ker_w    = (const float*)d_in[27];
  const float* s_ker_b    = (const float*)d_in[28];
  const float* f_out_w    = (const float*)d_in[29];
  const float* f_out_b    = (const float*)d_in[30];

  // ---- workspace layout (f64 csum first for alignment) ----
  double* CSUM = (double*)d_ws;
  float* FP   = (float*)((char*)d_ws + 12032);   // NB*NCH=1504 doubles
  float* XIN  = FP;                  // 720000
  float* XS   = XIN  + 720000;       // 819200
  float* T512 = XS   + 819200;       // 819200
  float* H15  = T512 + 819200;       // 2457600
  float* KER  = H15  + 2457600;      // 3073600
  float* AMPS = KER  + 3073600;      // 1600
  float* FILT = AMPS + 1600;         // 1638400  (B,200,1024)
  float* FS   = FILT + 1638400;      // 1536000
  float* HARM = FS   + 1536000;      // 1536000  (becomes dsp)
  float* XP   = HARM + 1536000;      // 1566720
  float* SPEC = XP   + 1566720;      // 6147200  (also im2col: 5734400)
  float* FT   = SPEC + 6147200;      // 6144000
  float* OUTF = FT   + 6144000;      // 3174400
  float* IM   = SPEC;                // im2col overlay (used before SPEC)
  // MFMA-DFT extras (only if workspace permits)
  uint32_t* T32 = (uint32_t*)(OUTF + 3174400);   // 14,753,280 u32 = 59.0 MB
  float* WIN    = (float*)(T32 + (size_t)NK2 * NFFT);  // 3840 floats
  size_t need_mfma = 12032ull + 29633920ull * 4 + (size_t)NK2 * NFFT * 4 + NFFT * 4;
  bool use_mfma = ws_size >= need_mfma;

  (void)in_sizes; (void)n_in; (void)out_size;

  build_xin<<<dim3((NB * CIN * LF + 255) / 256), 256, 0, stream>>>(content, f0, energy, spk, XIN);

  auto run_trunk = [&](const float* in_w, const float* in_b, const float* in_norm,
                       const float* dw_w, const float* dw_b, const float* lnp,
                       const float* pw1_w, const float* pw1_b,
                       const float* pw2_w, const float* pw2_b,
                       const float* out_norm) {
    gemm_act<<<dim3(4, 8, NB), 256, 0, stream>>>(in_w, XIN, in_b, nullptr, XS,
        CI, CIN, LF, 0, (long long)CI * LF, LF, 1);
    if (in_norm)
      ln_kernel<<<dim3(4, NB), 256, 0, stream>>>(XS, in_norm, in_norm + CI);
    for (int i = 0; i < NL; ++i) {
      dwconv_kernel<<<dim3((NB * CI * LF + 255) / 256), 256, 0, stream>>>(
          XS, dw_w + (size_t)i * CI * 7, dw_b + (size_t)i * CI, T512);
      ln_kernel<<<dim3(4, NB), 256, 0, stream>>>(T512, lnp + (size_t)(i * 2) * CI, lnp + (size_t)(i * 2 + 1) * CI);
      gemm_act<<<dim3(4, HID / 64, NB), 256, 0, stream>>>(
          pw1_w + (size_t)i * HID * CI, T512, pw1_b + (size_t)i * HID, nullptr, H15,
          HID, CI, LF, 1, (long long)HID * LF, LF, 1);
      gemm_act<<<dim3(4, CI / 64, NB), 256, 0, stream>>>(
          pw2_w + (size_t)i * CI * HID, H15, pw2_b + (size_t)i * CI, XS, XS,
          CI, HID, LF, 0, (long long)CI * LF, LF, 1);
    }
    ln_kernel<<<dim3(4, NB), 256, 0, stream>>>(XS, out_norm, out_norm + CI);
  };

  // ---- source trunk ----
  run_trunk(s_in_w, s_in_b, s_in_norm, s_dw_w, s_dw_b, s_ln,
            s_pw1_w, s_pw1_b, s_pw2_w, s_pw2_b, s_out_norm);
  amps_kernel<<<dim3(NB), 256, 0, stream>>>(XS, s_amp_w, s_amp_b, AMPS);
  gemm_act<<<dim3(4, (NFREQ + 63) / 64, NB), 256, 0, stream>>>(
      s_ker_w, XS, s_ker_b, nullptr, KER, NFREQ, CI, LF, 2, (long long)NFREQ * LF, LF, 1);

  // ---- filter trunk (no input norm) ----
  run_trunk(f_in_w, f_in_b, nullptr, f_dw_w, f_dw_b, f_ln,
            f_pw1_w, f_pw1_b, f_pw2_w, f_pw2_b, f_out_norm);
  im2col_kernel<<<dim3((NB * 3584 * LF + 255) / 256), 256, 0, stream>>>(XS, IM);
  gemm_act<<<dim3(4, NWIN / 64, NB), 256, 0, stream>>>(
      f_out_w, IM, f_out_b, nullptr, FILT, NWIN, 3584, LF, 0,
      (long long)LF * NWIN, 1LL, (long long)NWIN);

  // ---- harmonic source ----
  fs_kernel<<<dim3((NB * LW + 255) / 256), 256, 0, stream>>>(f0, FS);
  cumsum1<<<dim3(NCH, NB), 256, 0, stream>>>(FS, CSUM);
  cumsum2<<<dim3(NB), 64, 0, stream>>>(CSUM);
  harm_kernel<<<dim3(NCH, NB), 256, 0, stream>>>(FS, CSUM, f0, AMPS, HARM);

  // ---- filtered noise ----
  xp_kernel<<<dim3((NB * LPADW + 255) / 256), 256, 0, stream>>>(XP);
  if (use_mfma) {
    twfill<<<dim3(15, NK2), 256, 0, stream>>>(T32, WIN);
    dft_fwd_mfma<<<dim3((NK2 + 63) / 64, MTOT / 64), 256, 0, stream>>>(XP, T32, WIN, KER, SPEC);
    dft_inv_mfma<<<dim3(NFFT / 64, MTOT / 64), 256, 0, stream>>>(SPEC, T32, WIN, FT);
  } else {
    dft_fwd<<<dim3(LF, NB), 256, 0, stream>>>(XP, KER, SPEC);
    dft_inv<<<dim3(LF, NB), 256, 0, stream>>>(SPEC, FT);
  }
  ola_kernel<<<dim3((NB * LW + 255) / 256), 256, 0, stream>>>(FT, HARM);  // HARM -> dsp

  // ---- time-varying FIR + fold ----
  fir_kernel<<<dim3(LF, NB), 256, 0, stream>>>(HARM, FILT, OUTF);
  fold_kernel<<<dim3((NB * LW + 255) / 256), 256, 0, stream>>>(OUTF, (float*)d_out);
}

// Round 5
// 5568.784 us; speedup vs baseline: 3.1081x; 1.4481x over previous
//
#include <hip/hip_runtime.h>
#include <hip/hip_bf16.h>
#include <math.h>
#include <stdint.h>

#define FRAME 960
#define NFFT  3840
#define NWIN  1024
#define NFREQ 1921
#define NB    8
#define LF    200
#define LW    192000
#define LPADW 195840
#define CIN   450
#define CI    512
#define HID   1536
#define NL    6
#define NCH   188   // ceil(192000/1024)
#define NK2   3842  // 2*NFREQ columns (re/im interleaved)
#define MTOT  1600  // NB*LF frames (flattened row dim)

typedef __attribute__((ext_vector_type(8))) short short8v;
typedef __attribute__((ext_vector_type(4))) float f32x4;

// ---------------- threefry (JAX partitionable variant) ----------------
__device__ __forceinline__ uint32_t rotl32(uint32_t v, int r) { return (v << r) | (v >> (32 - r)); }

__device__ __forceinline__ void threefry2x32(uint32_t k0, uint32_t k1, uint32_t& x0, uint32_t& x1) {
  uint32_t ks2 = k0 ^ k1 ^ 0x1BD11BDAu;
  x0 += k0; x1 += k1;
#define TFR(r) { x0 += x1; x1 = rotl32(x1, r); x1 ^= x0; }
  TFR(13) TFR(15) TFR(26) TFR(6)  x0 += k1;  x1 += ks2 + 1u;
  TFR(17) TFR(29) TFR(16) TFR(24) x0 += ks2; x1 += k0 + 2u;
  TFR(13) TFR(15) TFR(26) TFR(6)  x0 += k0;  x1 += k1 + 3u;
  TFR(17) TFR(29) TFR(16) TFR(24) x0 += k1;  x1 += ks2 + 4u;
  TFR(13) TFR(15) TFR(26) TFR(6)  x0 += ks2; x1 += k0 + 5u;
#undef TFR
}

__device__ __forceinline__ float winf(int j) {
  return 0.5f - 0.5f * cosf((6.283185307179586f * (float)j) / 3840.0f);
}

// bf16 round-to-nearest-even helpers
__device__ __forceinline__ unsigned short f2bf(float v) {
  uint32_t b = __float_as_uint(v);
  return (unsigned short)((b + 0x7FFFu + ((b >> 16) & 1u)) >> 16);
}
__device__ __forceinline__ float bf2f(unsigned short h) {
  return __uint_as_float(((uint32_t)h) << 16);
}

// XCD-bijective chunked remap (m204): lin in [0,nwg) -> wg, contiguous chunks per XCD
__device__ __forceinline__ int xcd_remap(int lin, int nwg) {
  int q = nwg >> 3, r = nwg & 7;
  int xcd = lin & 7, base = lin >> 3;
  int start = (xcd < r) ? xcd * (q + 1) : r * (q + 1) + (xcd - r) * q;
  return start + base;
}

// ---------------- xin (B,L,450) ----------------
__global__ void build_xin(const float* __restrict__ content, const float* __restrict__ f0,
                          const float* __restrict__ energy, const float* __restrict__ spk,
                          float* __restrict__ xin) {
  int idx = blockIdx.x * 256 + threadIdx.x;
  if (idx >= MTOT * CIN) return;
  int row = idx / CIN, c = idx % CIN;
  int b = row / LF, l = row % LF;
  float v;
  if (c < 192)       v = content[((size_t)b * 192 + c) * LF + l];
  else if (c < 448)  v = spk[b * 256 + (c - 192)];
  else if (c == 448) v = logf(fmaxf(f0[b * LF + l], 0.0f) + 1e-6f);
  else               v = energy[b * LF + l];
  xin[idx] = v;
}

// ---------------- MFMA hi/lo GEMM: out[n,m] = act(sum_k W[m,k]*X[n,k] + bias[m]) (+res) ----------------
// X,out,res are (1600, K/M) row-major. grid (25, mtiles).
__global__ __launch_bounds__(256) void mm_hilo(
    const float* __restrict__ W, const float* __restrict__ X,
    const float* __restrict__ bias, const float* __restrict__ res,
    float* __restrict__ out, int M, int K, int act)
{
  __shared__ short Wh[64][40], Wl[64][40], Xh[64][40], Xl[64][40];
  int lin = blockIdx.x + blockIdx.y * 25;
  int nwg = 25 * gridDim.y;
  int wg = xcd_remap(lin, nwg);
  int mtile = wg / 25, ntile = wg % 25;   // n-inner: W-tile stays L2-resident
  int m0 = mtile * 64, n0 = ntile * 64;
  int tid = threadIdx.x;
  int lane = tid & 63, w = tid >> 6;
  int wm = w >> 1, wn = w & 1;
  f32x4 acc[2][2];
#pragma unroll
  for (int i = 0; i < 2; ++i)
#pragma unroll
    for (int j = 0; j < 2; ++j) acc[i][j] = (f32x4){0.f, 0.f, 0.f, 0.f};

  int row = tid >> 2, kc = (tid & 3) * 8;
  bool wv = (m0 + row) < M;
  const float* wrow = W + (size_t)(m0 + row) * K;
  const float* xrow = X + (size_t)(n0 + row) * K;
  int fr = lane & 15, fk = (lane >> 4) * 8;
  int phases = (K + 31) / 32;

  for (int ks = 0; ks < phases; ++ks) {
    int k0 = ks * 32;
#pragma unroll
    for (int c = 0; c < 8; c += 2) {
      int k = k0 + kc + c;
      float w0 = (wv && k < K) ? wrow[k] : 0.f;
      float w1 = (wv && (k + 1) < K) ? wrow[k + 1] : 0.f;
      unsigned short h0 = f2bf(w0), h1 = f2bf(w1);
      unsigned short l0 = f2bf(w0 - bf2f(h0)), l1 = f2bf(w1 - bf2f(h1));
      *(uint32_t*)&Wh[row][kc + c] = (uint32_t)h0 | ((uint32_t)h1 << 16);
      *(uint32_t*)&Wl[row][kc + c] = (uint32_t)l0 | ((uint32_t)l1 << 16);
      float x0 = (k < K) ? xrow[k] : 0.f;
      float x1 = ((k + 1) < K) ? xrow[k + 1] : 0.f;
      unsigned short xh0 = f2bf(x0), xh1 = f2bf(x1);
      unsigned short xl0 = f2bf(x0 - bf2f(xh0)), xl1 = f2bf(x1 - bf2f(xh1));
      *(uint32_t*)&Xh[row][kc + c] = (uint32_t)xh0 | ((uint32_t)xh1 << 16);
      *(uint32_t*)&Xl[row][kc + c] = (uint32_t)xl0 | ((uint32_t)xl1 << 16);
    }
    __syncthreads();
    short8v ah0 = *(const short8v*)&Wh[wm * 32 + fr][fk];
    short8v ah1 = *(const short8v*)&Wh[wm * 32 + 16 + fr][fk];
    short8v al0 = *(const short8v*)&Wl[wm * 32 + fr][fk];
    short8v al1 = *(const short8v*)&Wl[wm * 32 + 16 + fr][fk];
    short8v bh0 = *(const short8v*)&Xh[wn * 32 + fr][fk];
    short8v bh1 = *(const short8v*)&Xh[wn * 32 + 16 + fr][fk];
    short8v bl0 = *(const short8v*)&Xl[wn * 32 + fr][fk];
    short8v bl1 = *(const short8v*)&Xl[wn * 32 + 16 + fr][fk];
    acc[0][0] = __builtin_amdgcn_mfma_f32_16x16x32_bf16(ah0, bh0, acc[0][0], 0, 0, 0);
    acc[0][1] = __builtin_amdgcn_mfma_f32_16x16x32_bf16(ah0, bh1, acc[0][1], 0, 0, 0);
    acc[1][0] = __builtin_amdgcn_mfma_f32_16x16x32_bf16(ah1, bh0, acc[1][0], 0, 0, 0);
    acc[1][1] = __builtin_amdgcn_mfma_f32_16x16x32_bf16(ah1, bh1, acc[1][1], 0, 0, 0);
    acc[0][0] = __builtin_amdgcn_mfma_f32_16x16x32_bf16(ah0, bl0, acc[0][0], 0, 0, 0);
    acc[0][1] = __builtin_amdgcn_mfma_f32_16x16x32_bf16(ah0, bl1, acc[0][1], 0, 0, 0);
    acc[1][0] = __builtin_amdgcn_mfma_f32_16x16x32_bf16(ah1, bl0, acc[1][0], 0, 0, 0);
    acc[1][1] = __builtin_amdgcn_mfma_f32_16x16x32_bf16(ah1, bl1, acc[1][1], 0, 0, 0);
    acc[0][0] = __builtin_amdgcn_mfma_f32_16x16x32_bf16(al0, bh0, acc[0][0], 0, 0, 0);
    acc[0][1] = __builtin_amdgcn_mfma_f32_16x16x32_bf16(al0, bh1, acc[0][1], 0, 0, 0);
    acc[1][0] = __builtin_amdgcn_mfma_f32_16x16x32_bf16(al1, bh0, acc[1][0], 0, 0, 0);
    acc[1][1] = __builtin_amdgcn_mfma_f32_16x16x32_bf16(al1, bh1, acc[1][1], 0, 0, 0);
    __syncthreads();
  }
#pragma unroll
  for (int mi = 0; mi < 2; ++mi)
#pragma unroll
    for (int ni = 0; ni < 2; ++ni)
#pragma unroll
      for (int r = 0; r < 4; ++r) {
        int m = m0 + wm * 32 + mi * 16 + (lane >> 4) * 4 + r;
        int n = n0 + wn * 32 + ni * 16 + (lane & 15);
        if (m < M) {
          float v = acc[mi][ni][r] + (bias ? bias[m] : 0.f);
          if (act == 1)      v = 0.5f * v * (1.0f + erff(v * 0.7071067811865475f));
          else if (act == 2) v = (v > 0.f ? v : expm1f(v)) + 1.0f;
          size_t o = (size_t)n * M + m;
          if (res) v += res[o];
          out[o] = v;
        }
      }
}

// ---------------- channel LayerNorm on (1600, CI) rows, in-place ----------------
__global__ __launch_bounds__(256) void ln2_kernel(float* __restrict__ x, const float* __restrict__ g,
                                                  const float* __restrict__ bta) {
  int row = blockIdx.x * 4 + (threadIdx.x >> 6);
  int lane = threadIdx.x & 63;
  float* xr = x + (size_t)row * CI;
  int c0 = lane * 8;
  float4 v0 = *(float4*)&xr[c0], v1 = *(float4*)&xr[c0 + 4];
  float s = v0.x + v0.y + v0.z + v0.w + v1.x + v1.y + v1.z + v1.w;
#pragma unroll
  for (int m = 1; m < 64; m <<= 1) s += __shfl_xor(s, m, 64);
  float mean = s * (1.0f / CI);
  float d0 = v0.x - mean, d1 = v0.y - mean, d2 = v0.z - mean, d3 = v0.w - mean;
  float d4 = v1.x - mean, d5 = v1.y - mean, d6 = v1.z - mean, d7 = v1.w - mean;
  float s2 = d0*d0 + d1*d1 + d2*d2 + d3*d3 + d4*d4 + d5*d5 + d6*d6 + d7*d7;
#pragma unroll
  for (int m = 1; m < 64; m <<= 1) s2 += __shfl_xor(s2, m, 64);
  float rs = rsqrtf(s2 * (1.0f / CI) + 1e-5f);
  float4 g0 = *(const float4*)&g[c0], g1 = *(const float4*)&g[c0 + 4];
  float4 b0 = *(const float4*)&bta[c0], b1 = *(const float4*)&bta[c0 + 4];
  float4 o0, o1;
  o0.x = d0 * rs * g0.x + b0.x; o0.y = d1 * rs * g0.y + b0.y;
  o0.z = d2 * rs * g0.z + b0.z; o0.w = d3 * rs * g0.w + b0.w;
  o1.x = d4 * rs * g1.x + b1.x; o1.y = d5 * rs * g1.y + b1.y;
  o1.z = d6 * rs * g1.z + b1.z; o1.w = d7 * rs * g1.w + b1.w;
  *(float4*)&xr[c0] = o0; *(float4*)&xr[c0 + 4] = o1;
}

// ---------------- depthwise conv K=7 on (B,L,C) layout ----------------
__global__ void dwconv2_kernel(const float* __restrict__ x, const float* __restrict__ w,
                               const float* __restrict__ bias, float* __restrict__ out) {
  int idx = blockIdx.x * 256 + threadIdx.x;
  if (idx >= MTOT * CI) return;
  int row = idx / CI, c = idx % CI;
  int b = row / LF, l = row % LF;
  float acc = bias[c];
#pragma unroll
  for (int tau = 0; tau < 7; ++tau) {
    int j = l + tau - 3;
    if (j >= 0 && j < LF)
      acc = fmaf(x[((size_t)b * LF + j) * CI + c], w[c * 7 + tau], acc);
  }
  out[idx] = acc;
}

// ---------------- amps head on (1600, CI) rows ----------------
__global__ __launch_bounds__(256) void amps2_kernel(const float* __restrict__ x, const float* __restrict__ w,
                                                    const float* __restrict__ bias, float* __restrict__ amps) {
  int row = blockIdx.x * 4 + (threadIdx.x >> 6);
  int lane = threadIdx.x & 63;
  const float* xr = x + (size_t)row * CI;
  int c0 = lane * 8;
  float4 v0 = *(const float4*)&xr[c0], v1 = *(const float4*)&xr[c0 + 4];
  float4 w0 = *(const float4*)&w[c0], w1 = *(const float4*)&w[c0 + 4];
  float s = v0.x*w0.x + v0.y*w0.y + v0.z*w0.z + v0.w*w0.w
          + v1.x*w1.x + v1.y*w1.y + v1.z*w1.z + v1.w*w1.w;
#pragma unroll
  for (int m = 1; m < 64; m <<= 1) s += __shfl_xor(s, m, 64);
  if (lane == 0) {
    float a = s + bias[0];
    amps[row] = (a > 0.f ? a : expm1f(a)) + 1.0f;
  }
}

// ---------------- im2col (edge pad 3) -> IM (1600, 3584), kappa = c*7+tau ----------------
__global__ void im2col2_kernel(const float* __restrict__ x, float* __restrict__ im) {
  int idx = blockIdx.x * 256 + threadIdx.x;
  if (idx >= MTOT * 3584) return;
  int row = idx / 3584, kap = idx % 3584;
  int b = row / LF, l = row % LF;
  int c = kap / 7, tau = kap % 7;
  int j = l + tau - 3;
  j = j < 0 ? 0 : (j > LF - 1 ? LF - 1 : j);
  im[idx] = x[((size_t)b * LF + j) * CI + c];
}

// ---------------- f0 linear interp to LW ----------------
__global__ void fs_kernel(const float* __restrict__ f0, float* __restrict__ fs) {
  int idx = blockIdx.x * 256 + threadIdx.x;
  if (idx >= NB * LW) return;
  int b = idx / LW, n = idx % LW;
  float pos = ((float)n + 0.5f) * (200.0f / 192000.0f) - 0.5f;
  pos = fminf(fmaxf(pos, 0.0f), 199.0f);
  int i0 = (int)pos;
  int i1 = min(i0 + 1, 199);
  float w = pos - (float)i0;
  fs[idx] = f0[b * LF + i0] * (1.0f - w) + f0[b * LF + i1] * w;
}

// ---------------- cumsum phase 1: per-chunk f64 sums ----------------
__global__ __launch_bounds__(256) void cumsum1(const float* __restrict__ fs, double* __restrict__ csum) {
  int b = blockIdx.y, ch = blockIdx.x;
  const float* fsb = fs + (size_t)b * LW;
  int base = ch * 1024;
  double s = 0.0;
  for (int q = 0; q < 4; ++q) {
    int n = base + threadIdx.x * 4 + q;
    if (n < LW) {
      float sm = (3.14159274101257324f * fsb[n]) / 48000.0f;
      s += (double)sm;
    }
  }
  __shared__ double sh[256];
  sh[threadIdx.x] = s;
  __syncthreads();
  for (int o2 = 128; o2 > 0; o2 >>= 1) {
    if (threadIdx.x < o2) sh[threadIdx.x] += sh[threadIdx.x + o2];
    __syncthreads();
  }
  if (threadIdx.x == 0) csum[b * NCH + ch] = sh[0];
}

// ---------------- cumsum phase 2 ----------------
__global__ void cumsum2(double* __restrict__ csum) {
  int b = blockIdx.x;
  if (threadIdx.x == 0) {
    double acc = 0.0;
    for (int ch = 0; ch < NCH; ++ch) {
      double v = csum[b * NCH + ch];
      csum[b * NCH + ch] = acc;
      acc += v;
    }
  }
}

// ---------------- harmonic source ----------------
__global__ __launch_bounds__(256) void harm_kernel(
    const float* __restrict__ fs, const double* __restrict__ csum,
    const float* __restrict__ f0, const float* __restrict__ amps,
    float* __restrict__ harm) {
  int b = blockIdx.y, ch = blockIdx.x;
  const float* fsb = fs + (size_t)b * LW;
  int base = ch * 1024;
  int tid = threadIdx.x;
  double p[4]; double s = 0.0;
  int n0 = base + tid * 4;
  for (int q = 0; q < 4; ++q) {
    int n = n0 + q; float sm = 0.f;
    if (n < LW) sm = (3.14159274101257324f * fsb[n]) / 48000.0f;
    s += (double)sm; p[q] = s;
  }
  __shared__ double sh[256];
  sh[tid] = s; __syncthreads();
  for (int o2 = 1; o2 < 256; o2 <<= 1) {
    double v = (tid >= o2) ? sh[tid - o2] : 0.0;
    __syncthreads();
    sh[tid] += v;
    __syncthreads();
  }
  double excl = csum[b * NCH + ch] + (tid > 0 ? sh[tid - 1] : 0.0);
  const double PID = (double)3.14159274101257324f;
  for (int q = 0; q < 4; ++q) {
    int n = n0 + q; if (n >= LW) break;
    double S = excl + p[q];
    float pixf = (float)fmod(S, PID);
    float fsv = fsb[n];
    float a = rintf(48000.0f / fmaxf(fsv, 20.0f) * 0.5f) * 2.0f + 1.0f;
    float D = (pixf < 1e-8f) ? 1.0f : (sinf(a * pixf) / (a * sinf(pixf)));
    int ui = n / 960;
    float uv = (f0[b * LF + ui] > 20.0f) ? 1.0f : 0.0f;
    float posA = ((float)n + 0.5f) * (200.0f / 192000.0f) - 0.5f;
    posA = fminf(fmaxf(posA, 0.0f), 199.0f);
    int i0 = (int)posA;
    int i1 = min(i0 + 1, 199);
    float w = posA - (float)i0;
    float ampI = amps[b * LF + i0] * (1.0f - w) + amps[b * LF + i1] * w;
    harm[(size_t)b * LW + n] = (D * uv) * ampI;
  }
}

// ---------------- noise, reflect-padded ----------------
__global__ void xp_kernel(float* __restrict__ xp) {
  int idx = blockIdx.x * 256 + threadIdx.x;
  if (idx >= NB * LPADW) return;
  int b = idx / LPADW, j = idx % LPADW;
  int m = j - 1920;
  if (m < 0) m = -m;
  if (m >= LW) m = 2 * LW - 2 - m;
  uint32_t i = (uint32_t)(b * LW + m);
  uint32_t x0 = 0u, x1 = i;
  threefry2x32(0u, 123u, x0, x1);
  uint32_t bits = x0 ^ x1;
  xp[idx] = __uint_as_float((bits >> 9) | 0x3f800000u) - 1.0f;
}

// ================= MFMA DFT path =================
__global__ void twfill(uint32_t* __restrict__ T32, float* __restrict__ WIN) {
  int j = blockIdx.x * 256 + threadIdx.x;
  int k2 = blockIdx.y;
  int k = k2 >> 1;
  int m = (j * k) % NFFT;
  float ang = (float)m * (6.283185307179586f / 3840.0f);
  float val = (k2 & 1) ? -sinf(ang) : cosf(ang);
  unsigned short h = f2bf(val);
  unsigned short l = f2bf(val - bf2f(h));
  T32[(size_t)k2 * NFFT + j] = (uint32_t)h | ((uint32_t)l << 16);
  if (k2 == 0) WIN[j] = winf(j);
}

// fwd NT-GEMM: spec[t,k2] = (sum_j A[t,j]*T[k2,j]) * ker[t,k]
__global__ __launch_bounds__(256) void dft_fwd_mfma(const float* __restrict__ xp,
    const uint32_t* __restrict__ T32, const float* __restrict__ WIN,
    const float* __restrict__ ker, float* __restrict__ spec) {
  __shared__ short Ah[64][40], Al[64][40], Qh[64][40], Ql[64][40];
  int lin = blockIdx.x + blockIdx.y * gridDim.x;
  int wg = xcd_remap(lin, 61 * 25);
  int ntile = wg / 25, mtile = wg % 25;   // m-inner: T-tile stays L2-resident
  int m0 = mtile * 64, n0 = ntile * 64;
  int tid = threadIdx.x;
  int lane = tid & 63, w = tid >> 6;
  int wm = w >> 1, wn = w & 1;
  f32x4 acc[2][2];
#pragma unroll
  for (int i = 0; i < 2; ++i)
#pragma unroll
    for (int j = 0; j < 2; ++j) acc[i][j] = (f32x4){0.f, 0.f, 0.f, 0.f};

  int arow = tid >> 2, kc = (tid & 3) * 8;
  int t = m0 + arow;
  int bb = t / 200, tt = t - bb * 200;
  const float* xbase = xp + (size_t)bb * LPADW + (size_t)(tt + 1) * FRAME;
  int k2g = n0 + arow;
  const uint32_t* trow = T32 + (size_t)k2g * NFFT;
  bool qv = (k2g < NK2);
  int fr = lane & 15, fk = (lane >> 4) * 8;

  for (int ks = 0; ks < 120; ++ks) {
    int j0 = ks * 32;
#pragma unroll
    for (int c = 0; c < 8; c += 2) {
      int j = j0 + kc + c;
      float v0 = xbase[j] * WIN[j];
      float v1 = xbase[j + 1] * WIN[j + 1];
      unsigned short h0 = f2bf(v0), h1 = f2bf(v1);
      unsigned short l0 = f2bf(v0 - bf2f(h0)), l1 = f2bf(v1 - bf2f(h1));
      *(uint32_t*)&Ah[arow][kc + c] = (uint32_t)h0 | ((uint32_t)h1 << 16);
      *(uint32_t*)&Al[arow][kc + c] = (uint32_t)l0 | ((uint32_t)l1 << 16);
      uint32_t p0 = qv ? trow[j] : 0u;
      uint32_t p1 = qv ? trow[j + 1] : 0u;
      *(uint32_t*)&Qh[arow][kc + c] = (p0 & 0xFFFFu) | ((p1 & 0xFFFFu) << 16);
      *(uint32_t*)&Ql[arow][kc + c] = (p0 >> 16) | ((p1 >> 16) << 16);
    }
    __syncthreads();
    short8v ah0 = *(const short8v*)&Ah[wm * 32 + fr][fk];
    short8v ah1 = *(const short8v*)&Ah[wm * 32 + 16 + fr][fk];
    short8v al0 = *(const short8v*)&Al[wm * 32 + fr][fk];
    short8v al1 = *(const short8v*)&Al[wm * 32 + 16 + fr][fk];
    short8v qh0 = *(const short8v*)&Qh[wn * 32 + fr][fk];
    short8v qh1 = *(const short8v*)&Qh[wn * 32 + 16 + fr][fk];
    short8v ql0 = *(const short8v*)&Ql[wn * 32 + fr][fk];
    short8v ql1 = *(const short8v*)&Ql[wn * 32 + 16 + fr][fk];
    acc[0][0] = __builtin_amdgcn_mfma_f32_16x16x32_bf16(ah0, qh0, acc[0][0], 0, 0, 0);
    acc[0][1] = __builtin_amdgcn_mfma_f32_16x16x32_bf16(ah0, qh1, acc[0][1], 0, 0, 0);
    acc[1][0] = __builtin_amdgcn_mfma_f32_16x16x32_bf16(ah1, qh0, acc[1][0], 0, 0, 0);
    acc[1][1] = __builtin_amdgcn_mfma_f32_16x16x32_bf16(ah1, qh1, acc[1][1], 0, 0, 0);
    acc[0][0] = __builtin_amdgcn_mfma_f32_16x16x32_bf16(ah0, ql0, acc[0][0], 0, 0, 0);
    acc[0][1] = __builtin_amdgcn_mfma_f32_16x16x32_bf16(ah0, ql1, acc[0][1], 0, 0, 0);
    acc[1][0] = __builtin_amdgcn_mfma_f32_16x16x32_bf16(ah1, ql0, acc[1][0], 0, 0, 0);
    acc[1][1] = __builtin_amdgcn_mfma_f32_16x16x32_bf16(ah1, ql1, acc[1][1], 0, 0, 0);
    acc[0][0] = __builtin_amdgcn_mfma_f32_16x16x32_bf16(al0, qh0, acc[0][0], 0, 0, 0);
    acc[0][1] = __builtin_amdgcn_mfma_f32_16x16x32_bf16(al0, qh1, acc[0][1], 0, 0, 0);
    acc[1][0] = __builtin_amdgcn_mfma_f32_16x16x32_bf16(al1, qh0, acc[1][0], 0, 0, 0);
    acc[1][1] = __builtin_amdgcn_mfma_f32_16x16x32_bf16(al1, qh1, acc[1][1], 0, 0, 0);
    __syncthreads();
  }
#pragma unroll
  for (int mi = 0; mi < 2; ++mi)
#pragma unroll
    for (int ni = 0; ni < 2; ++ni)
#pragma unroll
      for (int r = 0; r < 4; ++r) {
        int m = m0 + wm * 32 + mi * 16 + (lane >> 4) * 4 + r;
        int n = n0 + wn * 32 + ni * 16 + (lane & 15);
        if (n < NK2) {
          int k = n >> 1;
          float kv = ker[(size_t)m * NFREQ + k];   // KER is (1600, NFREQ)
          spec[(size_t)m * NK2 + n] = acc[mi][ni][r] * kv;
        }
      }
}

// inv NN-GEMM: ft[t,j] = (sum_k2 S[t,k2]*T[k2,j]) * win[j]
__global__ __launch_bounds__(256) void dft_inv_mfma(const float* __restrict__ spec,
    const uint32_t* __restrict__ T32, const float* __restrict__ WIN,
    float* __restrict__ ft) {
  __shared__ short Sh[64][40], Sl[64][40];
  __shared__ short Qh[32][68], Ql[32][68];
  int lin = blockIdx.x + blockIdx.y * gridDim.x;
  int wg = xcd_remap(lin, 60 * 25);
  int ntile = wg / 25, mtile = wg % 25;   // m-inner: T column-slice L2-resident
  int m0 = mtile * 64, n0 = ntile * 64;
  int tid = threadIdx.x;
  int lane = tid & 63, w = tid >> 6;
  int wm = w >> 1, wn = w & 1;
  f32x4 acc[2][2];
#pragma unroll
  for (int i = 0; i < 2; ++i)
#pragma unroll
    for (int j = 0; j < 2; ++j) acc[i][j] = (f32x4){0.f, 0.f, 0.f, 0.f};

  int srow = tid >> 2, skc = (tid & 3) * 8;
  int qrow = tid >> 3, qjc = (tid & 7) * 8;
  const float* srcrow = spec + (size_t)(m0 + srow) * NK2;
  int fr = lane & 15, fk = (lane >> 4) * 8;

  for (int ks = 0; ks < 121; ++ks) {
    int k20 = ks * 32;
#pragma unroll
    for (int c = 0; c < 8; c += 2) {
      float v0 = 0.f, v1 = 0.f;
      int k2a = k20 + skc + c;
#pragma unroll
      for (int u = 0; u < 2; ++u) {
        int k2 = k2a + u;
        float v = 0.f;
        if (k2 < NK2) {
          int k = k2 >> 1;
          bool edge = (k == 0) || (k == 1920);
          float mult = edge ? (1.0f / NFFT) : (2.0f / NFFT);
          v = srcrow[k2] * mult;
          if ((k2 & 1) && edge) v = 0.f;
        }
        if (u == 0) v0 = v; else v1 = v;
      }
      unsigned short h0 = f2bf(v0), h1 = f2bf(v1);
      unsigned short l0 = f2bf(v0 - bf2f(h0)), l1 = f2bf(v1 - bf2f(h1));
      *(uint32_t*)&Sh[srow][skc + c] = (uint32_t)h0 | ((uint32_t)h1 << 16);
      *(uint32_t*)&Sl[srow][skc + c] = (uint32_t)l0 | ((uint32_t)l1 << 16);
    }
    {
      int k2 = k20 + qrow;
      bool qv = k2 < NK2;
      const uint32_t* trow = T32 + (size_t)k2 * NFFT + n0;
#pragma unroll
      for (int c = 0; c < 8; c += 2) {
        uint32_t p0 = qv ? trow[qjc + c] : 0u;
        uint32_t p1 = qv ? trow[qjc + c + 1] : 0u;
        *(uint32_t*)&Qh[qrow][qjc + c] = (p0 & 0xFFFFu) | ((p1 & 0xFFFFu) << 16);
        *(uint32_t*)&Ql[qrow][qjc + c] = (p0 >> 16) | ((p1 >> 16) << 16);
      }
    }
    __syncthreads();
    short8v sh0 = *(const short8v*)&Sh[wm * 32 + fr][fk];
    short8v sh1 = *(const short8v*)&Sh[wm * 32 + 16 + fr][fk];
    short8v sl0 = *(const short8v*)&Sl[wm * 32 + fr][fk];
    short8v sl1 = *(const short8v*)&Sl[wm * 32 + 16 + fr][fk];
    short8v qhf[2], qlf[2];
#pragma unroll
    for (int ni = 0; ni < 2; ++ni) {
      int ncol = wn * 32 + ni * 16 + fr;
      short8v qh, ql;
#pragma unroll
      for (int i = 0; i < 8; ++i) {
        qh[i] = Qh[fk + i][ncol];
        ql[i] = Ql[fk + i][ncol];
      }
      qhf[ni] = qh; qlf[ni] = ql;
    }
    acc[0][0] = __builtin_amdgcn_mfma_f32_16x16x32_bf16(sh0, qhf[0], acc[0][0], 0, 0, 0);
    acc[0][1] = __builtin_amdgcn_mfma_f32_16x16x32_bf16(sh0, qhf[1], acc[0][1], 0, 0, 0);
    acc[1][0] = __builtin_amdgcn_mfma_f32_16x16x32_bf16(sh1, qhf[0], acc[1][0], 0, 0, 0);
    acc[1][1] = __builtin_amdgcn_mfma_f32_16x16x32_bf16(sh1, qhf[1], acc[1][1], 0, 0, 0);
    acc[0][0] = __builtin_amdgcn_mfma_f32_16x16x32_bf16(sh0, qlf[0], acc[0][0], 0, 0, 0);
    acc[0][1] = __builtin_amdgcn_mfma_f32_16x16x32_bf16(sh0, qlf[1], acc[0][1], 0, 0, 0);
    acc[1][0] = __builtin_amdgcn_mfma_f32_16x16x32_bf16(sh1, qlf[0], acc[1][0], 0, 0, 0);
    acc[1][1] = __builtin_amdgcn_mfma_f32_16x16x32_bf16(sh1, qlf[1], acc[1][1], 0, 0, 0);
    acc[0][0] = __builtin_amdgcn_mfma_f32_16x16x32_bf16(sl0, qhf[0], acc[0][0], 0, 0, 0);
    acc[0][1] = __builtin_amdgcn_mfma_f32_16x16x32_bf16(sl0, qhf[1], acc[0][1], 0, 0, 0);
    acc[1][0] = __builtin_amdgcn_mfma_f32_16x16x32_bf16(sl1, qhf[0], acc[1][0], 0, 0, 0);
    acc[1][1] = __builtin_amdgcn_mfma_f32_16x16x32_bf16(sl1, qhf[1], acc[1][1], 0, 0, 0);
    __syncthreads();
  }
#pragma unroll
  for (int mi = 0; mi < 2; ++mi)
#pragma unroll
    for (int ni = 0; ni < 2; ++ni)
#pragma unroll
      for (int r = 0; r < 4; ++r) {
        int m = m0 + wm * 32 + mi * 16 + (lane >> 4) * 4 + r;
        int n = n0 + wn * 32 + ni * 16 + (lane & 15);
        ft[(size_t)m * NFFT + n] = acc[mi][ni][r] * WIN[n];
      }
}

// ---------------- OLA + wn normalize + add harm (in place -> dsp) ----------------
__global__ void ola_kernel(const float* __restrict__ ft, float* __restrict__ dsp) {
  int idx = blockIdx.x * 256 + threadIdx.x;
  if (idx >= NB * LW) return;
  int b = idx / LW, n = idx % LW;
  int p = n + 1920;
  int t0 = (p > 3839) ? ((p - 2880) / 960) : 0;
  int t1 = p / FRAME; if (t1 > 200) t1 = 200;
  float y = 0.f, wn = 0.f;
  for (int t = t0; t <= t1; ++t) {
    int j = p - FRAME * t;
    float w = winf(j);
    wn += w * w;
    if (t >= 1) y += ft[((size_t)b * LF + (t - 1)) * NFFT + j];
  }
  float den = wn > 1e-11f ? wn : 1.0f;
  dsp[idx] = dsp[idx] + y / den;
}

// ---------------- per-frame 1024-tap correlation ----------------
__global__ __launch_bounds__(256) void fir_kernel(const float* __restrict__ dsp,
                                                  const float* __restrict__ filt,
                                                  float* __restrict__ outf) {
  int t = blockIdx.x, b = blockIdx.y;
  __shared__ float fr[FRAME];
  __shared__ float fl[NWIN];
  for (int i = threadIdx.x; i < FRAME; i += 256) fr[i] = dsp[(size_t)b * LW + (size_t)t * FRAME + i];
  for (int i = threadIdx.x; i < NWIN; i += 256)  fl[i] = filt[((size_t)b * LF + t) * NWIN + i];
  __syncthreads();
  for (int i = threadIdx.x; i < FRAME + NWIN; i += 256) {
    int m0 = i - NWIN;
    int tau0 = m0 < 0 ? -m0 : 0;
    int tau1 = FRAME - m0; if (tau1 > NWIN) tau1 = NWIN;
    float acc = 0.f;
    for (int tau = tau0; tau < tau1; ++tau) acc = fmaf(fr[m0 + tau], fl[tau], acc);
    outf[((size_t)b * LF + t) * (FRAME + NWIN) + i] = acc;
  }
}

// ---------------- fold frames (stride 960) into output ----------------
__global__ void fold_kernel(const float* __restrict__ outf, float* __restrict__ out) {
  int idx = blockIdx.x * 256 + threadIdx.x;
  if (idx >= NB * LW) return;
  int b = idx / LW, n = idx % LW;
  int t0 = (n >= 1984) ? ((n - 1024) / 960) : 0;
  int t1 = n / 960; if (t1 > 199) t1 = 199;
  float acc = 0.f;
  for (int t = t0; t <= t1; ++t)
    acc += outf[((size_t)b * LF + t) * (FRAME + NWIN) + (n - 960 * t)];
  out[idx] = acc;
}

extern "C" void kernel_launch(void* const* d_in, const int* in_sizes, int n_in,
                              void* d_out, int out_size, void* d_ws, size_t ws_size,
                              hipStream_t stream) {
  const float* content    = (const float*)d_in[0];
  const float* f0         = (const float*)d_in[1];
  const float* energy     = (const float*)d_in[2];
  const float* spk        = (const float*)d_in[3];
  const float* s_in_w     = (const float*)d_in[4];
  const float* s_in_b     = (const float*)d_in[5];
  const float* s_dw_w     = (const float*)d_in[6];
  const float* s_dw_b     = (const float*)d_in[7];
  const float* s_ln       = (const float*)d_in[8];
  const float* s_pw1_w    = (const float*)d_in[9];
  const float* s_pw1_b    = (const float*)d_in[10];
  const float* s_pw2_w    = (const float*)d_in[11];
  const float* s_pw2_b    = (const float*)d_in[12];
  const float* s_out_norm = (const float*)d_in[13];
  const float* f_in_w     = (const float*)d_in[14];
  const float* f_in_b     = (const float*)d_in[15];
  const float* f_dw_w     = (const float*)d_in[16];
  const float* f_dw_b     = (const float*)d_in[17];
  const float* f_ln       = (const float*)d_in[18];
  const float* f_pw1_w    = (const float*)d_in[19];
  const float* f_pw1_b    = (const float*)d_in[20];
  const float* f_pw2_w    = (const float*)d_in[21];
  const float* f_pw2_b    = (const float*)d_in[22];
  const float* f_out_norm = (const float*)d_in[23];
  const float* s_in_norm  = (const float*)d_in[24];
  const float* s_amp_w    = (const float*)d_in[25];
  const float* s_amp_b    = (const float*)d_in[26];
  const float* s_ker_w    = (const float*)d_in[27];
  const float* s_ker_b    = (const float*)d_in[28];
  const float* f_out_w    = (const float*)d_in[29];
  const float* f_out_b    = (const float*)d_in[30];

  // ---- workspace layout (counts unchanged; activations now (1600, C) row-major) ----
  double* CSUM = (double*)d_ws;
  float* FP   = (float*)((char*)d_ws + 12032);
  float* XIN  = FP;                  // 720000   (1600,450)
  float* XS   = XIN  + 720000;       // 819200   (1600,512)
  float* T512 = XS   + 819200;       // 819200   (1600,512)
  float* H15  = T512 + 819200;       // 2457600  (1600,1536)
  float* KER  = H15  + 2457600;      // 3073600  (1600,1921)
  float* AMPS = KER  + 3073600;      // 1600
  float* FILT = AMPS + 1600;         // 1638400  (1600,1024)
  float* FS   = FILT + 1638400;      // 1536000
  float* HARM = FS   + 1536000;      // 1536000  (becomes dsp)
  float* XP   = HARM + 1536000;      // 1566720
  float* SPEC = XP   + 1566720;      // 6147200  (1600,3842)
  float* FT   = SPEC + 6147200;      // 6144000  (1600,3840)
  float* OUTF = FT   + 6144000;      // 3174400
  float* IM   = SPEC;                // im2col overlay (1600,3584), used before SPEC
  uint32_t* T32 = (uint32_t*)(OUTF + 3174400);        // 59 MB twiddle table
  float* WIN    = (float*)(T32 + (size_t)NK2 * NFFT); // 3840 floats

  (void)in_sizes; (void)n_in; (void)out_size; (void)ws_size;

  build_xin<<<dim3((MTOT * CIN + 255) / 256), 256, 0, stream>>>(content, f0, energy, spk, XIN);

  auto run_trunk = [&](const float* in_w, const float* in_b, const float* in_norm,
                       const float* dw_w, const float* dw_b, const float* lnp,
                       const float* pw1_w, const float* pw1_b,
                       const float* pw2_w, const float* pw2_b,
                       const float* out_norm) {
    mm_hilo<<<dim3(25, CI / 64), 256, 0, stream>>>(in_w, XIN, in_b, nullptr, XS, CI, CIN, 0);
    if (in_norm)
      ln2_kernel<<<dim3(MTOT / 4), 256, 0, stream>>>(XS, in_norm, in_norm + CI);
    for (int i = 0; i < NL; ++i) {
      dwconv2_kernel<<<dim3((MTOT * CI + 255) / 256), 256, 0, stream>>>(
          XS, dw_w + (size_t)i * CI * 7, dw_b + (size_t)i * CI, T512);
      ln2_kernel<<<dim3(MTOT / 4), 256, 0, stream>>>(T512, lnp + (size_t)(i * 2) * CI, lnp + (size_t)(i * 2 + 1) * CI);
      mm_hilo<<<dim3(25, HID / 64), 256, 0, stream>>>(
          pw1_w + (size_t)i * HID * CI, T512, pw1_b + (size_t)i * HID, nullptr, H15, HID, CI, 1);
      mm_hilo<<<dim3(25, CI / 64), 256, 0, stream>>>(
          pw2_w + (size_t)i * CI * HID, H15, pw2_b + (size_t)i * CI, XS, XS, CI, HID, 0);
    }
    ln2_kernel<<<dim3(MTOT / 4), 256, 0, stream>>>(XS, out_norm, out_norm + CI);
  };

  // ---- source trunk ----
  run_trunk(s_in_w, s_in_b, s_in_norm, s_dw_w, s_dw_b, s_ln,
            s_pw1_w, s_pw1_b, s_pw2_w, s_pw2_b, s_out_norm);
  amps2_kernel<<<dim3(MTOT / 4), 256, 0, stream>>>(XS, s_amp_w, s_amp_b, AMPS);
  mm_hilo<<<dim3(25, (NFREQ + 63) / 64), 256, 0, stream>>>(s_ker_w, XS, s_ker_b, nullptr, KER, NFREQ, CI, 2);

  // ---- filter trunk (no input norm) ----
  run_trunk(f_in_w, f_in_b, nullptr, f_dw_w, f_dw_b, f_ln,
            f_pw1_w, f_pw1_b, f_pw2_w, f_pw2_b, f_out_norm);
  im2col2_kernel<<<dim3((MTOT * 3584 + 255) / 256), 256, 0, stream>>>(XS, IM);
  mm_hilo<<<dim3(25, NWIN / 64), 256, 0, stream>>>(f_out_w, IM, f_out_b, nullptr, FILT, NWIN, 3584, 0);

  // ---- harmonic source ----
  fs_kernel<<<dim3((NB * LW + 255) / 256), 256, 0, stream>>>(f0, FS);
  cumsum1<<<dim3(NCH, NB), 256, 0, stream>>>(FS, CSUM);
  cumsum2<<<dim3(NB), 64, 0, stream>>>(CSUM);
  harm_kernel<<<dim3(NCH, NB), 256, 0, stream>>>(FS, CSUM, f0, AMPS, HARM);

  // ---- filtered noise ----
  xp_kernel<<<dim3((NB * LPADW + 255) / 256), 256, 0, stream>>>(XP);
  twfill<<<dim3(15, NK2), 256, 0, stream>>>(T32, WIN);
  dft_fwd_mfma<<<dim3(61, 25), 256, 0, stream>>>(XP, T32, WIN, KER, SPEC);
  dft_inv_mfma<<<dim3(60, 25), 256, 0, stream>>>(SPEC, T32, WIN, FT);
  ola_kernel<<<dim3((NB * LW + 255) / 256), 256, 0, stream>>>(FT, HARM);

  // ---- time-varying FIR + fold ----
  fir_kernel<<<dim3(LF, NB), 256, 0, stream>>>(HARM, FILT, OUTF);
  fold_kernel<<<dim3((NB * LW + 255) / 256), 256, 0, stream>>>(OUTF, (float*)d_out);
}

// Round 6
// 1902.780 us; speedup vs baseline: 9.0962x; 2.9267x over previous
//
#include <hip/hip_runtime.h>
#include <hip/hip_bf16.h>
#include <math.h>
#include <stdint.h>

#define FRAME 960
#define NFFT  3840
#define NWIN  1024
#define NFREQ 1921
#define NB    8
#define LF    200
#define LW    192000
#define CIN   450
#define CI    512
#define HID   1536
#define NL    6
#define NCH   188
#define NK2   3842
#define MTOT  1600

typedef __attribute__((ext_vector_type(8))) short short8v;
typedef __attribute__((ext_vector_type(4))) float f32x4;
typedef __attribute__((address_space(3))) uint32_t lds_u32;
typedef const __attribute__((address_space(1))) uint32_t glb_u32;

// ---------------- threefry (JAX partitionable) ----------------
__device__ __forceinline__ uint32_t rotl32(uint32_t v, int r) { return (v << r) | (v >> (32 - r)); }
__device__ __forceinline__ void threefry2x32(uint32_t k0, uint32_t k1, uint32_t& x0, uint32_t& x1) {
  uint32_t ks2 = k0 ^ k1 ^ 0x1BD11BDAu;
  x0 += k0; x1 += k1;
#define TFR(r) { x0 += x1; x1 = rotl32(x1, r); x1 ^= x0; }
  TFR(13) TFR(15) TFR(26) TFR(6)  x0 += k1;  x1 += ks2 + 1u;
  TFR(17) TFR(29) TFR(16) TFR(24) x0 += ks2; x1 += k0 + 2u;
  TFR(13) TFR(15) TFR(26) TFR(6)  x0 += k0;  x1 += k1 + 3u;
  TFR(17) TFR(29) TFR(16) TFR(24) x0 += k1;  x1 += ks2 + 4u;
  TFR(13) TFR(15) TFR(26) TFR(6)  x0 += ks2; x1 += k0 + 5u;
#undef TFR
}
__device__ __forceinline__ float noiseval(int b, int m) {
  if (m < 0) m = -m;
  if (m >= LW) m = 2 * LW - 2 - m;
  uint32_t x0 = 0u, x1 = (uint32_t)(b * LW + m);
  threefry2x32(0u, 123u, x0, x1);
  uint32_t bits = x0 ^ x1;
  return __uint_as_float((bits >> 9) | 0x3f800000u) - 1.0f;
}
__device__ __forceinline__ float winf(int j) {
  return 0.5f - 0.5f * cosf((6.283185307179586f * (float)j) / 3840.0f);
}
__device__ __forceinline__ unsigned short f2bf(float v) {
  uint32_t b = __float_as_uint(v);
  return (unsigned short)((b + 0x7FFFu + ((b >> 16) & 1u)) >> 16);
}
__device__ __forceinline__ float bf2f(unsigned short h) {
  return __uint_as_float(((uint32_t)h) << 16);
}
__device__ __forceinline__ uint32_t pack2(float a, float b, bool lo) {
  unsigned short ha = f2bf(a), hb = f2bf(b);
  if (!lo) return (uint32_t)ha | ((uint32_t)hb << 16);
  return (uint32_t)f2bf(a - bf2f(ha)) | ((uint32_t)f2bf(b - bf2f(hb)) << 16);
}
__device__ __forceinline__ int xcd_remap(int lin, int nwg) {
  int q = nwg >> 3, r = nwg & 7;
  int xcd = lin & 7, base = lin >> 3;
  int start = (xcd < r) ? xcd * (q + 1) : r * (q + 1) + (xcd - r) * q;
  return start + base;
}

// ---------------- xin packed (1600 x 480, zero-padded) ----------------
__global__ void build_xin_pk(const float* __restrict__ content, const float* __restrict__ f0,
                             const float* __restrict__ energy, const float* __restrict__ spk,
                             uint32_t* __restrict__ PH, uint32_t* __restrict__ PL) {
  int idx = blockIdx.x * 256 + threadIdx.x;
  if (idx >= MTOT * 240) return;
  int row = idx / 240, cp = idx % 240;
  int b = row / LF, l = row % LF;
  float v2[2];
#pragma unroll
  for (int u = 0; u < 2; ++u) {
    int c = cp * 2 + u;
    float v = 0.f;
    if (c < 192)       v = content[((size_t)b * 192 + c) * LF + l];
    else if (c < 448)  v = spk[b * 256 + (c - 192)];
    else if (c == 448) v = logf(fmaxf(f0[b * LF + l], 0.0f) + 1e-6f);
    else if (c == 449) v = energy[b * LF + l];
    v2[u] = v;
  }
  PH[idx] = pack2(v2[0], v2[1], false);
  PL[idx] = pack2(v2[0], v2[1], true);
}

// ---------------- generic weight pack: W (M x K) -> hi/lo (Mp x Kp), zero-padded ----------------
__global__ void pack_w(const float* __restrict__ W, uint32_t* __restrict__ PH, uint32_t* __restrict__ PL,
                       int M, int K, int Kp2, int total) {
  int idx = blockIdx.x * 256 + threadIdx.x;
  if (idx >= total) return;
  int m = idx / Kp2, kp = idx % Kp2;
  int k = kp * 2;
  float v0 = (m < M && k < K) ? W[(size_t)m * K + k] : 0.f;
  float v1 = (m < M && (k + 1) < K) ? W[(size_t)m * K + k + 1] : 0.f;
  PH[idx] = pack2(v0, v1, false);
  PL[idx] = pack2(v0, v1, true);
}

// ---------------- unified packed-bf16 NT GEMM with global_load_lds double-buffer ----------------
// C[m,n] = sum_k W[m,k]*X[n,k]; operands pre-split hi/lo bf16, row-major k-contiguous.
__global__ __launch_bounds__(256) void gemm_pk(
    const uint16_t* __restrict__ WH, const uint16_t* __restrict__ WL,
    const uint16_t* __restrict__ XH, const uint16_t* __restrict__ XL,
    const float* __restrict__ bias, const float* __restrict__ res,
    float* __restrict__ outF, uint16_t* __restrict__ outH, uint16_t* __restrict__ outL,
    const uint16_t* __restrict__ KERH,
    int M, int Kp, int mtiles, int ntiles, int order, int mode, int act)
{
  __shared__ __align__(16) char smem[2][4][4096];
  int nwg = mtiles * ntiles;
  int wg = xcd_remap(blockIdx.x, nwg);
  int mtile, ntile;
  if (order == 0) { mtile = wg / ntiles; ntile = wg % ntiles; }
  else            { ntile = wg / mtiles; mtile = wg % mtiles; }
  int m0 = mtile * 64, n0 = ntile * 64;
  int tid = threadIdx.x;
  int lane = tid & 63, w = tid >> 6;
  int wm = w >> 1, wn = w & 1;
  int rowg = Kp >> 3;   // granules per row
  int phases = Kp >> 5;

  const uint16_t* gb = (w == 0) ? WH : (w == 1) ? WL : (w == 2) ? XH : XL;
  int row0 = (w < 2) ? m0 : n0;
  // per-lane source row/granule for staging
  int sr = lane >> 2, scg = lane & 3;
  int sgsel = scg ^ ((sr >> 1) & 3);
  f32x4 acc[2][2];
#pragma unroll
  for (int i = 0; i < 2; ++i)
#pragma unroll
    for (int j = 0; j < 2; ++j) acc[i][j] = (f32x4){0.f, 0.f, 0.f, 0.f};

  auto stage = [&](int buf, int p) {
    int kg0 = p * 4;
#pragma unroll
    for (int i = 0; i < 4; ++i) {
      int r = i * 16 + sr;
      const uint16_t* src = gb + (size_t)(row0 + r) * rowg * 8 + (size_t)(kg0 + sgsel) * 8;
      __builtin_amdgcn_global_load_lds((glb_u32*)src, (lds_u32*)(&smem[buf][w][0] + i * 1024), 16, 0, 0);
    }
  };

  stage(0, 0);
  __syncthreads();
  int fr = lane & 15, fg = lane >> 4;
  int fsw = ((fr >> 1) & 3);
  int aoff0 = (wm * 32 + fr) * 64 + (fg ^ fsw) * 16;
  int aoff1 = (wm * 32 + 16 + fr) * 64 + (fg ^ fsw) * 16;
  int boff0 = (wn * 32 + fr) * 64 + (fg ^ fsw) * 16;
  int boff1 = (wn * 32 + 16 + fr) * 64 + (fg ^ fsw) * 16;

  for (int p = 0; p < phases; ++p) {
    int cur = p & 1;
    if (p + 1 < phases) stage(cur ^ 1, p + 1);
    short8v ah0 = *(const short8v*)(&smem[cur][0][0] + aoff0);
    short8v ah1 = *(const short8v*)(&smem[cur][0][0] + aoff1);
    short8v al0 = *(const short8v*)(&smem[cur][1][0] + aoff0);
    short8v al1 = *(const short8v*)(&smem[cur][1][0] + aoff1);
    short8v bh0 = *(const short8v*)(&smem[cur][2][0] + boff0);
    short8v bh1 = *(const short8v*)(&smem[cur][2][0] + boff1);
    short8v bl0 = *(const short8v*)(&smem[cur][3][0] + boff0);
    short8v bl1 = *(const short8v*)(&smem[cur][3][0] + boff1);
    acc[0][0] = __builtin_amdgcn_mfma_f32_16x16x32_bf16(ah0, bh0, acc[0][0], 0, 0, 0);
    acc[0][1] = __builtin_amdgcn_mfma_f32_16x16x32_bf16(ah0, bh1, acc[0][1], 0, 0, 0);
    acc[1][0] = __builtin_amdgcn_mfma_f32_16x16x32_bf16(ah1, bh0, acc[1][0], 0, 0, 0);
    acc[1][1] = __builtin_amdgcn_mfma_f32_16x16x32_bf16(ah1, bh1, acc[1][1], 0, 0, 0);
    acc[0][0] = __builtin_amdgcn_mfma_f32_16x16x32_bf16(ah0, bl0, acc[0][0], 0, 0, 0);
    acc[0][1] = __builtin_amdgcn_mfma_f32_16x16x32_bf16(ah0, bl1, acc[0][1], 0, 0, 0);
    acc[1][0] = __builtin_amdgcn_mfma_f32_16x16x32_bf16(ah1, bl0, acc[1][0], 0, 0, 0);
    acc[1][1] = __builtin_amdgcn_mfma_f32_16x16x32_bf16(ah1, bl1, acc[1][1], 0, 0, 0);
    acc[0][0] = __builtin_amdgcn_mfma_f32_16x16x32_bf16(al0, bh0, acc[0][0], 0, 0, 0);
    acc[0][1] = __builtin_amdgcn_mfma_f32_16x16x32_bf16(al0, bh1, acc[0][1], 0, 0, 0);
    acc[1][0] = __builtin_amdgcn_mfma_f32_16x16x32_bf16(al1, bh0, acc[1][0], 0, 0, 0);
    acc[1][1] = __builtin_amdgcn_mfma_f32_16x16x32_bf16(al1, bh1, acc[1][1], 0, 0, 0);
    __syncthreads();
  }

#pragma unroll
  for (int mi = 0; mi < 2; ++mi)
#pragma unroll
    for (int ni = 0; ni < 2; ++ni)
#pragma unroll
      for (int r = 0; r < 4; ++r) {
        int m = m0 + wm * 32 + mi * 16 + ((lane >> 4) << 2) + r;
        int n = n0 + wn * 32 + ni * 16 + (lane & 15);
        float v = acc[mi][ni][r];
        if (mode == 3) {
          if (n < 3872) {
            float o = 0.f;
            if (n < NK2) {
              int k = n >> 1;
              float kv = bf2f(KERH[(size_t)m * NFREQ + k]);
              bool edge = (k == 0) || (k == 1920);
              float mult = edge ? (1.0f / NFFT) : (2.0f / NFFT);
              o = v * kv * mult;
              if ((n & 1) && edge) o = 0.f;
            }
            unsigned short h = f2bf(o);
            outH[(size_t)m * 3872 + n] = h;
            outL[(size_t)m * 3872 + n] = f2bf(o - bf2f(h));
          }
        } else if (m < M) {
          v += bias ? bias[m] : 0.f;
          if (act == 1)      v = 0.5f * v * (1.0f + erff(v * 0.7071067811865475f));
          else if (act == 2) v = (v > 0.f ? v : expm1f(v)) + 1.0f;
          if (mode == 0) {
            if (res) v += res[(size_t)n * M + m];
            outF[(size_t)n * M + m] = v;
          } else if (mode == 1) {
            unsigned short h = f2bf(v);
            outH[(size_t)n * M + m] = h;
            outL[(size_t)n * M + m] = f2bf(v - bf2f(h));
          } else {  // 2: KER bf16
            outH[(size_t)n * NFREQ + m] = f2bf(v);
          }
        }
      }
}

// ---------------- inverse DFT GEMM: ft[t,j] = sum_k2 S[t,k2]*T[k2,j], T transpose-staged ----------------
__global__ __launch_bounds__(256) void gemm_inv(
    const uint16_t* __restrict__ SH, const uint16_t* __restrict__ SL,
    const uint16_t* __restrict__ THH, const uint16_t* __restrict__ THL,
    float* __restrict__ ft)
{
  __shared__ __align__(16) char smA[2][2][4096];
  __shared__ __align__(16) uint16_t smB[2][2][64][40];
  int wg = xcd_remap(blockIdx.x, 60 * 25);
  int ntile = wg / 25, mtile = wg % 25;
  int m0 = mtile * 64, n0 = ntile * 64;
  int tid = threadIdx.x;
  int lane = tid & 63, w = tid >> 6;
  int wm = w >> 1, wn = w & 1;
  int sr = lane >> 2, scg = lane & 3;
  int sgsel = scg ^ ((sr >> 1) & 3);
  int bk2 = tid >> 3, bj0 = (tid & 7) * 8;
  int bsw = ((tid & 7) & 3) << 3;
  f32x4 acc[2][2];
#pragma unroll
  for (int i = 0; i < 2; ++i)
#pragma unroll
    for (int j = 0; j < 2; ++j) acc[i][j] = (f32x4){0.f, 0.f, 0.f, 0.f};

  auto stage = [&](int buf, int p) {
    int kg0 = p * 4;
    if (w < 2) {
      const uint16_t* gbs = (w == 0) ? SH : SL;
#pragma unroll
      for (int i = 0; i < 4; ++i) {
        int r = i * 16 + sr;
        const uint16_t* src = gbs + (size_t)(m0 + r) * 3872 + (size_t)(kg0 + sgsel) * 8;
        __builtin_amdgcn_global_load_lds((glb_u32*)src, (lds_u32*)(&smA[buf][w][0] + i * 1024), 16, 0, 0);
      }
    }
    int k20 = p * 32;
    const uint16_t* th = THH + (size_t)(k20 + bk2) * 3840 + (n0 + bj0);
    const uint16_t* tl = THL + (size_t)(k20 + bk2) * 3840 + (n0 + bj0);
    uint4 vh = *(const uint4*)th;
    uint4 vl = *(const uint4*)tl;
    int k2s = bk2 ^ bsw;
#pragma unroll
    for (int q = 0; q < 8; ++q) {
      smB[buf][0][bj0 + q][k2s] = ((const uint16_t*)&vh)[q];
      smB[buf][1][bj0 + q][k2s] = ((const uint16_t*)&vl)[q];
    }
  };

  stage(0, 0);
  __syncthreads();
  int fr = lane & 15, fg = lane >> 4;
  int fsw = ((fr >> 1) & 3);
  int aoff0 = (wm * 32 + fr) * 64 + (fg ^ fsw) * 16;
  int aoff1 = (wm * 32 + 16 + fr) * 64 + (fg ^ fsw) * 16;
  int jl0 = wn * 32 + fr;
  int jl1 = wn * 32 + 16 + fr;
  int boff0 = jl0 * 80 + ((fg ^ ((jl0 >> 3) & 3)) << 4);
  int boff1 = jl1 * 80 + ((fg ^ ((jl1 >> 3) & 3)) << 4);

  for (int p = 0; p < 121; ++p) {
    int cur = p & 1;
    if (p + 1 < 121) stage(cur ^ 1, p + 1);
    short8v ah0 = *(const short8v*)(&smA[cur][0][0] + aoff0);
    short8v ah1 = *(const short8v*)(&smA[cur][0][0] + aoff1);
    short8v al0 = *(const short8v*)(&smA[cur][1][0] + aoff0);
    short8v al1 = *(const short8v*)(&smA[cur][1][0] + aoff1);
    short8v bh0 = *(const short8v*)((char*)&smB[cur][0][0][0] + boff0);
    short8v bh1 = *(const short8v*)((char*)&smB[cur][0][0][0] + boff1);
    short8v bl0 = *(const short8v*)((char*)&smB[cur][1][0][0] + boff0);
    short8v bl1 = *(const short8v*)((char*)&smB[cur][1][0][0] + boff1);
    acc[0][0] = __builtin_amdgcn_mfma_f32_16x16x32_bf16(ah0, bh0, acc[0][0], 0, 0, 0);
    acc[0][1] = __builtin_amdgcn_mfma_f32_16x16x32_bf16(ah0, bh1, acc[0][1], 0, 0, 0);
    acc[1][0] = __builtin_amdgcn_mfma_f32_16x16x32_bf16(ah1, bh0, acc[1][0], 0, 0, 0);
    acc[1][1] = __builtin_amdgcn_mfma_f32_16x16x32_bf16(ah1, bh1, acc[1][1], 0, 0, 0);
    acc[0][0] = __builtin_amdgcn_mfma_f32_16x16x32_bf16(ah0, bl0, acc[0][0], 0, 0, 0);
    acc[0][1] = __builtin_amdgcn_mfma_f32_16x16x32_bf16(ah0, bl1, acc[0][1], 0, 0, 0);
    acc[1][0] = __builtin_amdgcn_mfma_f32_16x16x32_bf16(ah1, bl0, acc[1][0], 0, 0, 0);
    acc[1][1] = __builtin_amdgcn_mfma_f32_16x16x32_bf16(ah1, bl1, acc[1][1], 0, 0, 0);
    acc[0][0] = __builtin_amdgcn_mfma_f32_16x16x32_bf16(al0, bh0, acc[0][0], 0, 0, 0);
    acc[0][1] = __builtin_amdgcn_mfma_f32_16x16x32_bf16(al0, bh1, acc[0][1], 0, 0, 0);
    acc[1][0] = __builtin_amdgcn_mfma_f32_16x16x32_bf16(al1, bh0, acc[1][0], 0, 0, 0);
    acc[1][1] = __builtin_amdgcn_mfma_f32_16x16x32_bf16(al1, bh1, acc[1][1], 0, 0, 0);
    __syncthreads();
  }
#pragma unroll
  for (int mi = 0; mi < 2; ++mi)
#pragma unroll
    for (int ni = 0; ni < 2; ++ni)
#pragma unroll
      for (int r = 0; r < 4; ++r) {
        int m = m0 + wm * 32 + mi * 16 + ((lane >> 4) << 2) + r;
        int n = n0 + wn * 32 + ni * 16 + (lane & 15);
        ft[(size_t)m * NFFT + n] = acc[mi][ni][r] * winf(n);
      }
}

// ---------------- LayerNorm rows (1600, CI) in place, optional packed out ----------------
__global__ __launch_bounds__(256) void ln2_kernel(float* __restrict__ x, const float* __restrict__ g,
                                                  const float* __restrict__ bta,
                                                  uint32_t* __restrict__ PH, uint32_t* __restrict__ PL) {
  int row = blockIdx.x * 4 + (threadIdx.x >> 6);
  int lane = threadIdx.x & 63;
  float* xr = x + (size_t)row * CI;
  int c0 = lane * 8;
  float4 v0 = *(float4*)&xr[c0], v1 = *(float4*)&xr[c0 + 4];
  float s = v0.x + v0.y + v0.z + v0.w + v1.x + v1.y + v1.z + v1.w;
#pragma unroll
  for (int m = 1; m < 64; m <<= 1) s += __shfl_xor(s, m, 64);
  float mean = s * (1.0f / CI);
  float d[8] = {v0.x - mean, v0.y - mean, v0.z - mean, v0.w - mean,
                v1.x - mean, v1.y - mean, v1.z - mean, v1.w - mean};
  float s2 = 0.f;
#pragma unroll
  for (int q = 0; q < 8; ++q) s2 += d[q] * d[q];
#pragma unroll
  for (int m = 1; m < 64; m <<= 1) s2 += __shfl_xor(s2, m, 64);
  float rs = rsqrtf(s2 * (1.0f / CI) + 1e-5f);
  float o[8];
#pragma unroll
  for (int q = 0; q < 8; ++q) o[q] = d[q] * rs * g[c0 + q] + bta[c0 + q];
  float4 w0 = {o[0], o[1], o[2], o[3]}, w1 = {o[4], o[5], o[6], o[7]};
  *(float4*)&xr[c0] = w0; *(float4*)&xr[c0 + 4] = w1;
  if (PH) {
    int base = (row * CI + c0) >> 1;
#pragma unroll
    for (int q = 0; q < 4; ++q) {
      PH[base + q] = pack2(o[2 * q], o[2 * q + 1], false);
      PL[base + q] = pack2(o[2 * q], o[2 * q + 1], true);
    }
  }
}

// ---------------- fused depthwise conv K=7 + LayerNorm -> packed ----------------
__global__ __launch_bounds__(256) void dwln_kernel(const float* __restrict__ xs,
    const float* __restrict__ dw, const float* __restrict__ db,
    const float* __restrict__ g, const float* __restrict__ bt,
    uint32_t* __restrict__ PH, uint32_t* __restrict__ PL) {
  int row = blockIdx.x;
  int b = row / LF, l = row % LF;
  int c = threadIdx.x * 2;
  float ax = db[c], ay = db[c + 1];
#pragma unroll
  for (int tau = 0; tau < 7; ++tau) {
    int j = l + tau - 3;
    if (j < 0 || j >= LF) continue;
    float2 xv = *(const float2*)&xs[((size_t)b * LF + j) * CI + c];
    ax = fmaf(xv.x, dw[c * 7 + tau], ax);
    ay = fmaf(xv.y, dw[(c + 1) * 7 + tau], ay);
  }
  __shared__ float red[4], red2[4];
  float s = ax + ay;
#pragma unroll
  for (int m = 1; m < 64; m <<= 1) s += __shfl_xor(s, m, 64);
  if ((threadIdx.x & 63) == 0) red[threadIdx.x >> 6] = s;
  __syncthreads();
  float mean = (red[0] + red[1] + red[2] + red[3]) * (1.0f / CI);
  float dx = ax - mean, dy = ay - mean;
  float s2 = dx * dx + dy * dy;
#pragma unroll
  for (int m = 1; m < 64; m <<= 1) s2 += __shfl_xor(s2, m, 64);
  if ((threadIdx.x & 63) == 0) red2[threadIdx.x >> 6] = s2;
  __syncthreads();
  float var = (red2[0] + red2[1] + red2[2] + red2[3]) * (1.0f / CI);
  float rs = rsqrtf(var + 1e-5f);
  float vx = dx * rs * g[c] + bt[c];
  float vy = dy * rs * g[c + 1] + bt[c + 1];
  PH[(size_t)row * 256 + threadIdx.x] = pack2(vx, vy, false);
  PL[(size_t)row * 256 + threadIdx.x] = pack2(vx, vy, true);
}

// ---------------- amps head ----------------
__global__ __launch_bounds__(256) void amps2_kernel(const float* __restrict__ x, const float* __restrict__ w,
                                                    const float* __restrict__ bias, float* __restrict__ amps) {
  int row = blockIdx.x * 4 + (threadIdx.x >> 6);
  int lane = threadIdx.x & 63;
  const float* xr = x + (size_t)row * CI;
  int c0 = lane * 8;
  float4 v0 = *(const float4*)&xr[c0], v1 = *(const float4*)&xr[c0 + 4];
  float4 w0 = *(const float4*)&w[c0], w1 = *(const float4*)&w[c0 + 4];
  float s = v0.x * w0.x + v0.y * w0.y + v0.z * w0.z + v0.w * w0.w
          + v1.x * w1.x + v1.y * w1.y + v1.z * w1.z + v1.w * w1.w;
#pragma unroll
  for (int m = 1; m < 64; m <<= 1) s += __shfl_xor(s, m, 64);
  if (lane == 0) {
    float a = s + bias[0];
    amps[row] = (a > 0.f ? a : expm1f(a)) + 1.0f;
  }
}

// ---------------- im2col packed (edge pad 3) -> (1600, 3584) ----------------
__global__ void im2col_pk(const float* __restrict__ x, uint32_t* __restrict__ PH, uint32_t* __restrict__ PL) {
  int idx = blockIdx.x * 256 + threadIdx.x;
  if (idx >= MTOT * 1792) return;
  int row = idx / 1792, kp = idx % 1792;
  int b = row / LF, l = row % LF;
  float v2[2];
#pragma unroll
  for (int u = 0; u < 2; ++u) {
    int kap = kp * 2 + u;
    int ch = kap / 7, tau = kap % 7;
    int j = l + tau - 3;
    j = j < 0 ? 0 : (j > LF - 1 ? LF - 1 : j);
    v2[u] = x[((size_t)b * LF + j) * CI + ch];
  }
  PH[idx] = pack2(v2[0], v2[1], false);
  PL[idx] = pack2(v2[0], v2[1], true);
}

// ---------------- noise*window packed A (1600 x 3840) ----------------
__global__ void pack_noise(uint32_t* __restrict__ AH, uint32_t* __restrict__ AL) {
  int idx = blockIdx.x * 256 + threadIdx.x;
  if (idx >= MTOT * 1920) return;
  int t = idx / 1920, jp = idx % 1920;
  int b = t / LF, tt = t % LF;
  int j = jp * 2;
  float v0 = noiseval(b, tt * 960 + j - 960) * winf(j);
  float v1 = noiseval(b, tt * 960 + j - 959) * winf(j + 1);
  AH[idx] = pack2(v0, v1, false);
  AL[idx] = pack2(v0, v1, true);
}

// ---------------- twiddle tables hi/lo (3904 x 3840) ----------------
__global__ void twfill_pk(uint32_t* __restrict__ TH, uint32_t* __restrict__ TL) {
  int idx = blockIdx.x * 256 + threadIdx.x;
  if (idx >= 3904 * 1920) return;
  int k2 = idx / 1920, jp = idx % 1920;
  float v2[2] = {0.f, 0.f};
  if (k2 < NK2) {
    int k = k2 >> 1;
#pragma unroll
    for (int u = 0; u < 2; ++u) {
      int j = jp * 2 + u;
      int m = (j * k) % NFFT;
      float ang = (float)m * (6.283185307179586f / 3840.0f);
      v2[u] = (k2 & 1) ? -sinf(ang) : cosf(ang);
    }
  }
  TH[idx] = pack2(v2[0], v2[1], false);
  TL[idx] = pack2(v2[0], v2[1], true);
}

// ---------------- harmonic path (unchanged, validated) ----------------
__global__ void fs_kernel(const float* __restrict__ f0, float* __restrict__ fs) {
  int idx = blockIdx.x * 256 + threadIdx.x;
  if (idx >= NB * LW) return;
  int b = idx / LW, n = idx % LW;
  float pos = ((float)n + 0.5f) * (200.0f / 192000.0f) - 0.5f;
  pos = fminf(fmaxf(pos, 0.0f), 199.0f);
  int i0 = (int)pos;
  int i1 = min(i0 + 1, 199);
  float w = pos - (float)i0;
  fs[idx] = f0[b * LF + i0] * (1.0f - w) + f0[b * LF + i1] * w;
}

__global__ __launch_bounds__(256) void cumsum1(const float* __restrict__ fs, double* __restrict__ csum) {
  int b = blockIdx.y, ch = blockIdx.x;
  const float* fsb = fs + (size_t)b * LW;
  int base = ch * 1024;
  double s = 0.0;
  for (int q = 0; q < 4; ++q) {
    int n = base + threadIdx.x * 4 + q;
    if (n < LW) s += (double)((3.14159274101257324f * fsb[n]) / 48000.0f);
  }
  __shared__ double sh[256];
  sh[threadIdx.x] = s;
  __syncthreads();
  for (int o2 = 128; o2 > 0; o2 >>= 1) {
    if (threadIdx.x < o2) sh[threadIdx.x] += sh[threadIdx.x + o2];
    __syncthreads();
  }
  if (threadIdx.x == 0) csum[b * NCH + ch] = sh[0];
}

__global__ void cumsum2(double* __restrict__ csum) {
  int b = blockIdx.x;
  if (threadIdx.x == 0) {
    double acc = 0.0;
    for (int ch = 0; ch < NCH; ++ch) {
      double v = csum[b * NCH + ch];
      csum[b * NCH + ch] = acc;
      acc += v;
    }
  }
}

__global__ __launch_bounds__(256) void harm_kernel(
    const float* __restrict__ fs, const double* __restrict__ csum,
    const float* __restrict__ f0, const float* __restrict__ amps,
    float* __restrict__ harm) {
  int b = blockIdx.y, ch = blockIdx.x;
  const float* fsb = fs + (size_t)b * LW;
  int base = ch * 1024;
  int tid = threadIdx.x;
  double p[4]; double s = 0.0;
  int n0 = base + tid * 4;
  for (int q = 0; q < 4; ++q) {
    int n = n0 + q; float sm = 0.f;
    if (n < LW) sm = (3.14159274101257324f * fsb[n]) / 48000.0f;
    s += (double)sm; p[q] = s;
  }
  __shared__ double sh[256];
  sh[tid] = s; __syncthreads();
  for (int o2 = 1; o2 < 256; o2 <<= 1) {
    double v = (tid >= o2) ? sh[tid - o2] : 0.0;
    __syncthreads();
    sh[tid] += v;
    __syncthreads();
  }
  double excl = csum[b * NCH + ch] + (tid > 0 ? sh[tid - 1] : 0.0);
  const double PID = (double)3.14159274101257324f;
  for (int q = 0; q < 4; ++q) {
    int n = n0 + q; if (n >= LW) break;
    double S = excl + p[q];
    float pixf = (float)fmod(S, PID);
    float fsv = fsb[n];
    float a = rintf(48000.0f / fmaxf(fsv, 20.0f) * 0.5f) * 2.0f + 1.0f;
    float D = (pixf < 1e-8f) ? 1.0f : (sinf(a * pixf) / (a * sinf(pixf)));
    int ui = n / 960;
    float uv = (f0[b * LF + ui] > 20.0f) ? 1.0f : 0.0f;
    float posA = ((float)n + 0.5f) * (200.0f / 192000.0f) - 0.5f;
    posA = fminf(fmaxf(posA, 0.0f), 199.0f);
    int i0 = (int)posA;
    int i1 = min(i0 + 1, 199);
    float w = posA - (float)i0;
    float ampI = amps[b * LF + i0] * (1.0f - w) + amps[b * LF + i1] * w;
    harm[(size_t)b * LW + n] = (D * uv) * ampI;
  }
}

// ---------------- OLA + wn normalize + add to harm (-> dsp) ----------------
__global__ void ola_kernel(const float* __restrict__ ft, float* __restrict__ dsp) {
  int idx = blockIdx.x * 256 + threadIdx.x;
  if (idx >= NB * LW) return;
  int b = idx / LW, n = idx % LW;
  int p = n + 1920;
  int t0 = (p > 3839) ? ((p - 2880) / 960) : 0;
  int t1 = p / FRAME; if (t1 > 200) t1 = 200;
  float y = 0.f, wn = 0.f;
  for (int t = t0; t <= t1; ++t) {
    int j = p - FRAME * t;
    float w = winf(j);
    wn += w * w;
    if (t >= 1) y += ft[((size_t)b * LF + (t - 1)) * NFFT + j];
  }
  float den = wn > 1e-11f ? wn : 1.0f;
  dsp[idx] = dsp[idx] + y / den;
}

// ---------------- per-frame FIR via padded LDS + 8-output register blocking ----------------
__global__ __launch_bounds__(256) void fir2_kernel(const float* __restrict__ dsp,
                                                   const float* __restrict__ filt,
                                                   float* __restrict__ outf) {
  int t = blockIdx.x, b = blockIdx.y;
  __shared__ float frp[3008];
  __shared__ float fl[NWIN];
  int tid = threadIdx.x;
  for (int i = tid; i < 3008; i += 256) frp[i] = 0.f;
  __syncthreads();
  for (int i = tid; i < FRAME; i += 256) frp[1024 + i] = dsp[(size_t)b * LW + (size_t)t * FRAME + i];
  for (int i = tid; i < NWIN; i += 256) fl[i] = filt[((size_t)b * LF + t) * NWIN + i];
  __syncthreads();
  float a[8] = {0.f, 0.f, 0.f, 0.f, 0.f, 0.f, 0.f, 0.f};
  for (int tau = 0; tau < NWIN; ++tau) {
    float fv = fl[tau];
#pragma unroll
    for (int q = 0; q < 8; ++q) a[q] = fmaf(frp[tid + q * 256 + tau], fv, a[q]);
  }
#pragma unroll
  for (int q = 0; q < 8; ++q) {
    int i = tid + q * 256;
    if (i < 1984) outf[((size_t)b * LF + t) * 1984 + i] = a[q];
  }
}

// ---------------- fold ----------------
__global__ void fold_kernel(const float* __restrict__ outf, float* __restrict__ out) {
  int idx = blockIdx.x * 256 + threadIdx.x;
  if (idx >= NB * LW) return;
  int b = idx / LW, n = idx % LW;
  int t0 = (n >= 1984) ? ((n - 1024) / 960) : 0;
  int t1 = n / 960; if (t1 > 199) t1 = 199;
  float acc = 0.f;
  for (int t = t0; t <= t1; ++t)
    acc += outf[((size_t)b * LF + t) * 1984 + (n - 960 * t)];
  out[idx] = acc;
}

extern "C" void kernel_launch(void* const* d_in, const int* in_sizes, int n_in,
                              void* d_out, int out_size, void* d_ws, size_t ws_size,
                              hipStream_t stream) {
  const float* content    = (const float*)d_in[0];
  const float* f0         = (const float*)d_in[1];
  const float* energy     = (const float*)d_in[2];
  const float* spk        = (const float*)d_in[3];
  const float* s_in_w     = (const float*)d_in[4];
  const float* s_in_b     = (const float*)d_in[5];
  const float* s_dw_w     = (const float*)d_in[6];
  const float* s_dw_b     = (const float*)d_in[7];
  const float* s_ln       = (const float*)d_in[8];
  const float* s_pw1_w    = (const float*)d_in[9];
  const float* s_pw1_b    = (const float*)d_in[10];
  const float* s_pw2_w    = (const float*)d_in[11];
  const float* s_pw2_b    = (const float*)d_in[12];
  const float* s_out_norm = (const float*)d_in[13];
  const float* f_in_w     = (const float*)d_in[14];
  const float* f_in_b     = (const float*)d_in[15];
  const float* f_dw_w     = (const float*)d_in[16];
  const float* f_dw_b     = (const float*)d_in[17];
  const float* f_ln       = (const float*)d_in[18];
  const float* f_pw1_w    = (const float*)d_in[19];
  const float* f_pw1_b    = (const float*)d_in[20];
  const float* f_pw2_w    = (const float*)d_in[21];
  const float* f_pw2_b    = (const float*)d_in[22];
  const float* f_out_norm = (const float*)d_in[23];
  const float* s_in_norm  = (const float*)d_in[24];
  const float* s_amp_w    = (const float*)d_in[25];
  const float* s_amp_b    = (const float*)d_in[26];
  const float* s_ker_w    = (const float*)d_in[27];
  const float* s_ker_b    = (const float*)d_in[28];
  const float* f_out_w    = (const float*)d_in[29];
  const float* f_out_b    = (const float*)d_in[30];

  // ---- workspace layout (bytes; 167.4 MB total; proven ws >= 177.6 MB) ----
  char* W0 = (char*)d_ws;
  double*   CSUM  = (double*)W0;                               // 12,032
  uint32_t* XINPH = (uint32_t*)(W0 + 12032);                   // 1,536,000
  uint32_t* XINPL = (uint32_t*)(W0 + 1548032);                 // 1,536,000
  float*    XS    = (float*)   (W0 + 3084032);                 // 3,276,800
  uint32_t* XSPH  = (uint32_t*)(W0 + 6360832);                 // 1,638,400
  uint32_t* XSPL  = (uint32_t*)(W0 + 7999232);                 // 1,638,400
  uint32_t* TPH   = (uint32_t*)(W0 + 9637632);                 // 1,638,400
  uint32_t* TPL   = (uint32_t*)(W0 + 11276032);                // 1,638,400
  uint32_t* H15PH = (uint32_t*)(W0 + 12914432);                // 4,915,200
  uint32_t* H15PL = (uint32_t*)(W0 + 17829632);                // 4,915,200
  uint16_t* KERH  = (uint16_t*)(W0 + 22744832);                // 6,147,200
  float*    AMPS  = (float*)   (W0 + 28892032);                // 6,400
  float*    FILT  = (float*)   (W0 + 28898432);                // 6,553,600
  float*    HARM  = (float*)   (W0 + 35452032);                // 6,144,000
  char*     R2    = W0 + 41596032;                             // 24,780,800
  char*     FTR   = W0 + 66376832;                             // 24,576,000
  char*     U     = W0 + 90952832;                             // 24,576,000
  uint32_t* TH32  = (uint32_t*)(W0 + 115528832);               // 29,982,720
  uint32_t* TL32  = (uint32_t*)(W0 + 145511552);               // 29,982,720
  // overlays
  uint32_t* IMPH = (uint32_t*)R2;                 // 11,468,800
  uint32_t* IMPL = (uint32_t*)(R2 + 11468800);
  uint16_t* SH   = (uint16_t*)R2;                 // 12,390,400  (after IMP dead)
  uint16_t* SL   = (uint16_t*)(R2 + 12390400);
  float*    OUTF = (float*)R2;                    // 12,697,600  (after SH/SL dead)
  float*    FS   = (float*)FTR;                   // 6,144,000
  float*    FT   = (float*)FTR;                   // 24,576,000  (after FS dead)
  uint32_t* WPH  = (uint32_t*)U;                  // <= 7,340,032
  uint32_t* WPL  = (uint32_t*)(U + 7340032);
  uint16_t* AH   = (uint16_t*)U;                  // 12,288,000  (after WPACK dead)
  uint16_t* AL   = (uint16_t*)(U + 12288000);

  (void)in_sizes; (void)n_in; (void)out_size; (void)ws_size;

  build_xin_pk<<<dim3((MTOT * 240 + 255) / 256), 256, 0, stream>>>(content, f0, energy, spk, XINPH, XINPL);

  auto pw = [&](const float* Wm, int M, int K, int Mp, int Kp) {
    int total = Mp * (Kp / 2);
    pack_w<<<dim3((total + 255) / 256), 256, 0, stream>>>(Wm, WPH, WPL, M, K, Kp / 2, total);
  };
  auto run_trunk = [&](const float* in_w, const float* in_b, const float* in_norm,
                       const float* dw_w, const float* dw_b, const float* lnp,
                       const float* pw1_w, const float* pw1_b,
                       const float* pw2_w, const float* pw2_b) {
    pw(in_w, CI, CIN, CI, 480);
    gemm_pk<<<dim3(8 * 25), 256, 0, stream>>>((uint16_t*)WPH, (uint16_t*)WPL, (uint16_t*)XINPH, (uint16_t*)XINPL,
        in_b, nullptr, XS, nullptr, nullptr, nullptr, CI, 480, 8, 25, 0, 0, 0);
    if (in_norm)
      ln2_kernel<<<dim3(MTOT / 4), 256, 0, stream>>>(XS, in_norm, in_norm + CI, nullptr, nullptr);
    for (int i = 0; i < NL; ++i) {
      dwln_kernel<<<dim3(MTOT), 256, 0, stream>>>(XS, dw_w + (size_t)i * CI * 7, dw_b + (size_t)i * CI,
          lnp + (size_t)(i * 2) * CI, lnp + (size_t)(i * 2 + 1) * CI, TPH, TPL);
      pw(pw1_w + (size_t)i * HID * CI, HID, CI, HID, 512);
      gemm_pk<<<dim3(24 * 25), 256, 0, stream>>>((uint16_t*)WPH, (uint16_t*)WPL, (uint16_t*)TPH, (uint16_t*)TPL,
          pw1_b + (size_t)i * HID, nullptr, nullptr, (uint16_t*)H15PH, (uint16_t*)H15PL, nullptr,
          HID, 512, 24, 25, 0, 1, 1);
      pw(pw2_w + (size_t)i * CI * HID, CI, HID, CI, 1536);
      gemm_pk<<<dim3(8 * 25), 256, 0, stream>>>((uint16_t*)WPH, (uint16_t*)WPL, (uint16_t*)H15PH, (uint16_t*)H15PL,
          pw2_b + (size_t)i * CI, XS, XS, nullptr, nullptr, nullptr, CI, 1536, 8, 25, 0, 0, 0);
    }
  };

  // ---- source trunk ----
  run_trunk(s_in_w, s_in_b, s_in_norm, s_dw_w, s_dw_b, s_ln, s_pw1_w, s_pw1_b, s_pw2_w, s_pw2_b);
  ln2_kernel<<<dim3(MTOT / 4), 256, 0, stream>>>(XS, s_out_norm, s_out_norm + CI, XSPH, XSPL);
  amps2_kernel<<<dim3(MTOT / 4), 256, 0, stream>>>(XS, s_amp_w, s_amp_b, AMPS);
  pw(s_ker_w, NFREQ, CI, 1984, 512);
  gemm_pk<<<dim3(31 * 25), 256, 0, stream>>>((uint16_t*)WPH, (uint16_t*)WPL, (uint16_t*)XSPH, (uint16_t*)XSPL,
      s_ker_b, nullptr, nullptr, KERH, nullptr, nullptr, NFREQ, 512, 31, 25, 0, 2, 2);

  // ---- filter trunk ----
  run_trunk(f_in_w, f_in_b, nullptr, f_dw_w, f_dw_b, f_ln, f_pw1_w, f_pw1_b, f_pw2_w, f_pw2_b);
  ln2_kernel<<<dim3(MTOT / 4), 256, 0, stream>>>(XS, f_out_norm, f_out_norm + CI, nullptr, nullptr);
  im2col_pk<<<dim3((MTOT * 1792 + 255) / 256), 256, 0, stream>>>(XS, IMPH, IMPL);
  pw(f_out_w, NWIN, 3584, NWIN, 3584);
  gemm_pk<<<dim3(16 * 25), 256, 0, stream>>>((uint16_t*)WPH, (uint16_t*)WPL, (uint16_t*)IMPH, (uint16_t*)IMPL,
      f_out_b, nullptr, FILT, nullptr, nullptr, nullptr, NWIN, 3584, 16, 25, 0, 0, 0);

  // ---- harmonic source (FS lives in FT region, dead before inv) ----
  fs_kernel<<<dim3((NB * LW + 255) / 256), 256, 0, stream>>>(f0, FS);
  cumsum1<<<dim3(NCH, NB), 256, 0, stream>>>(FS, CSUM);
  cumsum2<<<dim3(NB), 64, 0, stream>>>(CSUM);
  harm_kernel<<<dim3(NCH, NB), 256, 0, stream>>>(FS, CSUM, f0, AMPS, HARM);

  // ---- filtered noise: pack + tables + two MFMA GEMMs ----
  pack_noise<<<dim3((MTOT * 1920 + 255) / 256), 256, 0, stream>>>((uint32_t*)AH, (uint32_t*)AL);
  twfill_pk<<<dim3((3904 * 1920 + 255) / 256), 256, 0, stream>>>(TH32, TL32);
  // fwd: W-side = noise A (1600 rows), X-side = T (3904 rows), K=3840, m-inner order
  gemm_pk<<<dim3(25 * 61), 256, 0, stream>>>(AH, AL, (uint16_t*)TH32, (uint16_t*)TL32,
      nullptr, nullptr, nullptr, SH, SL, KERH, MTOT, 3840, 25, 61, 1, 3, 0);
  gemm_inv<<<dim3(60 * 25), 256, 0, stream>>>(SH, SL, (uint16_t*)TH32, (uint16_t*)TL32, FT);
  ola_kernel<<<dim3((NB * LW + 255) / 256), 256, 0, stream>>>(FT, HARM);

  // ---- time-varying FIR + fold ----
  fir2_kernel<<<dim3(LF, NB), 256, 0, stream>>>(HARM, FILT, OUTF);
  fold_kernel<<<dim3((NB * LW + 255) / 256), 256, 0, stream>>>(OUTF, (float*)d_out);
}

// Round 7
// 1627.625 us; speedup vs baseline: 10.6340x; 1.1691x over previous
//
#include <hip/hip_runtime.h>
#include <hip/hip_bf16.h>
#include <math.h>
#include <stdint.h>

#define FRAME 960
#define NFFT  3840
#define NWIN  1024
#define NFREQ 1921
#define NB    8
#define LF    200
#define LW    192000
#define CIN   450
#define CI    512
#define HID   1536
#define NL    6
#define NCH   188
#define NK2   3842
#define MTOT  1600
#define MB2   3200   // both trunks batched
#define SWID  3968   // padded spec width (31*128)

typedef __attribute__((ext_vector_type(8))) short short8v;
typedef __attribute__((ext_vector_type(4))) float f32x4;
typedef __attribute__((address_space(3))) uint32_t lds_u32;
typedef const __attribute__((address_space(1))) uint32_t glb_u32;

// ---------------- threefry (JAX partitionable) ----------------
__device__ __forceinline__ uint32_t rotl32(uint32_t v, int r) { return (v << r) | (v >> (32 - r)); }
__device__ __forceinline__ void threefry2x32(uint32_t k0, uint32_t k1, uint32_t& x0, uint32_t& x1) {
  uint32_t ks2 = k0 ^ k1 ^ 0x1BD11BDAu;
  x0 += k0; x1 += k1;
#define TFR(r) { x0 += x1; x1 = rotl32(x1, r); x1 ^= x0; }
  TFR(13) TFR(15) TFR(26) TFR(6)  x0 += k1;  x1 += ks2 + 1u;
  TFR(17) TFR(29) TFR(16) TFR(24) x0 += ks2; x1 += k0 + 2u;
  TFR(13) TFR(15) TFR(26) TFR(6)  x0 += k0;  x1 += k1 + 3u;
  TFR(17) TFR(29) TFR(16) TFR(24) x0 += k1;  x1 += ks2 + 4u;
  TFR(13) TFR(15) TFR(26) TFR(6)  x0 += ks2; x1 += k0 + 5u;
#undef TFR
}
__device__ __forceinline__ float noiseval(int b, int m) {
  if (m < 0) m = -m;
  if (m >= LW) m = 2 * LW - 2 - m;
  uint32_t x0 = 0u, x1 = (uint32_t)(b * LW + m);
  threefry2x32(0u, 123u, x0, x1);
  uint32_t bits = x0 ^ x1;
  return __uint_as_float((bits >> 9) | 0x3f800000u) - 1.0f;
}
__device__ __forceinline__ float winf(int j) {
  return 0.5f - 0.5f * cosf((6.283185307179586f * (float)j) / 3840.0f);
}
__device__ __forceinline__ unsigned short f2bf(float v) {
  uint32_t b = __float_as_uint(v);
  return (unsigned short)((b + 0x7FFFu + ((b >> 16) & 1u)) >> 16);
}
__device__ __forceinline__ float bf2f(unsigned short h) {
  return __uint_as_float(((uint32_t)h) << 16);
}
__device__ __forceinline__ uint32_t pack2(float a, float b, bool lo) {
  unsigned short ha = f2bf(a), hb = f2bf(b);
  if (!lo) return (uint32_t)ha | ((uint32_t)hb << 16);
  return (uint32_t)f2bf(a - bf2f(ha)) | ((uint32_t)f2bf(b - bf2f(hb)) << 16);
}
__device__ __forceinline__ int xcd_remap(int lin, int nwg) {
  int q = nwg >> 3, r = nwg & 7;
  int xcd = lin & 7, base = lin >> 3;
  int start = (xcd < r) ? xcd * (q + 1) : r * (q + 1) + (xcd - r) * q;
  return start + base;
}

// ---------------- xin packed, duplicated for both trunks (3200 x 480) ----------------
__global__ void build_xin_pk(const float* __restrict__ content, const float* __restrict__ f0,
                             const float* __restrict__ energy, const float* __restrict__ spk,
                             uint32_t* __restrict__ PH, uint32_t* __restrict__ PL) {
  int idx = blockIdx.x * 256 + threadIdx.x;
  if (idx >= MB2 * 240) return;
  int row = idx / 240, cp = idx % 240;
  int rb = row % MTOT;
  int b = rb / LF, l = rb % LF;
  float v2[2];
#pragma unroll
  for (int u = 0; u < 2; ++u) {
    int c = cp * 2 + u;
    float v = 0.f;
    if (c < 192)       v = content[((size_t)b * 192 + c) * LF + l];
    else if (c < 448)  v = spk[b * 256 + (c - 192)];
    else if (c == 448) v = logf(fmaxf(f0[b * LF + l], 0.0f) + 1e-6f);
    else if (c == 449) v = energy[b * LF + l];
    v2[u] = v;
  }
  PH[idx] = pack2(v2[0], v2[1], false);
  PL[idx] = pack2(v2[0], v2[1], true);
}

// ---------------- weight pack ----------------
__global__ void pack_w(const float* __restrict__ W, uint32_t* __restrict__ PH, uint32_t* __restrict__ PL,
                       int M, int K, int Kp2, int total) {
  int idx = blockIdx.x * 256 + threadIdx.x;
  if (idx >= total) return;
  int m = idx / Kp2, kp = idx % Kp2;
  int k = kp * 2;
  float v0 = (m < M && k < K) ? W[(size_t)m * K + k] : 0.f;
  float v1 = (m < M && (k + 1) < K) ? W[(size_t)m * K + k + 1] : 0.f;
  PH[idx] = pack2(v0, v1, false);
  PL[idx] = pack2(v0, v1, true);
}

// ---------------- packed-bf16 NT GEMM, 64x64 tile, dual-weight-set batched ----------------
__global__ __launch_bounds__(256) void gemm_pk(
    const uint16_t* __restrict__ WH, const uint16_t* __restrict__ WL,
    const uint16_t* __restrict__ XH, const uint16_t* __restrict__ XL,
    const float* __restrict__ bias, const float* __restrict__ bias2,
    const float* __restrict__ res,
    float* __restrict__ outF, uint16_t* __restrict__ outH, uint16_t* __restrict__ outL,
    int M, int Kp, int mtiles, int ntiles, int mode, int act, int nsp, size_t woff)
{
  __shared__ __align__(16) char smem[2][4][4096];
  int nwg = mtiles * ntiles;
  int wg = xcd_remap(blockIdx.x, nwg);
  int mtile = wg / ntiles, ntile = wg % ntiles;
  int m0 = mtile * 64, n0 = ntile * 64;
  int tid = threadIdx.x;
  int lane = tid & 63, w = tid >> 6;
  int wm = w >> 1, wn = w & 1;
  int rowg = Kp >> 3;
  int phases = Kp >> 5;

  const uint16_t* gb = (w == 0) ? WH : (w == 1) ? WL : (w == 2) ? XH : XL;
  if (w < 2 && ntile >= nsp) gb += woff;
  int row0 = (w < 2) ? m0 : n0;
  int sr = lane >> 2, scg = lane & 3;
  int sgsel = scg ^ ((sr >> 1) & 3);
  f32x4 acc[2][2];
#pragma unroll
  for (int i = 0; i < 2; ++i)
#pragma unroll
    for (int j = 0; j < 2; ++j) acc[i][j] = (f32x4){0.f, 0.f, 0.f, 0.f};

  auto stage = [&](int buf, int p) {
    int kg0 = p * 4;
#pragma unroll
    for (int i = 0; i < 4; ++i) {
      int r = i * 16 + sr;
      const uint16_t* src = gb + (size_t)(row0 + r) * rowg * 8 + (size_t)(kg0 + sgsel) * 8;
      __builtin_amdgcn_global_load_lds((glb_u32*)src, (lds_u32*)(&smem[buf][w][0] + i * 1024), 16, 0, 0);
    }
  };

  stage(0, 0);
  __syncthreads();
  int fr = lane & 15, fg = lane >> 4;
  int fsw = ((fr >> 1) & 3);
  int aoff0 = (wm * 32 + fr) * 64 + (fg ^ fsw) * 16;
  int aoff1 = (wm * 32 + 16 + fr) * 64 + (fg ^ fsw) * 16;
  int boff0 = (wn * 32 + fr) * 64 + (fg ^ fsw) * 16;
  int boff1 = (wn * 32 + 16 + fr) * 64 + (fg ^ fsw) * 16;

  for (int p = 0; p < phases; ++p) {
    int cur = p & 1;
    if (p + 1 < phases) stage(cur ^ 1, p + 1);
    short8v ah0 = *(const short8v*)(&smem[cur][0][0] + aoff0);
    short8v ah1 = *(const short8v*)(&smem[cur][0][0] + aoff1);
    short8v al0 = *(const short8v*)(&smem[cur][1][0] + aoff0);
    short8v al1 = *(const short8v*)(&smem[cur][1][0] + aoff1);
    short8v bh0 = *(const short8v*)(&smem[cur][2][0] + boff0);
    short8v bh1 = *(const short8v*)(&smem[cur][2][0] + boff1);
    short8v bl0 = *(const short8v*)(&smem[cur][3][0] + boff0);
    short8v bl1 = *(const short8v*)(&smem[cur][3][0] + boff1);
    acc[0][0] = __builtin_amdgcn_mfma_f32_16x16x32_bf16(ah0, bh0, acc[0][0], 0, 0, 0);
    acc[0][1] = __builtin_amdgcn_mfma_f32_16x16x32_bf16(ah0, bh1, acc[0][1], 0, 0, 0);
    acc[1][0] = __builtin_amdgcn_mfma_f32_16x16x32_bf16(ah1, bh0, acc[1][0], 0, 0, 0);
    acc[1][1] = __builtin_amdgcn_mfma_f32_16x16x32_bf16(ah1, bh1, acc[1][1], 0, 0, 0);
    acc[0][0] = __builtin_amdgcn_mfma_f32_16x16x32_bf16(ah0, bl0, acc[0][0], 0, 0, 0);
    acc[0][1] = __builtin_amdgcn_mfma_f32_16x16x32_bf16(ah0, bl1, acc[0][1], 0, 0, 0);
    acc[1][0] = __builtin_amdgcn_mfma_f32_16x16x32_bf16(ah1, bl0, acc[1][0], 0, 0, 0);
    acc[1][1] = __builtin_amdgcn_mfma_f32_16x16x32_bf16(ah1, bl1, acc[1][1], 0, 0, 0);
    acc[0][0] = __builtin_amdgcn_mfma_f32_16x16x32_bf16(al0, bh0, acc[0][0], 0, 0, 0);
    acc[0][1] = __builtin_amdgcn_mfma_f32_16x16x32_bf16(al0, bh1, acc[0][1], 0, 0, 0);
    acc[1][0] = __builtin_amdgcn_mfma_f32_16x16x32_bf16(al1, bh0, acc[1][0], 0, 0, 0);
    acc[1][1] = __builtin_amdgcn_mfma_f32_16x16x32_bf16(al1, bh1, acc[1][1], 0, 0, 0);
    __syncthreads();
  }

#pragma unroll
  for (int mi = 0; mi < 2; ++mi)
#pragma unroll
    for (int ni = 0; ni < 2; ++ni)
#pragma unroll
      for (int r = 0; r < 4; ++r) {
        int m = m0 + wm * 32 + mi * 16 + ((lane >> 4) << 2) + r;
        int n = n0 + wn * 32 + ni * 16 + (lane & 15);
        if (m >= M) continue;
        float v = acc[mi][ni][r];
        if (bias) v += (bias2 && n >= nsp * 64) ? bias2[m] : bias[m];
        if (act == 1)      v = 0.5f * v * (1.0f + erff(v * 0.7071067811865475f));
        else if (act == 2) v = (v > 0.f ? v : expm1f(v)) + 1.0f;
        if (mode == 0) {
          if (res) v += res[(size_t)n * M + m];
          outF[(size_t)n * M + m] = v;
        } else if (mode == 1) {
          unsigned short h = f2bf(v);
          outH[(size_t)n * M + m] = h;
          outL[(size_t)n * M + m] = f2bf(v - bf2f(h));
        } else {  // 2: KER bf16 (NFREQ row stride)
          outH[(size_t)n * NFREQ + m] = f2bf(v);
        }
      }
}

// ---------------- fwd DFT GEMM: 128x128 tile, 4 waves, wave-per-64x64-quadrant ----------------
__global__ __launch_bounds__(256) void gemm_fwd128(
    const uint16_t* __restrict__ AH, const uint16_t* __restrict__ AL,
    const uint16_t* __restrict__ TH, const uint16_t* __restrict__ TL,
    const uint16_t* __restrict__ KERH,
    uint16_t* __restrict__ SH, uint16_t* __restrict__ SL)
{
  __shared__ __align__(16) char smem[2][4][8192];
  int wg = xcd_remap(blockIdx.x, 13 * 31);
  int ntile = wg / 13, mtile = wg % 13;   // m-inner: T-tile L2-resident
  int m0 = mtile * 128, n0 = ntile * 128;
  int tid = threadIdx.x;
  int lane = tid & 63, w = tid >> 6;
  int wm = w >> 1, wn = w & 1;
  const uint16_t* gb = (w == 0) ? AH : (w == 1) ? AL : (w == 2) ? TH : TL;
  int row0 = (w < 2) ? m0 : n0;
  f32x4 acc[4][4];
#pragma unroll
  for (int i = 0; i < 4; ++i)
#pragma unroll
    for (int j = 0; j < 4; ++j) acc[i][j] = (f32x4){0.f, 0.f, 0.f, 0.f};

  auto stage = [&](int buf, int p) {
#pragma unroll
    for (int i = 0; i < 8; ++i) {
      int gl = i * 64 + lane;
      int row = gl >> 2, cg = gl & 3;
      int sg = cg ^ ((row >> 1) & 3);
      const uint16_t* src = gb + (size_t)(row0 + row) * 3840 + p * 32 + sg * 8;
      __builtin_amdgcn_global_load_lds((glb_u32*)src, (lds_u32*)(&smem[buf][w][0] + i * 1024), 16, 0, 0);
    }
  };

  stage(0, 0);
  __syncthreads();
  int fr = lane & 15, fg = lane >> 4;

  for (int p = 0; p < 120; ++p) {
    int cur = p & 1;
    if (p + 1 < 120) stage(cur ^ 1, p + 1);
    short8v a_h[4], a_l[4], b_h[4], b_l[4];
#pragma unroll
    for (int q = 0; q < 4; ++q) {
      int ra = wm * 64 + q * 16 + fr;
      int oa = ra * 64 + ((fg ^ ((ra >> 1) & 3)) << 4);
      a_h[q] = *(const short8v*)(&smem[cur][0][0] + oa);
      a_l[q] = *(const short8v*)(&smem[cur][1][0] + oa);
      int rb = wn * 64 + q * 16 + fr;
      int ob = rb * 64 + ((fg ^ ((rb >> 1) & 3)) << 4);
      b_h[q] = *(const short8v*)(&smem[cur][2][0] + ob);
      b_l[q] = *(const short8v*)(&smem[cur][3][0] + ob);
    }
#pragma unroll
    for (int mi = 0; mi < 4; ++mi)
#pragma unroll
      for (int ni = 0; ni < 4; ++ni) {
        acc[mi][ni] = __builtin_amdgcn_mfma_f32_16x16x32_bf16(a_h[mi], b_h[ni], acc[mi][ni], 0, 0, 0);
        acc[mi][ni] = __builtin_amdgcn_mfma_f32_16x16x32_bf16(a_h[mi], b_l[ni], acc[mi][ni], 0, 0, 0);
        acc[mi][ni] = __builtin_amdgcn_mfma_f32_16x16x32_bf16(a_l[mi], b_h[ni], acc[mi][ni], 0, 0, 0);
      }
    __syncthreads();
  }

#pragma unroll
  for (int mi = 0; mi < 4; ++mi)
#pragma unroll
    for (int ni = 0; ni < 4; ++ni)
#pragma unroll
      for (int r = 0; r < 4; ++r) {
        int m = m0 + wm * 64 + mi * 16 + ((lane >> 4) << 2) + r;
        int n = n0 + wn * 64 + ni * 16 + (lane & 15);
        if (m < MTOT) {
          float o = 0.f;
          if (n < NK2) {
            int k = n >> 1;
            float kv = bf2f(KERH[(size_t)m * NFREQ + k]);
            bool edge = (k == 0) || (k == 1920);
            float mult = edge ? (1.0f / NFFT) : (2.0f / NFFT);
            o = acc[mi][ni][r] * kv * mult;
            if ((n & 1) && edge) o = 0.f;
          }
          unsigned short h = f2bf(o);
          SH[(size_t)m * SWID + n] = h;
          SL[(size_t)m * SWID + n] = f2bf(o - bf2f(h));
        }
      }
}

// ---------------- inverse DFT GEMM (64x64, T transpose-staged) ----------------
__global__ __launch_bounds__(256) void gemm_inv(
    const uint16_t* __restrict__ SH, const uint16_t* __restrict__ SL,
    const uint16_t* __restrict__ THH, const uint16_t* __restrict__ THL,
    float* __restrict__ ft)
{
  __shared__ __align__(16) char smA[2][2][4096];
  __shared__ __align__(16) uint16_t smB[2][2][64][40];
  int wg = xcd_remap(blockIdx.x, 60 * 25);
  int ntile = wg / 25, mtile = wg % 25;
  int m0 = mtile * 64, n0 = ntile * 64;
  int tid = threadIdx.x;
  int lane = tid & 63, w = tid >> 6;
  int wm = w >> 1, wn = w & 1;
  int sr = lane >> 2, scg = lane & 3;
  int sgsel = scg ^ ((sr >> 1) & 3);
  int bk2 = tid >> 3, bj0 = (tid & 7) * 8;
  int bsw = ((tid & 7) & 3) << 3;
  f32x4 acc[2][2];
#pragma unroll
  for (int i = 0; i < 2; ++i)
#pragma unroll
    for (int j = 0; j < 2; ++j) acc[i][j] = (f32x4){0.f, 0.f, 0.f, 0.f};

  auto stage = [&](int buf, int p) {
    int kg0 = p * 4;
    if (w < 2) {
      const uint16_t* gbs = (w == 0) ? SH : SL;
#pragma unroll
      for (int i = 0; i < 4; ++i) {
        int r = i * 16 + sr;
        const uint16_t* src = gbs + (size_t)(m0 + r) * SWID + (size_t)(kg0 + sgsel) * 8;
        __builtin_amdgcn_global_load_lds((glb_u32*)src, (lds_u32*)(&smA[buf][w][0] + i * 1024), 16, 0, 0);
      }
    }
    int k20 = p * 32;
    const uint16_t* th = THH + (size_t)(k20 + bk2) * 3840 + (n0 + bj0);
    const uint16_t* tl = THL + (size_t)(k20 + bk2) * 3840 + (n0 + bj0);
    uint4 vh = *(const uint4*)th;
    uint4 vl = *(const uint4*)tl;
    int k2s = bk2 ^ bsw;
#pragma unroll
    for (int q = 0; q < 8; ++q) {
      smB[buf][0][bj0 + q][k2s] = ((const uint16_t*)&vh)[q];
      smB[buf][1][bj0 + q][k2s] = ((const uint16_t*)&vl)[q];
    }
  };

  stage(0, 0);
  __syncthreads();
  int fr = lane & 15, fg = lane >> 4;
  int fsw = ((fr >> 1) & 3);
  int aoff0 = (wm * 32 + fr) * 64 + (fg ^ fsw) * 16;
  int aoff1 = (wm * 32 + 16 + fr) * 64 + (fg ^ fsw) * 16;
  int jl0 = wn * 32 + fr;
  int jl1 = wn * 32 + 16 + fr;
  int boff0 = jl0 * 80 + ((fg ^ ((jl0 >> 3) & 3)) << 4);
  int boff1 = jl1 * 80 + ((fg ^ ((jl1 >> 3) & 3)) << 4);

  for (int p = 0; p < 124; ++p) {
    int cur = p & 1;
    if (p + 1 < 124) stage(cur ^ 1, p + 1);
    short8v ah0 = *(const short8v*)(&smA[cur][0][0] + aoff0);
    short8v ah1 = *(const short8v*)(&smA[cur][0][0] + aoff1);
    short8v al0 = *(const short8v*)(&smA[cur][1][0] + aoff0);
    short8v al1 = *(const short8v*)(&smA[cur][1][0] + aoff1);
    short8v bh0 = *(const short8v*)((char*)&smB[cur][0][0][0] + boff0);
    short8v bh1 = *(const short8v*)((char*)&smB[cur][0][0][0] + boff1);
    short8v bl0 = *(const short8v*)((char*)&smB[cur][1][0][0] + boff0);
    short8v bl1 = *(const short8v*)((char*)&smB[cur][1][0][0] + boff1);
    acc[0][0] = __builtin_amdgcn_mfma_f32_16x16x32_bf16(ah0, bh0, acc[0][0], 0, 0, 0);
    acc[0][1] = __builtin_amdgcn_mfma_f32_16x16x32_bf16(ah0, bh1, acc[0][1], 0, 0, 0);
    acc[1][0] = __builtin_amdgcn_mfma_f32_16x16x32_bf16(ah1, bh0, acc[1][0], 0, 0, 0);
    acc[1][1] = __builtin_amdgcn_mfma_f32_16x16x32_bf16(ah1, bh1, acc[1][1], 0, 0, 0);
    acc[0][0] = __builtin_amdgcn_mfma_f32_16x16x32_bf16(ah0, bl0, acc[0][0], 0, 0, 0);
    acc[0][1] = __builtin_amdgcn_mfma_f32_16x16x32_bf16(ah0, bl1, acc[0][1], 0, 0, 0);
    acc[1][0] = __builtin_amdgcn_mfma_f32_16x16x32_bf16(ah1, bl0, acc[1][0], 0, 0, 0);
    acc[1][1] = __builtin_amdgcn_mfma_f32_16x16x32_bf16(ah1, bl1, acc[1][1], 0, 0, 0);
    acc[0][0] = __builtin_amdgcn_mfma_f32_16x16x32_bf16(al0, bh0, acc[0][0], 0, 0, 0);
    acc[0][1] = __builtin_amdgcn_mfma_f32_16x16x32_bf16(al0, bh1, acc[0][1], 0, 0, 0);
    acc[1][0] = __builtin_amdgcn_mfma_f32_16x16x32_bf16(al1, bh0, acc[1][0], 0, 0, 0);
    acc[1][1] = __builtin_amdgcn_mfma_f32_16x16x32_bf16(al1, bh1, acc[1][1], 0, 0, 0);
    __syncthreads();
  }
#pragma unroll
  for (int mi = 0; mi < 2; ++mi)
#pragma unroll
    for (int ni = 0; ni < 2; ++ni)
#pragma unroll
      for (int r = 0; r < 4; ++r) {
        int m = m0 + wm * 32 + mi * 16 + ((lane >> 4) << 2) + r;
        int n = n0 + wn * 32 + ni * 16 + (lane & 15);
        ft[(size_t)m * NFFT + n] = acc[mi][ni][r] * winf(n);
      }
}

// ---------------- LayerNorm rows (1600 rows from base), optional packed out ----------------
__global__ __launch_bounds__(256) void ln2_kernel(float* __restrict__ x, const float* __restrict__ g,
                                                  const float* __restrict__ bta,
                                                  uint32_t* __restrict__ PH, uint32_t* __restrict__ PL) {
  int row = blockIdx.x * 4 + (threadIdx.x >> 6);
  int lane = threadIdx.x & 63;
  float* xr = x + (size_t)row * CI;
  int c0 = lane * 8;
  float4 v0 = *(float4*)&xr[c0], v1 = *(float4*)&xr[c0 + 4];
  float s = v0.x + v0.y + v0.z + v0.w + v1.x + v1.y + v1.z + v1.w;
#pragma unroll
  for (int m = 1; m < 64; m <<= 1) s += __shfl_xor(s, m, 64);
  float mean = s * (1.0f / CI);
  float d[8] = {v0.x - mean, v0.y - mean, v0.z - mean, v0.w - mean,
                v1.x - mean, v1.y - mean, v1.z - mean, v1.w - mean};
  float s2 = 0.f;
#pragma unroll
  for (int q = 0; q < 8; ++q) s2 += d[q] * d[q];
#pragma unroll
  for (int m = 1; m < 64; m <<= 1) s2 += __shfl_xor(s2, m, 64);
  float rs = rsqrtf(s2 * (1.0f / CI) + 1e-5f);
  float o[8];
#pragma unroll
  for (int q = 0; q < 8; ++q) o[q] = d[q] * rs * g[c0 + q] + bta[c0 + q];
  float4 w0 = {o[0], o[1], o[2], o[3]}, w1 = {o[4], o[5], o[6], o[7]};
  *(float4*)&xr[c0] = w0; *(float4*)&xr[c0 + 4] = w1;
  if (PH) {
    int base = (row * CI + c0) >> 1;
#pragma unroll
    for (int q = 0; q < 4; ++q) {
      PH[base + q] = pack2(o[2 * q], o[2 * q + 1], false);
      PL[base + q] = pack2(o[2 * q], o[2 * q + 1], true);
    }
  }
}

// ---------------- fused dwconv K=7 + LN -> packed, dual-trunk batched (grid 3200) ----------------
__global__ __launch_bounds__(256) void dwln_kernel(const float* __restrict__ xs,
    const float* __restrict__ dws, const float* __restrict__ dbs,
    const float* __restrict__ gs, const float* __restrict__ bts,
    const float* __restrict__ dwf, const float* __restrict__ dbf,
    const float* __restrict__ gf, const float* __restrict__ btf,
    uint32_t* __restrict__ PH, uint32_t* __restrict__ PL) {
  int row = blockIdx.x;
  int half = row >= MTOT;
  const float* dw = half ? dwf : dws;
  const float* db = half ? dbf : dbs;
  const float* g  = half ? gf : gs;
  const float* bt = half ? btf : bts;
  int rb = row - half * MTOT;
  int b = rb / LF, l = rb % LF;
  int rbase = half * MTOT + b * LF;
  int c = threadIdx.x * 2;
  float ax = db[c], ay = db[c + 1];
#pragma unroll
  for (int tau = 0; tau < 7; ++tau) {
    int j = l + tau - 3;
    if (j < 0 || j >= LF) continue;
    float2 xv = *(const float2*)&xs[((size_t)(rbase + j)) * CI + c];
    ax = fmaf(xv.x, dw[c * 7 + tau], ax);
    ay = fmaf(xv.y, dw[(c + 1) * 7 + tau], ay);
  }
  __shared__ float red[4], red2[4];
  float s = ax + ay;
#pragma unroll
  for (int m = 1; m < 64; m <<= 1) s += __shfl_xor(s, m, 64);
  if ((threadIdx.x & 63) == 0) red[threadIdx.x >> 6] = s;
  __syncthreads();
  float mean = (red[0] + red[1] + red[2] + red[3]) * (1.0f / CI);
  float dx = ax - mean, dy = ay - mean;
  float s2 = dx * dx + dy * dy;
#pragma unroll
  for (int m = 1; m < 64; m <<= 1) s2 += __shfl_xor(s2, m, 64);
  if ((threadIdx.x & 63) == 0) red2[threadIdx.x >> 6] = s2;
  __syncthreads();
  float var = (red2[0] + red2[1] + red2[2] + red2[3]) * (1.0f / CI);
  float rs = rsqrtf(var + 1e-5f);
  float vx = dx * rs * g[c] + bt[c];
  float vy = dy * rs * g[c + 1] + bt[c + 1];
  PH[(size_t)row * 256 + threadIdx.x] = pack2(vx, vy, false);
  PL[(size_t)row * 256 + threadIdx.x] = pack2(vx, vy, true);
}

// ---------------- amps head (s-trunk rows) ----------------
__global__ __launch_bounds__(256) void amps2_kernel(const float* __restrict__ x, const float* __restrict__ w,
                                                    const float* __restrict__ bias, float* __restrict__ amps) {
  int row = blockIdx.x * 4 + (threadIdx.x >> 6);
  int lane = threadIdx.x & 63;
  const float* xr = x + (size_t)row * CI;
  int c0 = lane * 8;
  float4 v0 = *(const float4*)&xr[c0], v1 = *(const float4*)&xr[c0 + 4];
  float4 w0 = *(const float4*)&w[c0], w1 = *(const float4*)&w[c0 + 4];
  float s = v0.x * w0.x + v0.y * w0.y + v0.z * w0.z + v0.w * w0.w
          + v1.x * w1.x + v1.y * w1.y + v1.z * w1.z + v1.w * w1.w;
#pragma unroll
  for (int m = 1; m < 64; m <<= 1) s += __shfl_xor(s, m, 64);
  if (lane == 0) {
    float a = s + bias[0];
    amps[row] = (a > 0.f ? a : expm1f(a)) + 1.0f;
  }
}

// ---------------- im2col packed (edge pad 3), x = f-trunk base ----------------
__global__ void im2col_pk(const float* __restrict__ x, uint32_t* __restrict__ PH, uint32_t* __restrict__ PL) {
  int idx = blockIdx.x * 256 + threadIdx.x;
  if (idx >= MTOT * 1792) return;
  int row = idx / 1792, kp = idx % 1792;
  int b = row / LF, l = row % LF;
  float v2[2];
#pragma unroll
  for (int u = 0; u < 2; ++u) {
    int kap = kp * 2 + u;
    int ch = kap / 7, tau = kap % 7;
    int j = l + tau - 3;
    j = j < 0 ? 0 : (j > LF - 1 ? LF - 1 : j);
    v2[u] = x[((size_t)b * LF + j) * CI + ch];
  }
  PH[idx] = pack2(v2[0], v2[1], false);
  PL[idx] = pack2(v2[0], v2[1], true);
}

// ---------------- noise*window packed A (1664 x 3840, rows>=1600 zero) ----------------
__global__ void pack_noise(uint32_t* __restrict__ AH, uint32_t* __restrict__ AL) {
  int idx = blockIdx.x * 256 + threadIdx.x;
  if (idx >= 1664 * 1920) return;
  int t = idx / 1920, jp = idx % 1920;
  float v0 = 0.f, v1 = 0.f;
  if (t < MTOT) {
    int b = t / LF, tt = t % LF;
    int j = jp * 2;
    v0 = noiseval(b, tt * 960 + j - 960) * winf(j);
    v1 = noiseval(b, tt * 960 + j - 959) * winf(j + 1);
  }
  AH[idx] = pack2(v0, v1, false);
  AL[idx] = pack2(v0, v1, true);
}

// ---------------- twiddle tables hi/lo (3968 x 3840) ----------------
__global__ void twfill_pk(uint32_t* __restrict__ TH, uint32_t* __restrict__ TL) {
  int idx = blockIdx.x * 256 + threadIdx.x;
  if (idx >= SWID * 1920) return;
  int k2 = idx / 1920, jp = idx % 1920;
  float v2[2] = {0.f, 0.f};
  if (k2 < NK2) {
    int k = k2 >> 1;
#pragma unroll
    for (int u = 0; u < 2; ++u) {
      int j = jp * 2 + u;
      int m = (j * k) % NFFT;
      float ang = (float)m * (6.283185307179586f / 3840.0f);
      v2[u] = (k2 & 1) ? -sinf(ang) : cosf(ang);
    }
  }
  TH[idx] = pack2(v2[0], v2[1], false);
  TL[idx] = pack2(v2[0], v2[1], true);
}

// ---------------- harmonic path ----------------
__global__ void fs_kernel(const float* __restrict__ f0, float* __restrict__ fs) {
  int idx = blockIdx.x * 256 + threadIdx.x;
  if (idx >= NB * LW) return;
  int b = idx / LW, n = idx % LW;
  float pos = ((float)n + 0.5f) * (200.0f / 192000.0f) - 0.5f;
  pos = fminf(fmaxf(pos, 0.0f), 199.0f);
  int i0 = (int)pos;
  int i1 = min(i0 + 1, 199);
  float w = pos - (float)i0;
  fs[idx] = f0[b * LF + i0] * (1.0f - w) + f0[b * LF + i1] * w;
}

__global__ __launch_bounds__(256) void cumsum1(const float* __restrict__ fs, double* __restrict__ csum) {
  int b = blockIdx.y, ch = blockIdx.x;
  const float* fsb = fs + (size_t)b * LW;
  int base = ch * 1024;
  double s = 0.0;
  for (int q = 0; q < 4; ++q) {
    int n = base + threadIdx.x * 4 + q;
    if (n < LW) s += (double)((3.14159274101257324f * fsb[n]) / 48000.0f);
  }
  __shared__ double sh[256];
  sh[threadIdx.x] = s;
  __syncthreads();
  for (int o2 = 128; o2 > 0; o2 >>= 1) {
    if (threadIdx.x < o2) sh[threadIdx.x] += sh[threadIdx.x + o2];
    __syncthreads();
  }
  if (threadIdx.x == 0) csum[b * NCH + ch] = sh[0];
}

__global__ void cumsum2(double* __restrict__ csum) {
  int b = blockIdx.x;
  if (threadIdx.x == 0) {
    double acc = 0.0;
    for (int ch = 0; ch < NCH; ++ch) {
      double v = csum[b * NCH + ch];
      csum[b * NCH + ch] = acc;
      acc += v;
    }
  }
}

__global__ __launch_bounds__(256) void harm_kernel(
    const float* __restrict__ fs, const double* __restrict__ csum,
    const float* __restrict__ f0, const float* __restrict__ amps,
    float* __restrict__ harm) {
  int b = blockIdx.y, ch = blockIdx.x;
  const float* fsb = fs + (size_t)b * LW;
  int base = ch * 1024;
  int tid = threadIdx.x;
  double p[4]; double s = 0.0;
  int n0 = base + tid * 4;
  for (int q = 0; q < 4; ++q) {
    int n = n0 + q; float sm = 0.f;
    if (n < LW) sm = (3.14159274101257324f * fsb[n]) / 48000.0f;
    s += (double)sm; p[q] = s;
  }
  __shared__ double sh[256];
  sh[tid] = s; __syncthreads();
  for (int o2 = 1; o2 < 256; o2 <<= 1) {
    double v = (tid >= o2) ? sh[tid - o2] : 0.0;
    __syncthreads();
    sh[tid] += v;
    __syncthreads();
  }
  double excl = csum[b * NCH + ch] + (tid > 0 ? sh[tid - 1] : 0.0);
  const double PID = (double)3.14159274101257324f;
  for (int q = 0; q < 4; ++q) {
    int n = n0 + q; if (n >= LW) break;
    double S = excl + p[q];
    float pixf = (float)fmod(S, PID);
    float fsv = fsb[n];
    float a = rintf(48000.0f / fmaxf(fsv, 20.0f) * 0.5f) * 2.0f + 1.0f;
    float D = (pixf < 1e-8f) ? 1.0f : (sinf(a * pixf) / (a * sinf(pixf)));
    int ui = n / 960;
    float uv = (f0[b * LF + ui] > 20.0f) ? 1.0f : 0.0f;
    float posA = ((float)n + 0.5f) * (200.0f / 192000.0f) - 0.5f;
    posA = fminf(fmaxf(posA, 0.0f), 199.0f);
    int i0 = (int)posA;
    int i1 = min(i0 + 1, 199);
    float w = posA - (float)i0;
    float ampI = amps[b * LF + i0] * (1.0f - w) + amps[b * LF + i1] * w;
    harm[(size_t)b * LW + n] = (D * uv) * ampI;
  }
}

// ---------------- OLA + wn normalize + add to harm ----------------
__global__ void ola_kernel(const float* __restrict__ ft, float* __restrict__ dsp) {
  int idx = blockIdx.x * 256 + threadIdx.x;
  if (idx >= NB * LW) return;
  int b = idx / LW, n = idx % LW;
  int p = n + 1920;
  int t0 = (p > 3839) ? ((p - 2880) / 960) : 0;
  int t1 = p / FRAME; if (t1 > 200) t1 = 200;
  float y = 0.f, wn = 0.f;
  for (int t = t0; t <= t1; ++t) {
    int j = p - FRAME * t;
    float w = winf(j);
    wn += w * w;
    if (t >= 1) y += ft[((size_t)b * LF + (t - 1)) * NFFT + j];
  }
  float den = wn > 1e-11f ? wn : 1.0f;
  dsp[idx] = dsp[idx] + y / den;
}

// ---------------- per-frame FIR ----------------
__global__ __launch_bounds__(256) void fir2_kernel(const float* __restrict__ dsp,
                                                   const float* __restrict__ filt,
                                                   float* __restrict__ outf) {
  int t = blockIdx.x, b = blockIdx.y;
  __shared__ float frp[3008];
  __shared__ float fl[NWIN];
  int tid = threadIdx.x;
  for (int i = tid; i < 3008; i += 256) frp[i] = 0.f;
  __syncthreads();
  for (int i = tid; i < FRAME; i += 256) frp[1024 + i] = dsp[(size_t)b * LW + (size_t)t * FRAME + i];
  for (int i = tid; i < NWIN; i += 256) fl[i] = filt[((size_t)b * LF + t) * NWIN + i];
  __syncthreads();
  float a[8] = {0.f, 0.f, 0.f, 0.f, 0.f, 0.f, 0.f, 0.f};
  for (int tau = 0; tau < NWIN; ++tau) {
    float fv = fl[tau];
#pragma unroll
    for (int q = 0; q < 8; ++q) a[q] = fmaf(frp[tid + q * 256 + tau], fv, a[q]);
  }
#pragma unroll
  for (int q = 0; q < 8; ++q) {
    int i = tid + q * 256;
    if (i < 1984) outf[((size_t)b * LF + t) * 1984 + i] = a[q];
  }
}

// ---------------- fold ----------------
__global__ void fold_kernel(const float* __restrict__ outf, float* __restrict__ out) {
  int idx = blockIdx.x * 256 + threadIdx.x;
  if (idx >= NB * LW) return;
  int b = idx / LW, n = idx % LW;
  int t0 = (n >= 1984) ? ((n - 1024) / 960) : 0;
  int t1 = n / 960; if (t1 > 199) t1 = 199;
  float acc = 0.f;
  for (int t = t0; t <= t1; ++t)
    acc += outf[((size_t)b * LF + t) * 1984 + (n - 960 * t)];
  out[idx] = acc;
}

extern "C" void kernel_launch(void* const* d_in, const int* in_sizes, int n_in,
                              void* d_out, int out_size, void* d_ws, size_t ws_size,
                              hipStream_t stream) {
  const float* content    = (const float*)d_in[0];
  const float* f0         = (const float*)d_in[1];
  const float* energy     = (const float*)d_in[2];
  const float* spk        = (const float*)d_in[3];
  const float* s_in_w     = (const float*)d_in[4];
  const float* s_in_b     = (const float*)d_in[5];
  const float* s_dw_w     = (const float*)d_in[6];
  const float* s_dw_b     = (const float*)d_in[7];
  const float* s_ln       = (const float*)d_in[8];
  const float* s_pw1_w    = (const float*)d_in[9];
  const float* s_pw1_b    = (const float*)d_in[10];
  const float* s_pw2_w    = (const float*)d_in[11];
  const float* s_pw2_b    = (const float*)d_in[12];
  const float* s_out_norm = (const float*)d_in[13];
  const float* f_in_w     = (const float*)d_in[14];
  const float* f_in_b     = (const float*)d_in[15];
  const float* f_dw_w     = (const float*)d_in[16];
  const float* f_dw_b     = (const float*)d_in[17];
  const float* f_ln       = (const float*)d_in[18];
  const float* f_pw1_w    = (const float*)d_in[19];
  const float* f_pw1_b    = (const float*)d_in[20];
  const float* f_pw2_w    = (const float*)d_in[21];
  const float* f_pw2_b    = (const float*)d_in[22];
  const float* f_out_norm = (const float*)d_in[23];
  const float* s_in_norm  = (const float*)d_in[24];
  const float* s_amp_w    = (const float*)d_in[25];
  const float* s_amp_b    = (const float*)d_in[26];
  const float* s_ker_w    = (const float*)d_in[27];
  const float* s_ker_b    = (const float*)d_in[28];
  const float* f_out_w    = (const float*)d_in[29];
  const float* f_out_b    = (const float*)d_in[30];

  // ---- workspace layout (174.6 MB; proven ws >= 177.58 MB) ----
  char* W0 = (char*)d_ws;
  double*   CSUM  = (double*)W0;                         // 12,032
  uint32_t* XINPH = (uint32_t*)(W0 + 12032);             // 3,072,000
  uint32_t* XINPL = (uint32_t*)(W0 + 3084032);           // 3,072,000
  float*    XS    = (float*)   (W0 + 6156032);           // 6,553,600 (3200 x 512)
  uint32_t* TPH   = (uint32_t*)(W0 + 12709632);          // 3,276,800 (3200 x 256)
  uint32_t* TPL   = (uint32_t*)(W0 + 15986432);          // 3,276,800
  uint16_t* KERH  = (uint16_t*)(W0 + 19263232);          // 6,147,200
  float*    AMPS  = (float*)   (W0 + 25410432);          // 8,192
  float*    FILT  = (float*)   (W0 + 25418624);          // 6,553,600
  float*    HARM  = (float*)   (W0 + 31972224);          // 6,144,000
  char*     R2    = W0 + 38116224;                       // 25,395,200
  char*     FTR   = W0 + 63511424;                       // 24,576,000
  char*     U     = W0 + 88087424;                       // 25,559,040
  uint32_t* TH32  = (uint32_t*)(W0 + 113646464);         // 30,474,240
  uint32_t* TL32  = (uint32_t*)(W0 + 144120704);         // 30,474,240 -> ends 174,594,944
  // overlays
  uint32_t* XSPH = TPH;                                  // 1,638,400 (after trunk, TP dead)
  uint32_t* XSPL = (uint32_t*)((char*)TPH + 1638400);
  uint32_t* H15PH = (uint32_t*)R2;                       // 9,830,400 (3200 x 768)
  uint32_t* H15PL = (uint32_t*)(R2 + 9830400);
  uint32_t* IMPH = (uint32_t*)R2;                        // 11,468,800 (after H15 dead)
  uint32_t* IMPL = (uint32_t*)(R2 + 11468800);
  uint16_t* SH   = (uint16_t*)R2;                        // 12,697,600 (after IMP dead)
  uint16_t* SL   = (uint16_t*)(R2 + 12697600);
  float*    OUTF = (float*)R2;                           // 12,697,600 (after SH/SL dead)
  float*    FS   = (float*)FTR;                          // 6,144,000
  float*    FT   = (float*)FTR;                          // 24,576,000 (after FS dead)
  uint32_t* WPH  = (uint32_t*)U;                         // 7,340,032
  uint32_t* WPL  = (uint32_t*)(U + 7340032);
  uint16_t* AH   = (uint16_t*)U;                         // 12,779,520 (after WP dead)
  uint16_t* AL   = (uint16_t*)(U + 12779520);

  (void)in_sizes; (void)n_in; (void)out_size; (void)ws_size;

  build_xin_pk<<<dim3((MB2 * 240 + 255) / 256), 256, 0, stream>>>(content, f0, energy, spk, XINPH, XINPL);

  auto pw1set = [&](const float* Wm, int M, int K, int Mp, int Kp) {
    int total = Mp * (Kp / 2);
    pack_w<<<dim3((total + 255) / 256), 256, 0, stream>>>(Wm, WPH, WPL, M, K, Kp / 2, total);
  };
  auto pw2sets = [&](const float* Ws, const float* Wf, int M, int K, int Mp, int Kp) {
    int total = Mp * (Kp / 2);
    pack_w<<<dim3((total + 255) / 256), 256, 0, stream>>>(Ws, WPH, WPL, M, K, Kp / 2, total);
    pack_w<<<dim3((total + 255) / 256), 256, 0, stream>>>(Wf, WPH + total, WPL + total, M, K, Kp / 2, total);
  };

  // ---- batched dual-trunk ----
  pw2sets(s_in_w, f_in_w, CI, CIN, CI, 480);
  gemm_pk<<<dim3(8 * 50), 256, 0, stream>>>((uint16_t*)WPH, (uint16_t*)WPL, (uint16_t*)XINPH, (uint16_t*)XINPL,
      s_in_b, f_in_b, nullptr, XS, nullptr, nullptr, CI, 480, 8, 50, 0, 0, 25, (size_t)512 * 480);
  ln2_kernel<<<dim3(MTOT / 4), 256, 0, stream>>>(XS, s_in_norm, s_in_norm + CI, nullptr, nullptr);
  for (int i = 0; i < NL; ++i) {
    dwln_kernel<<<dim3(MB2), 256, 0, stream>>>(XS,
        s_dw_w + (size_t)i * CI * 7, s_dw_b + (size_t)i * CI,
        s_ln + (size_t)(i * 2) * CI, s_ln + (size_t)(i * 2 + 1) * CI,
        f_dw_w + (size_t)i * CI * 7, f_dw_b + (size_t)i * CI,
        f_ln + (size_t)(i * 2) * CI, f_ln + (size_t)(i * 2 + 1) * CI,
        TPH, TPL);
    pw2sets(s_pw1_w + (size_t)i * HID * CI, f_pw1_w + (size_t)i * HID * CI, HID, CI, HID, 512);
    gemm_pk<<<dim3(24 * 50), 256, 0, stream>>>((uint16_t*)WPH, (uint16_t*)WPL, (uint16_t*)TPH, (uint16_t*)TPL,
        s_pw1_b + (size_t)i * HID, f_pw1_b + (size_t)i * HID, nullptr,
        nullptr, (uint16_t*)H15PH, (uint16_t*)H15PL, HID, 512, 24, 50, 1, 1, 25, (size_t)1536 * 512);
    pw2sets(s_pw2_w + (size_t)i * CI * HID, f_pw2_w + (size_t)i * CI * HID, CI, HID, CI, 1536);
    gemm_pk<<<dim3(8 * 50), 256, 0, stream>>>((uint16_t*)WPH, (uint16_t*)WPL, (uint16_t*)H15PH, (uint16_t*)H15PL,
        s_pw2_b + (size_t)i * CI, f_pw2_b + (size_t)i * CI, XS,
        XS, nullptr, nullptr, CI, 1536, 8, 50, 0, 0, 25, (size_t)512 * 1536);
  }

  // ---- heads ----
  ln2_kernel<<<dim3(MTOT / 4), 256, 0, stream>>>(XS, s_out_norm, s_out_norm + CI, XSPH, XSPL);
  amps2_kernel<<<dim3(MTOT / 4), 256, 0, stream>>>(XS, s_amp_w, s_amp_b, AMPS);
  pw1set(s_ker_w, NFREQ, CI, 1984, 512);
  gemm_pk<<<dim3(31 * 25), 256, 0, stream>>>((uint16_t*)WPH, (uint16_t*)WPL, (uint16_t*)XSPH, (uint16_t*)XSPL,
      s_ker_b, nullptr, nullptr, nullptr, KERH, nullptr, NFREQ, 512, 31, 25, 2, 2, 1000, 0);

  ln2_kernel<<<dim3(MTOT / 4), 256, 0, stream>>>(XS + (size_t)MTOT * CI, f_out_norm, f_out_norm + CI, nullptr, nullptr);
  im2col_pk<<<dim3((MTOT * 1792 + 255) / 256), 256, 0, stream>>>(XS + (size_t)MTOT * CI, IMPH, IMPL);
  pw1set(f_out_w, NWIN, 3584, NWIN, 3584);
  gemm_pk<<<dim3(16 * 25), 256, 0, stream>>>((uint16_t*)WPH, (uint16_t*)WPL, (uint16_t*)IMPH, (uint16_t*)IMPL,
      f_out_b, nullptr, nullptr, FILT, nullptr, nullptr, NWIN, 3584, 16, 25, 0, 0, 1000, 0);

  // ---- harmonic source ----
  fs_kernel<<<dim3((NB * LW + 255) / 256), 256, 0, stream>>>(f0, FS);
  cumsum1<<<dim3(NCH, NB), 256, 0, stream>>>(FS, CSUM);
  cumsum2<<<dim3(NB), 64, 0, stream>>>(CSUM);
  harm_kernel<<<dim3(NCH, NB), 256, 0, stream>>>(FS, CSUM, f0, AMPS, HARM);

  // ---- filtered noise ----
  pack_noise<<<dim3((1664 * 1920 + 255) / 256), 256, 0, stream>>>((uint32_t*)AH, (uint32_t*)AL);
  twfill_pk<<<dim3((SWID * 1920 + 255) / 256), 256, 0, stream>>>(TH32, TL32);
  gemm_fwd128<<<dim3(13 * 31), 256, 0, stream>>>(AH, AL, (uint16_t*)TH32, (uint16_t*)TL32, KERH, SH, SL);
  gemm_inv<<<dim3(60 * 25), 256, 0, stream>>>(SH, SL, (uint16_t*)TH32, (uint16_t*)TL32, FT);
  ola_kernel<<<dim3((NB * LW + 255) / 256), 256, 0, stream>>>(FT, HARM);

  // ---- FIR + fold ----
  fir2_kernel<<<dim3(LF, NB), 256, 0, stream>>>(HARM, FILT, OUTF);
  fold_kernel<<<dim3((NB * LW + 255) / 256), 256, 0, stream>>>(OUTF, (float*)d_out);
}

// Round 8
// 1599.439 us; speedup vs baseline: 10.8214x; 1.0176x over previous
//
#include <hip/hip_runtime.h>
#include <hip/hip_bf16.h>
#include <math.h>
#include <stdint.h>

#define FRAME 960
#define NFFT  3840
#define NWIN  1024
#define NFREQ 1921
#define NB    8
#define LF    200
#define LW    192000
#define CIN   450
#define CI    512
#define HID   1536
#define NL    6
#define NCH   188
#define NK2   3842
#define MTOT  1600
#define MB2   3200   // both trunks batched
#define SWID  3968   // padded spec width (31*128)
#define MPAD  1664   // padded frame rows (13*128)

typedef __attribute__((ext_vector_type(8))) short short8v;
typedef __attribute__((ext_vector_type(4))) float f32x4;
typedef __attribute__((address_space(3))) uint32_t lds_u32;
typedef const __attribute__((address_space(1))) uint32_t glb_u32;

// ---------------- threefry (JAX partitionable) ----------------
__device__ __forceinline__ uint32_t rotl32(uint32_t v, int r) { return (v << r) | (v >> (32 - r)); }
__device__ __forceinline__ void threefry2x32(uint32_t k0, uint32_t k1, uint32_t& x0, uint32_t& x1) {
  uint32_t ks2 = k0 ^ k1 ^ 0x1BD11BDAu;
  x0 += k0; x1 += k1;
#define TFR(r) { x0 += x1; x1 = rotl32(x1, r); x1 ^= x0; }
  TFR(13) TFR(15) TFR(26) TFR(6)  x0 += k1;  x1 += ks2 + 1u;
  TFR(17) TFR(29) TFR(16) TFR(24) x0 += ks2; x1 += k0 + 2u;
  TFR(13) TFR(15) TFR(26) TFR(6)  x0 += k0;  x1 += k1 + 3u;
  TFR(17) TFR(29) TFR(16) TFR(24) x0 += k1;  x1 += ks2 + 4u;
  TFR(13) TFR(15) TFR(26) TFR(6)  x0 += ks2; x1 += k0 + 5u;
#undef TFR
}
__device__ __forceinline__ float noiseval(int b, int m) {
  if (m < 0) m = -m;
  if (m >= LW) m = 2 * LW - 2 - m;
  uint32_t x0 = 0u, x1 = (uint32_t)(b * LW + m);
  threefry2x32(0u, 123u, x0, x1);
  uint32_t bits = x0 ^ x1;
  return __uint_as_float((bits >> 9) | 0x3f800000u) - 1.0f;
}
__device__ __forceinline__ float winf(int j) {
  return 0.5f - 0.5f * cosf((6.283185307179586f * (float)j) / 3840.0f);
}
__device__ __forceinline__ unsigned short f2bf(float v) {
  uint32_t b = __float_as_uint(v);
  return (unsigned short)((b + 0x7FFFu + ((b >> 16) & 1u)) >> 16);
}
__device__ __forceinline__ float bf2f(unsigned short h) {
  return __uint_as_float(((uint32_t)h) << 16);
}
__device__ __forceinline__ uint32_t pack2(float a, float b, bool lo) {
  unsigned short ha = f2bf(a), hb = f2bf(b);
  if (!lo) return (uint32_t)ha | ((uint32_t)hb << 16);
  return (uint32_t)f2bf(a - bf2f(ha)) | ((uint32_t)f2bf(b - bf2f(hb)) << 16);
}
__device__ __forceinline__ int xcd_remap(int lin, int nwg) {
  int q = nwg >> 3, r = nwg & 7;
  int xcd = lin & 7, base = lin >> 3;
  int start = (xcd < r) ? xcd * (q + 1) : r * (q + 1) + (xcd - r) * q;
  return start + base;
}

// ---------------- xin packed, duplicated for both trunks (3200 x 480) ----------------
__global__ void build_xin_pk(const float* __restrict__ content, const float* __restrict__ f0,
                             const float* __restrict__ energy, const float* __restrict__ spk,
                             uint32_t* __restrict__ PH, uint32_t* __restrict__ PL) {
  int idx = blockIdx.x * 256 + threadIdx.x;
  if (idx >= MB2 * 240) return;
  int row = idx / 240, cp = idx % 240;
  int rb = row % MTOT;
  int b = rb / LF, l = rb % LF;
  float v2[2];
#pragma unroll
  for (int u = 0; u < 2; ++u) {
    int c = cp * 2 + u;
    float v = 0.f;
    if (c < 192)       v = content[((size_t)b * 192 + c) * LF + l];
    else if (c < 448)  v = spk[b * 256 + (c - 192)];
    else if (c == 448) v = logf(fmaxf(f0[b * LF + l], 0.0f) + 1e-6f);
    else if (c == 449) v = energy[b * LF + l];
    v2[u] = v;
  }
  PH[idx] = pack2(v2[0], v2[1], false);
  PL[idx] = pack2(v2[0], v2[1], true);
}

// ---------------- weight pack ----------------
__global__ void pack_w(const float* __restrict__ W, uint32_t* __restrict__ PH, uint32_t* __restrict__ PL,
                       int M, int K, int Kp2, int total) {
  int idx = blockIdx.x * 256 + threadIdx.x;
  if (idx >= total) return;
  int m = idx / Kp2, kp = idx % Kp2;
  int k = kp * 2;
  float v0 = (m < M && k < K) ? W[(size_t)m * K + k] : 0.f;
  float v1 = (m < M && (k + 1) < K) ? W[(size_t)m * K + k + 1] : 0.f;
  PH[idx] = pack2(v0, v1, false);
  PL[idx] = pack2(v0, v1, true);
}

// ---------------- packed-bf16 NT GEMM, 64x64 tile, dual-weight-set batched ----------------
__global__ __launch_bounds__(256) void gemm_pk(
    const uint16_t* __restrict__ WH, const uint16_t* __restrict__ WL,
    const uint16_t* __restrict__ XH, const uint16_t* __restrict__ XL,
    const float* __restrict__ bias, const float* __restrict__ bias2,
    const float* __restrict__ res,
    float* __restrict__ outF, uint16_t* __restrict__ outH, uint16_t* __restrict__ outL,
    int M, int Kp, int mtiles, int ntiles, int mode, int act, int nsp, size_t woff)
{
  __shared__ __align__(16) char smem[2][4][4096];
  int nwg = mtiles * ntiles;
  int wg = xcd_remap(blockIdx.x, nwg);
  int mtile = wg / ntiles, ntile = wg % ntiles;
  int m0 = mtile * 64, n0 = ntile * 64;
  int tid = threadIdx.x;
  int lane = tid & 63, w = tid >> 6;
  int wm = w >> 1, wn = w & 1;
  int rowg = Kp >> 3;
  int phases = Kp >> 5;

  const uint16_t* gb = (w == 0) ? WH : (w == 1) ? WL : (w == 2) ? XH : XL;
  if (w < 2 && ntile >= nsp) gb += woff;
  int row0 = (w < 2) ? m0 : n0;
  int sr = lane >> 2, scg = lane & 3;
  int sgsel = scg ^ ((sr >> 1) & 3);
  f32x4 acc[2][2];
#pragma unroll
  for (int i = 0; i < 2; ++i)
#pragma unroll
    for (int j = 0; j < 2; ++j) acc[i][j] = (f32x4){0.f, 0.f, 0.f, 0.f};

  auto stage = [&](int buf, int p) {
    int kg0 = p * 4;
#pragma unroll
    for (int i = 0; i < 4; ++i) {
      int r = i * 16 + sr;
      const uint16_t* src = gb + (size_t)(row0 + r) * rowg * 8 + (size_t)(kg0 + sgsel) * 8;
      __builtin_amdgcn_global_load_lds((glb_u32*)src, (lds_u32*)(&smem[buf][w][0] + i * 1024), 16, 0, 0);
    }
  };

  stage(0, 0);
  __syncthreads();
  int fr = lane & 15, fg = lane >> 4;
  int fsw = ((fr >> 1) & 3);
  int aoff0 = (wm * 32 + fr) * 64 + (fg ^ fsw) * 16;
  int aoff1 = (wm * 32 + 16 + fr) * 64 + (fg ^ fsw) * 16;
  int boff0 = (wn * 32 + fr) * 64 + (fg ^ fsw) * 16;
  int boff1 = (wn * 32 + 16 + fr) * 64 + (fg ^ fsw) * 16;

  for (int p = 0; p < phases; ++p) {
    int cur = p & 1;
    if (p + 1 < phases) stage(cur ^ 1, p + 1);
    short8v ah0 = *(const short8v*)(&smem[cur][0][0] + aoff0);
    short8v ah1 = *(const short8v*)(&smem[cur][0][0] + aoff1);
    short8v al0 = *(const short8v*)(&smem[cur][1][0] + aoff0);
    short8v al1 = *(const short8v*)(&smem[cur][1][0] + aoff1);
    short8v bh0 = *(const short8v*)(&smem[cur][2][0] + boff0);
    short8v bh1 = *(const short8v*)(&smem[cur][2][0] + boff1);
    short8v bl0 = *(const short8v*)(&smem[cur][3][0] + boff0);
    short8v bl1 = *(const short8v*)(&smem[cur][3][0] + boff1);
    acc[0][0] = __builtin_amdgcn_mfma_f32_16x16x32_bf16(ah0, bh0, acc[0][0], 0, 0, 0);
    acc[0][1] = __builtin_amdgcn_mfma_f32_16x16x32_bf16(ah0, bh1, acc[0][1], 0, 0, 0);
    acc[1][0] = __builtin_amdgcn_mfma_f32_16x16x32_bf16(ah1, bh0, acc[1][0], 0, 0, 0);
    acc[1][1] = __builtin_amdgcn_mfma_f32_16x16x32_bf16(ah1, bh1, acc[1][1], 0, 0, 0);
    acc[0][0] = __builtin_amdgcn_mfma_f32_16x16x32_bf16(ah0, bl0, acc[0][0], 0, 0, 0);
    acc[0][1] = __builtin_amdgcn_mfma_f32_16x16x32_bf16(ah0, bl1, acc[0][1], 0, 0, 0);
    acc[1][0] = __builtin_amdgcn_mfma_f32_16x16x32_bf16(ah1, bl0, acc[1][0], 0, 0, 0);
    acc[1][1] = __builtin_amdgcn_mfma_f32_16x16x32_bf16(ah1, bl1, acc[1][1], 0, 0, 0);
    acc[0][0] = __builtin_amdgcn_mfma_f32_16x16x32_bf16(al0, bh0, acc[0][0], 0, 0, 0);
    acc[0][1] = __builtin_amdgcn_mfma_f32_16x16x32_bf16(al0, bh1, acc[0][1], 0, 0, 0);
    acc[1][0] = __builtin_amdgcn_mfma_f32_16x16x32_bf16(al1, bh0, acc[1][0], 0, 0, 0);
    acc[1][1] = __builtin_amdgcn_mfma_f32_16x16x32_bf16(al1, bh1, acc[1][1], 0, 0, 0);
    __syncthreads();
  }

#pragma unroll
  for (int mi = 0; mi < 2; ++mi)
#pragma unroll
    for (int ni = 0; ni < 2; ++ni)
#pragma unroll
      for (int r = 0; r < 4; ++r) {
        int m = m0 + wm * 32 + mi * 16 + ((lane >> 4) << 2) + r;
        int n = n0 + wn * 32 + ni * 16 + (lane & 15);
        if (m >= M) continue;
        float v = acc[mi][ni][r];
        if (bias) v += (bias2 && n >= nsp * 64) ? bias2[m] : bias[m];
        if (act == 1)      v = 0.5f * v * (1.0f + erff(v * 0.7071067811865475f));
        else if (act == 2) v = (v > 0.f ? v : expm1f(v)) + 1.0f;
        if (mode == 0) {
          if (res) v += res[(size_t)n * M + m];
          outF[(size_t)n * M + m] = v;
        } else if (mode == 1) {
          unsigned short h = f2bf(v);
          outH[(size_t)n * M + m] = h;
          outL[(size_t)n * M + m] = f2bf(v - bf2f(h));
        } else {  // 2: KER bf16 (NFREQ row stride)
          outH[(size_t)n * NFREQ + m] = f2bf(v);
        }
      }
}

// ---------------- fwd DFT GEMM: 128x128 tile, 4 waves, wave-per-64x64-quadrant ----------------
__global__ __launch_bounds__(256) void gemm_fwd128(
    const uint16_t* __restrict__ AH, const uint16_t* __restrict__ AL,
    const uint16_t* __restrict__ TH, const uint16_t* __restrict__ TL,
    const uint16_t* __restrict__ KERH,
    uint16_t* __restrict__ SH, uint16_t* __restrict__ SL)
{
  __shared__ __align__(16) char smem[2][4][8192];
  int wg = xcd_remap(blockIdx.x, 13 * 31);
  int ntile = wg / 13, mtile = wg % 13;   // m-inner: T-tile L2-resident
  int m0 = mtile * 128, n0 = ntile * 128;
  int tid = threadIdx.x;
  int lane = tid & 63, w = tid >> 6;
  int wm = w >> 1, wn = w & 1;
  const uint16_t* gb = (w == 0) ? AH : (w == 1) ? AL : (w == 2) ? TH : TL;
  int row0 = (w < 2) ? m0 : n0;
  f32x4 acc[4][4];
#pragma unroll
  for (int i = 0; i < 4; ++i)
#pragma unroll
    for (int j = 0; j < 4; ++j) acc[i][j] = (f32x4){0.f, 0.f, 0.f, 0.f};

  auto stage = [&](int buf, int p) {
#pragma unroll
    for (int i = 0; i < 8; ++i) {
      int gl = i * 64 + lane;
      int row = gl >> 2, cg = gl & 3;
      int sg = cg ^ ((row >> 1) & 3);
      const uint16_t* src = gb + (size_t)(row0 + row) * 3840 + p * 32 + sg * 8;
      __builtin_amdgcn_global_load_lds((glb_u32*)src, (lds_u32*)(&smem[buf][w][0] + i * 1024), 16, 0, 0);
    }
  };

  stage(0, 0);
  __syncthreads();
  int fr = lane & 15, fg = lane >> 4;

  for (int p = 0; p < 120; ++p) {
    int cur = p & 1;
    if (p + 1 < 120) stage(cur ^ 1, p + 1);
    short8v a_h[4], a_l[4], b_h[4], b_l[4];
#pragma unroll
    for (int q = 0; q < 4; ++q) {
      int ra = wm * 64 + q * 16 + fr;
      int oa = ra * 64 + ((fg ^ ((ra >> 1) & 3)) << 4);
      a_h[q] = *(const short8v*)(&smem[cur][0][0] + oa);
      a_l[q] = *(const short8v*)(&smem[cur][1][0] + oa);
      int rb = wn * 64 + q * 16 + fr;
      int ob = rb * 64 + ((fg ^ ((rb >> 1) & 3)) << 4);
      b_h[q] = *(const short8v*)(&smem[cur][2][0] + ob);
      b_l[q] = *(const short8v*)(&smem[cur][3][0] + ob);
    }
#pragma unroll
    for (int mi = 0; mi < 4; ++mi)
#pragma unroll
      for (int ni = 0; ni < 4; ++ni) {
        acc[mi][ni] = __builtin_amdgcn_mfma_f32_16x16x32_bf16(a_h[mi], b_h[ni], acc[mi][ni], 0, 0, 0);
        acc[mi][ni] = __builtin_amdgcn_mfma_f32_16x16x32_bf16(a_h[mi], b_l[ni], acc[mi][ni], 0, 0, 0);
        acc[mi][ni] = __builtin_amdgcn_mfma_f32_16x16x32_bf16(a_l[mi], b_h[ni], acc[mi][ni], 0, 0, 0);
      }
    __syncthreads();
  }

#pragma unroll
  for (int mi = 0; mi < 4; ++mi)
#pragma unroll
    for (int ni = 0; ni < 4; ++ni)
#pragma unroll
      for (int r = 0; r < 4; ++r) {
        int m = m0 + wm * 64 + mi * 16 + ((lane >> 4) << 2) + r;
        int n = n0 + wn * 64 + ni * 16 + (lane & 15);
        if (m < MTOT) {
          float o = 0.f;
          if (n < NK2) {
            int k = n >> 1;
            float kv = bf2f(KERH[(size_t)m * NFREQ + k]);
            bool edge = (k == 0) || (k == 1920);
            float mult = edge ? (1.0f / NFFT) : (2.0f / NFFT);
            o = acc[mi][ni][r] * kv * mult;
            if ((n & 1) && edge) o = 0.f;
          }
          unsigned short h = f2bf(o);
          SH[(size_t)m * SWID + n] = h;
          SL[(size_t)m * SWID + n] = f2bf(o - bf2f(h));
        }
      }
}

// ---------------- inverse DFT GEMM: 128x128 tile, T transpose-staged w/ granule-XOR ----------------
__global__ __launch_bounds__(256) void gemm_inv128(
    const uint16_t* __restrict__ SH, const uint16_t* __restrict__ SL,
    const uint16_t* __restrict__ THH, const uint16_t* __restrict__ THL,
    float* __restrict__ ft)
{
  __shared__ __align__(16) char smA[2][2][8192];        // [buf][hi/lo] 128 rows x 32 k2
  __shared__ __align__(16) uint16_t smB[2][2][128][32]; // [buf][hi/lo][j][k2 granule-XOR]
  int wg = xcd_remap(blockIdx.x, 30 * 13);
  int ntile = wg / 13, mtile = wg % 13;   // m-inner: T column-slice L2-resident
  int m0 = mtile * 128, n0 = ntile * 128;
  int tid = threadIdx.x;
  int lane = tid & 63, w = tid >> 6;
  int wm = w >> 1, wn = w & 1;
  f32x4 acc[4][4];
#pragma unroll
  for (int i = 0; i < 4; ++i)
#pragma unroll
    for (int j = 0; j < 4; ++j) acc[i][j] = (f32x4){0.f, 0.f, 0.f, 0.f};

  int bk2 = tid >> 3;            // 0..31
  int bj0 = (tid & 7) * 16;      // j group of 16
  int gk = bk2 >> 3, ek = bk2 & 7;

  auto stage = [&](int buf, int p) {
    if (w < 2) {
      const uint16_t* gbs = (w == 0) ? SH : SL;
#pragma unroll
      for (int i = 0; i < 8; ++i) {
        int gl = i * 64 + lane;
        int row = gl >> 2, cg = gl & 3;
        int sg = cg ^ ((row >> 1) & 3);
        const uint16_t* src = gbs + (size_t)(m0 + row) * SWID + p * 32 + sg * 8;
        __builtin_amdgcn_global_load_lds((glb_u32*)src, (lds_u32*)(&smA[buf][w][0] + i * 1024), 16, 0, 0);
      }
    }
    int k20 = p * 32;
    const uint16_t* th = THH + (size_t)(k20 + bk2) * 3840 + (n0 + bj0);
    const uint16_t* tl = THL + (size_t)(k20 + bk2) * 3840 + (n0 + bj0);
    uint4 vh0 = *(const uint4*)th;
    uint4 vh1 = *(const uint4*)(th + 8);
    uint4 vl0 = *(const uint4*)tl;
    uint4 vl1 = *(const uint4*)(tl + 8);
#pragma unroll
    for (int q = 0; q < 8; ++q) {
      int j = bj0 + q;
      int col = ((gk ^ (j & 3)) << 3) + ek;
      smB[buf][0][j][col] = ((const uint16_t*)&vh0)[q];
      smB[buf][1][j][col] = ((const uint16_t*)&vl0)[q];
    }
#pragma unroll
    for (int q = 0; q < 8; ++q) {
      int j = bj0 + 8 + q;
      int col = ((gk ^ (j & 3)) << 3) + ek;
      smB[buf][0][j][col] = ((const uint16_t*)&vh1)[q];
      smB[buf][1][j][col] = ((const uint16_t*)&vl1)[q];
    }
  };

  stage(0, 0);
  __syncthreads();
  int fr = lane & 15, fg = lane >> 4;

  for (int p = 0; p < 124; ++p) {
    int cur = p & 1;
    if (p + 1 < 124) stage(cur ^ 1, p + 1);
    short8v a_h[4], a_l[4], b_h[4], b_l[4];
#pragma unroll
    for (int q = 0; q < 4; ++q) {
      int ra = wm * 64 + q * 16 + fr;
      int oa = ra * 64 + ((fg ^ ((ra >> 1) & 3)) << 4);
      a_h[q] = *(const short8v*)(&smA[cur][0][0] + oa);
      a_l[q] = *(const short8v*)(&smA[cur][1][0] + oa);
      int jb = wn * 64 + q * 16 + fr;
      int ob = (fg ^ (jb & 3)) << 4;
      b_h[q] = *(const short8v*)((const char*)&smB[cur][0][jb][0] + ob);
      b_l[q] = *(const short8v*)((const char*)&smB[cur][1][jb][0] + ob);
    }
#pragma unroll
    for (int mi = 0; mi < 4; ++mi)
#pragma unroll
      for (int ni = 0; ni < 4; ++ni) {
        acc[mi][ni] = __builtin_amdgcn_mfma_f32_16x16x32_bf16(a_h[mi], b_h[ni], acc[mi][ni], 0, 0, 0);
        acc[mi][ni] = __builtin_amdgcn_mfma_f32_16x16x32_bf16(a_h[mi], b_l[ni], acc[mi][ni], 0, 0, 0);
        acc[mi][ni] = __builtin_amdgcn_mfma_f32_16x16x32_bf16(a_l[mi], b_h[ni], acc[mi][ni], 0, 0, 0);
      }
    __syncthreads();
  }

#pragma unroll
  for (int mi = 0; mi < 4; ++mi)
#pragma unroll
    for (int ni = 0; ni < 4; ++ni)
#pragma unroll
      for (int r = 0; r < 4; ++r) {
        int m = m0 + wm * 64 + mi * 16 + ((lane >> 4) << 2) + r;
        int n = n0 + wn * 64 + ni * 16 + (lane & 15);
        if (m < MTOT) ft[(size_t)m * NFFT + n] = acc[mi][ni][r] * winf(n);
      }
}

// ---------------- LayerNorm rows, optional packed out ----------------
__global__ __launch_bounds__(256) void ln2_kernel(float* __restrict__ x, const float* __restrict__ g,
                                                  const float* __restrict__ bta,
                                                  uint32_t* __restrict__ PH, uint32_t* __restrict__ PL) {
  int row = blockIdx.x * 4 + (threadIdx.x >> 6);
  int lane = threadIdx.x & 63;
  float* xr = x + (size_t)row * CI;
  int c0 = lane * 8;
  float4 v0 = *(float4*)&xr[c0], v1 = *(float4*)&xr[c0 + 4];
  float s = v0.x + v0.y + v0.z + v0.w + v1.x + v1.y + v1.z + v1.w;
#pragma unroll
  for (int m = 1; m < 64; m <<= 1) s += __shfl_xor(s, m, 64);
  float mean = s * (1.0f / CI);
  float d[8] = {v0.x - mean, v0.y - mean, v0.z - mean, v0.w - mean,
                v1.x - mean, v1.y - mean, v1.z - mean, v1.w - mean};
  float s2 = 0.f;
#pragma unroll
  for (int q = 0; q < 8; ++q) s2 += d[q] * d[q];
#pragma unroll
  for (int m = 1; m < 64; m <<= 1) s2 += __shfl_xor(s2, m, 64);
  float rs = rsqrtf(s2 * (1.0f / CI) + 1e-5f);
  float o[8];
#pragma unroll
  for (int q = 0; q < 8; ++q) o[q] = d[q] * rs * g[c0 + q] + bta[c0 + q];
  float4 w0 = {o[0], o[1], o[2], o[3]}, w1 = {o[4], o[5], o[6], o[7]};
  *(float4*)&xr[c0] = w0; *(float4*)&xr[c0 + 4] = w1;
  if (PH) {
    int base = (row * CI + c0) >> 1;
#pragma unroll
    for (int q = 0; q < 4; ++q) {
      PH[base + q] = pack2(o[2 * q], o[2 * q + 1], false);
      PL[base + q] = pack2(o[2 * q], o[2 * q + 1], true);
    }
  }
}

// ---------------- fused dwconv K=7 + LN -> packed, dual-trunk batched ----------------
__global__ __launch_bounds__(256) void dwln_kernel(const float* __restrict__ xs,
    const float* __restrict__ dws, const float* __restrict__ dbs,
    const float* __restrict__ gs, const float* __restrict__ bts,
    const float* __restrict__ dwf, const float* __restrict__ dbf,
    const float* __restrict__ gf, const float* __restrict__ btf,
    uint32_t* __restrict__ PH, uint32_t* __restrict__ PL) {
  int row = blockIdx.x;
  int half = row >= MTOT;
  const float* dw = half ? dwf : dws;
  const float* db = half ? dbf : dbs;
  const float* g  = half ? gf : gs;
  const float* bt = half ? btf : bts;
  int rb = row - half * MTOT;
  int b = rb / LF, l = rb % LF;
  int rbase = half * MTOT + b * LF;
  int c = threadIdx.x * 2;
  float ax = db[c], ay = db[c + 1];
#pragma unroll
  for (int tau = 0; tau < 7; ++tau) {
    int j = l + tau - 3;
    if (j < 0 || j >= LF) continue;
    float2 xv = *(const float2*)&xs[((size_t)(rbase + j)) * CI + c];
    ax = fmaf(xv.x, dw[c * 7 + tau], ax);
    ay = fmaf(xv.y, dw[(c + 1) * 7 + tau], ay);
  }
  __shared__ float red[4], red2[4];
  float s = ax + ay;
#pragma unroll
  for (int m = 1; m < 64; m <<= 1) s += __shfl_xor(s, m, 64);
  if ((threadIdx.x & 63) == 0) red[threadIdx.x >> 6] = s;
  __syncthreads();
  float mean = (red[0] + red[1] + red[2] + red[3]) * (1.0f / CI);
  float dx = ax - mean, dy = ay - mean;
  float s2 = dx * dx + dy * dy;
#pragma unroll
  for (int m = 1; m < 64; m <<= 1) s2 += __shfl_xor(s2, m, 64);
  if ((threadIdx.x & 63) == 0) red2[threadIdx.x >> 6] = s2;
  __syncthreads();
  float var = (red2[0] + red2[1] + red2[2] + red2[3]) * (1.0f / CI);
  float rs = rsqrtf(var + 1e-5f);
  float vx = dx * rs * g[c] + bt[c];
  float vy = dy * rs * g[c + 1] + bt[c + 1];
  PH[(size_t)row * 256 + threadIdx.x] = pack2(vx, vy, false);
  PL[(size_t)row * 256 + threadIdx.x] = pack2(vx, vy, true);
}

// ---------------- amps head ----------------
__global__ __launch_bounds__(256) void amps2_kernel(const float* __restrict__ x, const float* __restrict__ w,
                                                    const float* __restrict__ bias, float* __restrict__ amps) {
  int row = blockIdx.x * 4 + (threadIdx.x >> 6);
  int lane = threadIdx.x & 63;
  const float* xr = x + (size_t)row * CI;
  int c0 = lane * 8;
  float4 v0 = *(const float4*)&xr[c0], v1 = *(const float4*)&xr[c0 + 4];
  float4 w0 = *(const float4*)&w[c0], w1 = *(const float4*)&w[c0 + 4];
  float s = v0.x * w0.x + v0.y * w0.y + v0.z * w0.z + v0.w * w0.w
          + v1.x * w1.x + v1.y * w1.y + v1.z * w1.z + v1.w * w1.w;
#pragma unroll
  for (int m = 1; m < 64; m <<= 1) s += __shfl_xor(s, m, 64);
  if (lane == 0) {
    float a = s + bias[0];
    amps[row] = (a > 0.f ? a : expm1f(a)) + 1.0f;
  }
}

// ---------------- im2col packed (edge pad 3) ----------------
__global__ void im2col_pk(const float* __restrict__ x, uint32_t* __restrict__ PH, uint32_t* __restrict__ PL) {
  int idx = blockIdx.x * 256 + threadIdx.x;
  if (idx >= MTOT * 1792) return;
  int row = idx / 1792, kp = idx % 1792;
  int b = row / LF, l = row % LF;
  float v2[2];
#pragma unroll
  for (int u = 0; u < 2; ++u) {
    int kap = kp * 2 + u;
    int ch = kap / 7, tau = kap % 7;
    int j = l + tau - 3;
    j = j < 0 ? 0 : (j > LF - 1 ? LF - 1 : j);
    v2[u] = x[((size_t)b * LF + j) * CI + ch];
  }
  PH[idx] = pack2(v2[0], v2[1], false);
  PL[idx] = pack2(v2[0], v2[1], true);
}

// ---------------- noise*window packed A (1664 x 3840, rows>=1600 zero) ----------------
__global__ void pack_noise(uint32_t* __restrict__ AH, uint32_t* __restrict__ AL) {
  int idx = blockIdx.x * 256 + threadIdx.x;
  if (idx >= MPAD * 1920) return;
  int t = idx / 1920, jp = idx % 1920;
  float v0 = 0.f, v1 = 0.f;
  if (t < MTOT) {
    int b = t / LF, tt = t % LF;
    int j = jp * 2;
    v0 = noiseval(b, tt * 960 + j - 960) * winf(j);
    v1 = noiseval(b, tt * 960 + j - 959) * winf(j + 1);
  }
  AH[idx] = pack2(v0, v1, false);
  AL[idx] = pack2(v0, v1, true);
}

// ---------------- twiddle tables hi/lo (3968 x 3840) ----------------
__global__ void twfill_pk(uint32_t* __restrict__ TH, uint32_t* __restrict__ TL) {
  int idx = blockIdx.x * 256 + threadIdx.x;
  if (idx >= SWID * 1920) return;
  int k2 = idx / 1920, jp = idx % 1920;
  float v2[2] = {0.f, 0.f};
  if (k2 < NK2) {
    int k = k2 >> 1;
#pragma unroll
    for (int u = 0; u < 2; ++u) {
      int j = jp * 2 + u;
      int m = (j * k) % NFFT;
      float ang = (float)m * (6.283185307179586f / 3840.0f);
      v2[u] = (k2 & 1) ? -sinf(ang) : cosf(ang);
    }
  }
  TH[idx] = pack2(v2[0], v2[1], false);
  TL[idx] = pack2(v2[0], v2[1], true);
}

// ---------------- harmonic path ----------------
__global__ void fs_kernel(const float* __restrict__ f0, float* __restrict__ fs) {
  int idx = blockIdx.x * 256 + threadIdx.x;
  if (idx >= NB * LW) return;
  int b = idx / LW, n = idx % LW;
  float pos = ((float)n + 0.5f) * (200.0f / 192000.0f) - 0.5f;
  pos = fminf(fmaxf(pos, 0.0f), 199.0f);
  int i0 = (int)pos;
  int i1 = min(i0 + 1, 199);
  float w = pos - (float)i0;
  fs[idx] = f0[b * LF + i0] * (1.0f - w) + f0[b * LF + i1] * w;
}

__global__ __launch_bounds__(256) void cumsum1(const float* __restrict__ fs, double* __restrict__ csum) {
  int b = blockIdx.y, ch = blockIdx.x;
  const float* fsb = fs + (size_t)b * LW;
  int base = ch * 1024;
  double s = 0.0;
  for (int q = 0; q < 4; ++q) {
    int n = base + threadIdx.x * 4 + q;
    if (n < LW) s += (double)((3.14159274101257324f * fsb[n]) / 48000.0f);
  }
  __shared__ double sh[256];
  sh[threadIdx.x] = s;
  __syncthreads();
  for (int o2 = 128; o2 > 0; o2 >>= 1) {
    if (threadIdx.x < o2) sh[threadIdx.x] += sh[threadIdx.x + o2];
    __syncthreads();
  }
  if (threadIdx.x == 0) csum[b * NCH + ch] = sh[0];
}

__global__ void cumsum2(double* __restrict__ csum) {
  int b = blockIdx.x;
  if (threadIdx.x == 0) {
    double acc = 0.0;
    for (int ch = 0; ch < NCH; ++ch) {
      double v = csum[b * NCH + ch];
      csum[b * NCH + ch] = acc;
      acc += v;
    }
  }
}

__global__ __launch_bounds__(256) void harm_kernel(
    const float* __restrict__ fs, const double* __restrict__ csum,
    const float* __restrict__ f0, const float* __restrict__ amps,
    float* __restrict__ harm) {
  int b = blockIdx.y, ch = blockIdx.x;
  const float* fsb = fs + (size_t)b * LW;
  int base = ch * 1024;
  int tid = threadIdx.x;
  double p[4]; double s = 0.0;
  int n0 = base + tid * 4;
  for (int q = 0; q < 4; ++q) {
    int n = n0 + q; float sm = 0.f;
    if (n < LW) sm = (3.14159274101257324f * fsb[n]) / 48000.0f;
    s += (double)sm; p[q] = s;
  }
  __shared__ double sh[256];
  sh[tid] = s; __syncthreads();
  for (int o2 = 1; o2 < 256; o2 <<= 1) {
    double v = (tid >= o2) ? sh[tid - o2] : 0.0;
    __syncthreads();
    sh[tid] += v;
    __syncthreads();
  }
  double excl = csum[b * NCH + ch] + (tid > 0 ? sh[tid - 1] : 0.0);
  const double PID = (double)3.14159274101257324f;
  for (int q = 0; q < 4; ++q) {
    int n = n0 + q; if (n >= LW) break;
    double S = excl + p[q];
    float pixf = (float)fmod(S, PID);
    float fsv = fsb[n];
    float a = rintf(48000.0f / fmaxf(fsv, 20.0f) * 0.5f) * 2.0f + 1.0f;
    float D = (pixf < 1e-8f) ? 1.0f : (sinf(a * pixf) / (a * sinf(pixf)));
    int ui = n / 960;
    float uv = (f0[b * LF + ui] > 20.0f) ? 1.0f : 0.0f;
    float posA = ((float)n + 0.5f) * (200.0f / 192000.0f) - 0.5f;
    posA = fminf(fmaxf(posA, 0.0f), 199.0f);
    int i0 = (int)posA;
    int i1 = min(i0 + 1, 199);
    float w = posA - (float)i0;
    float ampI = amps[b * LF + i0] * (1.0f - w) + amps[b * LF + i1] * w;
    harm[(size_t)b * LW + n] = (D * uv) * ampI;
  }
}

// ---------------- OLA + wn normalize + add to harm ----------------
__global__ void ola_kernel(const float* __restrict__ ft, float* __restrict__ dsp) {
  int idx = blockIdx.x * 256 + threadIdx.x;
  if (idx >= NB * LW) return;
  int b = idx / LW, n = idx % LW;
  int p = n + 1920;
  int t0 = (p > 3839) ? ((p - 2880) / 960) : 0;
  int t1 = p / FRAME; if (t1 > 200) t1 = 200;
  float y = 0.f, wn = 0.f;
  for (int t = t0; t <= t1; ++t) {
    int j = p - FRAME * t;
    float w = winf(j);
    wn += w * w;
    if (t >= 1) y += ft[((size_t)b * LF + (t - 1)) * NFFT + j];
  }
  float den = wn > 1e-11f ? wn : 1.0f;
  dsp[idx] = dsp[idx] + y / den;
}

// ---------------- per-frame FIR: sliding-window, 8 consecutive outputs/thread ----------------
// frp padded: index i stored at i + (i>>3); lane stride 9 dwords -> 2-way banks (free)
__global__ __launch_bounds__(256) void fir3_kernel(const float* __restrict__ dsp,
                                                   const float* __restrict__ filt,
                                                   float* __restrict__ outf) {
  int t = blockIdx.x, b = blockIdx.y;
  __shared__ float frp[3456];
  __shared__ float fl[NWIN];
  int tid = threadIdx.x;
  for (int i = tid; i < 3456; i += 256) frp[i] = 0.f;
  __syncthreads();
  for (int i = tid; i < FRAME; i += 256) {
    int x = 1024 + i;
    frp[x + (x >> 3)] = dsp[(size_t)b * LW + (size_t)t * FRAME + i];
  }
  for (int i = tid; i < NWIN; i += 256) fl[i] = filt[((size_t)b * LF + t) * NWIN + i];
  __syncthreads();
  float a[8] = {0.f, 0.f, 0.f, 0.f, 0.f, 0.f, 0.f, 0.f};
  float wbuf[8];
  int base = 9 * tid;
#pragma unroll
  for (int r = 0; r < 8; ++r) wbuf[r] = frp[base + r];
  int nbase = base + 9;
  for (int tau8 = 0; tau8 < 128; ++tau8) {
    int nb = nbase + tau8 * 9;
#pragma unroll
    for (int r = 0; r < 8; ++r) {
      float fv = fl[tau8 * 8 + r];
#pragma unroll
      for (int q = 0; q < 8; ++q)
        a[q] = fmaf(wbuf[(r + q) & 7], fv, a[q]);
      wbuf[r] = frp[nb + r];
    }
  }
#pragma unroll
  for (int q = 0; q < 8; ++q) {
    int i = tid * 8 + q;
    if (i < 1984) outf[((size_t)b * LF + t) * 1984 + i] = a[q];
  }
}

// ---------------- fold ----------------
__global__ void fold_kernel(const float* __restrict__ outf, float* __restrict__ out) {
  int idx = blockIdx.x * 256 + threadIdx.x;
  if (idx >= NB * LW) return;
  int b = idx / LW, n = idx % LW;
  int t0 = (n >= 1984) ? ((n - 1024) / 960) : 0;
  int t1 = n / 960; if (t1 > 199) t1 = 199;
  float acc = 0.f;
  for (int t = t0; t <= t1; ++t)
    acc += outf[((size_t)b * LF + t) * 1984 + (n - 960 * t)];
  out[idx] = acc;
}

extern "C" void kernel_launch(void* const* d_in, const int* in_sizes, int n_in,
                              void* d_out, int out_size, void* d_ws, size_t ws_size,
                              hipStream_t stream) {
  const float* content    = (const float*)d_in[0];
  const float* f0         = (const float*)d_in[1];
  const float* energy     = (const float*)d_in[2];
  const float* spk        = (const float*)d_in[3];
  const float* s_in_w     = (const float*)d_in[4];
  const float* s_in_b     = (const float*)d_in[5];
  const float* s_dw_w     = (const float*)d_in[6];
  const float* s_dw_b     = (const float*)d_in[7];
  const float* s_ln       = (const float*)d_in[8];
  const float* s_pw1_w    = (const float*)d_in[9];
  const float* s_pw1_b    = (const float*)d_in[10];
  const float* s_pw2_w    = (const float*)d_in[11];
  const float* s_pw2_b    = (const float*)d_in[12];
  const float* s_out_norm = (const float*)d_in[13];
  const float* f_in_w     = (const float*)d_in[14];
  const float* f_in_b     = (const float*)d_in[15];
  const float* f_dw_w     = (const float*)d_in[16];
  const float* f_dw_b     = (const float*)d_in[17];
  const float* f_ln       = (const float*)d_in[18];
  const float* f_pw1_w    = (const float*)d_in[19];
  const float* f_pw1_b    = (const float*)d_in[20];
  const float* f_pw2_w    = (const float*)d_in[21];
  const float* f_pw2_b    = (const float*)d_in[22];
  const float* f_out_norm = (const float*)d_in[23];
  const float* s_in_norm  = (const float*)d_in[24];
  const float* s_amp_w    = (const float*)d_in[25];
  const float* s_amp_b    = (const float*)d_in[26];
  const float* s_ker_w    = (const float*)d_in[27];
  const float* s_ker_b    = (const float*)d_in[28];
  const float* f_out_w    = (const float*)d_in[29];
  const float* f_out_b    = (const float*)d_in[30];

  // ---- workspace layout (175.61 MB; proven ws >= 177.57 MB) ----
  char* W0 = (char*)d_ws;
  double*   CSUM  = (double*)W0;                         // 12,032
  uint32_t* XINPH = (uint32_t*)(W0 + 12032);             // 3,072,000
  uint32_t* XINPL = (uint32_t*)(W0 + 3084032);           // 3,072,000
  float*    XS    = (float*)   (W0 + 6156032);           // 6,553,600 (3200 x 512)
  uint32_t* TPH   = (uint32_t*)(W0 + 12709632);          // 3,276,800 (3200 x 256)
  uint32_t* TPL   = (uint32_t*)(W0 + 15986432);          // 3,276,800
  uint16_t* KERH  = (uint16_t*)(W0 + 19263232);          // 6,147,200
  float*    AMPS  = (float*)   (W0 + 25410432);          // 8,192
  float*    FILT  = (float*)   (W0 + 25418624);          // 6,553,600
  float*    HARM  = (float*)   (W0 + 31972224);          // 6,144,000
  char*     R2    = W0 + 38116224;                       // 26,411,008
  char*     FTR   = W0 + 64527232;                       // 24,576,000
  char*     U     = W0 + 89103232;                       // 25,559,040
  uint32_t* TH32  = (uint32_t*)(W0 + 114662272);         // 30,474,240
  uint32_t* TL32  = (uint32_t*)(W0 + 145136512);         // 30,474,240 -> ends 175,610,752
  // overlays
  uint32_t* XSPH = TPH;                                  // (after trunk, TP dead)
  uint32_t* XSPL = (uint32_t*)((char*)TPH + 1638400);
  uint32_t* H15PH = (uint32_t*)R2;                       // 9,830,400 (3200 x 768)
  uint32_t* H15PL = (uint32_t*)(R2 + 9830400);
  uint32_t* IMPH = (uint32_t*)R2;                        // 11,468,800 (after H15 dead)
  uint32_t* IMPL = (uint32_t*)(R2 + 11468800);
  uint16_t* SH   = (uint16_t*)R2;                        // 13,205,504 (1664 x 3968, after IMP dead)
  uint16_t* SL   = (uint16_t*)(R2 + 13205504);
  float*    OUTF = (float*)R2;                           // 12,697,600 (after SH/SL dead)
  float*    FS   = (float*)FTR;                          // 6,144,000
  float*    FT   = (float*)FTR;                          // 24,576,000 (after FS dead)
  uint32_t* WPH  = (uint32_t*)U;                         // 7,340,032
  uint32_t* WPL  = (uint32_t*)(U + 7340032);
  uint16_t* AH   = (uint16_t*)U;                         // 12,779,520 (after WP dead)
  uint16_t* AL   = (uint16_t*)(U + 12779520);

  (void)in_sizes; (void)n_in; (void)out_size; (void)ws_size;

  build_xin_pk<<<dim3((MB2 * 240 + 255) / 256), 256, 0, stream>>>(content, f0, energy, spk, XINPH, XINPL);

  auto pw1set = [&](const float* Wm, int M, int K, int Mp, int Kp) {
    int total = Mp * (Kp / 2);
    pack_w<<<dim3((total + 255) / 256), 256, 0, stream>>>(Wm, WPH, WPL, M, K, Kp / 2, total);
  };
  auto pw2sets = [&](const float* Ws, const float* Wf, int M, int K, int Mp, int Kp) {
    int total = Mp * (Kp / 2);
    pack_w<<<dim3((total + 255) / 256), 256, 0, stream>>>(Ws, WPH, WPL, M, K, Kp / 2, total);
    pack_w<<<dim3((total + 255) / 256), 256, 0, stream>>>(Wf, WPH + total, WPL + total, M, K, Kp / 2, total);
  };

  // ---- batched dual-trunk ----
  pw2sets(s_in_w, f_in_w, CI, CIN, CI, 480);
  gemm_pk<<<dim3(8 * 50), 256, 0, stream>>>((uint16_t*)WPH, (uint16_t*)WPL, (uint16_t*)XINPH, (uint16_t*)XINPL,
      s_in_b, f_in_b, nullptr, XS, nullptr, nullptr, CI, 480, 8, 50, 0, 0, 25, (size_t)512 * 480);
  ln2_kernel<<<dim3(MTOT / 4), 256, 0, stream>>>(XS, s_in_norm, s_in_norm + CI, nullptr, nullptr);
  for (int i = 0; i < NL; ++i) {
    dwln_kernel<<<dim3(MB2), 256, 0, stream>>>(XS,
        s_dw_w + (size_t)i * CI * 7, s_dw_b + (size_t)i * CI,
        s_ln + (size_t)(i * 2) * CI, s_ln + (size_t)(i * 2 + 1) * CI,
        f_dw_w + (size_t)i * CI * 7, f_dw_b + (size_t)i * CI,
        f_ln + (size_t)(i * 2) * CI, f_ln + (size_t)(i * 2 + 1) * CI,
        TPH, TPL);
    pw2sets(s_pw1_w + (size_t)i * HID * CI, f_pw1_w + (size_t)i * HID * CI, HID, CI, HID, 512);
    gemm_pk<<<dim3(24 * 50), 256, 0, stream>>>((uint16_t*)WPH, (uint16_t*)WPL, (uint16_t*)TPH, (uint16_t*)TPL,
        s_pw1_b + (size_t)i * HID, f_pw1_b + (size_t)i * HID, nullptr,
        nullptr, (uint16_t*)H15PH, (uint16_t*)H15PL, HID, 512, 24, 50, 1, 1, 25, (size_t)1536 * 512);
    pw2sets(s_pw2_w + (size_t)i * CI * HID, f_pw2_w + (size_t)i * CI * HID, CI, HID, CI, 1536);
    gemm_pk<<<dim3(8 * 50), 256, 0, stream>>>((uint16_t*)WPH, (uint16_t*)WPL, (uint16_t*)H15PH, (uint16_t*)H15PL,
        s_pw2_b + (size_t)i * CI, f_pw2_b + (size_t)i * CI, XS,
        XS, nullptr, nullptr, CI, 1536, 8, 50, 0, 0, 25, (size_t)512 * 1536);
  }

  // ---- heads ----
  ln2_kernel<<<dim3(MTOT / 4), 256, 0, stream>>>(XS, s_out_norm, s_out_norm + CI, XSPH, XSPL);
  amps2_kernel<<<dim3(MTOT / 4), 256, 0, stream>>>(XS, s_amp_w, s_amp_b, AMPS);
  pw1set(s_ker_w, NFREQ, CI, 1984, 512);
  gemm_pk<<<dim3(31 * 25), 256, 0, stream>>>((uint16_t*)WPH, (uint16_t*)WPL, (uint16_t*)XSPH, (uint16_t*)XSPL,
      s_ker_b, nullptr, nullptr, nullptr, KERH, nullptr, NFREQ, 512, 31, 25, 2, 2, 1000, 0);

  ln2_kernel<<<dim3(MTOT / 4), 256, 0, stream>>>(XS + (size_t)MTOT * CI, f_out_norm, f_out_norm + CI, nullptr, nullptr);
  im2col_pk<<<dim3((MTOT * 1792 + 255) / 256), 256, 0, stream>>>(XS + (size_t)MTOT * CI, IMPH, IMPL);
  pw1set(f_out_w, NWIN, 3584, NWIN, 3584);
  gemm_pk<<<dim3(16 * 25), 256, 0, stream>>>((uint16_t*)WPH, (uint16_t*)WPL, (uint16_t*)IMPH, (uint16_t*)IMPL,
      f_out_b, nullptr, nullptr, FILT, nullptr, nullptr, NWIN, 3584, 16, 25, 0, 0, 1000, 0);

  // ---- harmonic source ----
  fs_kernel<<<dim3((NB * LW + 255) / 256), 256, 0, stream>>>(f0, FS);
  cumsum1<<<dim3(NCH, NB), 256, 0, stream>>>(FS, CSUM);
  cumsum2<<<dim3(NB), 64, 0, stream>>>(CSUM);
  harm_kernel<<<dim3(NCH, NB), 256, 0, stream>>>(FS, CSUM, f0, AMPS, HARM);

  // ---- filtered noise ----
  pack_noise<<<dim3((MPAD * 1920 + 255) / 256), 256, 0, stream>>>((uint32_t*)AH, (uint32_t*)AL);
  twfill_pk<<<dim3((SWID * 1920 + 255) / 256), 256, 0, stream>>>(TH32, TL32);
  gemm_fwd128<<<dim3(13 * 31), 256, 0, stream>>>(AH, AL, (uint16_t*)TH32, (uint16_t*)TL32, KERH, SH, SL);
  gemm_inv128<<<dim3(30 * 13), 256, 0, stream>>>(SH, SL, (uint16_t*)TH32, (uint16_t*)TL32, FT);
  ola_kernel<<<dim3((NB * LW + 255) / 256), 256, 0, stream>>>(FT, HARM);

  // ---- FIR + fold ----
  fir3_kernel<<<dim3(LF, NB), 256, 0, stream>>>(HARM, FILT, OUTF);
  fold_kernel<<<dim3((NB * LW + 255) / 256), 256, 0, stream>>>(OUTF, (float*)d_out);
}

// Round 11
// 1420.913 us; speedup vs baseline: 12.1810x; 1.1256x over previous
//
#include <hip/hip_runtime.h>
#include <hip/hip_bf16.h>
#include <math.h>
#include <stdint.h>

#define FRAME 960
#define NFFT  3840
#define NWIN  1024
#define NFREQ 1921
#define NB    8
#define LF    200
#define LW    192000
#define CIN   450
#define CI    512
#define HID   1536
#define NL    6
#define NCH   188
#define NK2   3842
#define MTOT  1600
#define MB2   3200   // both trunks batched
#define SWID  3968   // padded spec width (31*128 = 124*32)
#define MPAD  1664   // padded frame rows (13*128)

typedef __attribute__((ext_vector_type(8))) short short8v;
typedef __attribute__((ext_vector_type(4))) float f32x4;
typedef __attribute__((address_space(3))) uint32_t lds_u32;
typedef const __attribute__((address_space(1))) uint32_t glb_u32;

// ---------------- threefry (JAX partitionable) ----------------
__device__ __forceinline__ uint32_t rotl32(uint32_t v, int r) { return (v << r) | (v >> (32 - r)); }
__device__ __forceinline__ void threefry2x32(uint32_t k0, uint32_t k1, uint32_t& x0, uint32_t& x1) {
  uint32_t ks2 = k0 ^ k1 ^ 0x1BD11BDAu;
  x0 += k0; x1 += k1;
#define TFR(r) { x0 += x1; x1 = rotl32(x1, r); x1 ^= x0; }
  TFR(13) TFR(15) TFR(26) TFR(6)  x0 += k1;  x1 += ks2 + 1u;
  TFR(17) TFR(29) TFR(16) TFR(24) x0 += ks2; x1 += k0 + 2u;
  TFR(13) TFR(15) TFR(26) TFR(6)  x0 += k0;  x1 += k1 + 3u;
  TFR(17) TFR(29) TFR(16) TFR(24) x0 += k1;  x1 += ks2 + 4u;
  TFR(13) TFR(15) TFR(26) TFR(6)  x0 += ks2; x1 += k0 + 5u;
#undef TFR
}
__device__ __forceinline__ float noiseval(int b, int m) {
  if (m < 0) m = -m;
  if (m >= LW) m = 2 * LW - 2 - m;
  uint32_t x0 = 0u, x1 = (uint32_t)(b * LW + m);
  threefry2x32(0u, 123u, x0, x1);
  uint32_t bits = x0 ^ x1;
  return __uint_as_float((bits >> 9) | 0x3f800000u) - 1.0f;
}
__device__ __forceinline__ float winf(int j) {
  return 0.5f - 0.5f * cosf((6.283185307179586f * (float)j) / 3840.0f);
}
__device__ __forceinline__ unsigned short f2bf(float v) {
  uint32_t b = __float_as_uint(v);
  return (unsigned short)((b + 0x7FFFu + ((b >> 16) & 1u)) >> 16);
}
__device__ __forceinline__ float bf2f(unsigned short h) {
  return __uint_as_float(((uint32_t)h) << 16);
}
__device__ __forceinline__ uint32_t pack2(float a, float b, bool lo) {
  unsigned short ha = f2bf(a), hb = f2bf(b);
  if (!lo) return (uint32_t)ha | ((uint32_t)hb << 16);
  return (uint32_t)f2bf(a - bf2f(ha)) | ((uint32_t)f2bf(b - bf2f(hb)) << 16);
}
__device__ __forceinline__ int xcd_remap(int lin, int nwg) {
  int q = nwg >> 3, r = nwg & 7;
  int xcd = lin & 7, base = lin >> 3;
  int start = (xcd < r) ? xcd * (q + 1) : r * (q + 1) + (xcd - r) * q;
  return start + base;
}

// ---------------- xin packed, duplicated for both trunks (3200 x 480) ----------------
__global__ void build_xin_pk(const float* __restrict__ content, const float* __restrict__ f0,
                             const float* __restrict__ energy, const float* __restrict__ spk,
                             uint32_t* __restrict__ PH, uint32_t* __restrict__ PL) {
  int idx = blockIdx.x * 256 + threadIdx.x;
  if (idx >= MB2 * 240) return;
  int row = idx / 240, cp = idx % 240;
  int rb = row % MTOT;
  int b = rb / LF, l = rb % LF;
  float v2[2];
#pragma unroll
  for (int u = 0; u < 2; ++u) {
    int c = cp * 2 + u;
    float v = 0.f;
    if (c < 192)       v = content[((size_t)b * 192 + c) * LF + l];
    else if (c < 448)  v = spk[b * 256 + (c - 192)];
    else if (c == 448) v = logf(fmaxf(f0[b * LF + l], 0.0f) + 1e-6f);
    else if (c == 449) v = energy[b * LF + l];
    v2[u] = v;
  }
  PH[idx] = pack2(v2[0], v2[1], false);
  PL[idx] = pack2(v2[0], v2[1], true);
}

// ---------------- weight pack ----------------
__global__ void pack_w(const float* __restrict__ W, uint32_t* __restrict__ PH, uint32_t* __restrict__ PL,
                       int M, int K, int Kp2, int total) {
  int idx = blockIdx.x * 256 + threadIdx.x;
  if (idx >= total) return;
  int m = idx / Kp2, kp = idx % Kp2;
  int k = kp * 2;
  float v0 = (m < M && k < K) ? W[(size_t)m * K + k] : 0.f;
  float v1 = (m < M && (k + 1) < K) ? W[(size_t)m * K + k + 1] : 0.f;
  PH[idx] = pack2(v0, v1, false);
  PL[idx] = pack2(v0, v1, true);
}

// ---------------- packed-bf16 NT GEMM, 64x64 tile, dual-weight-set batched ----------------
__global__ __launch_bounds__(256) void gemm_pk(
    const uint16_t* __restrict__ WH, const uint16_t* __restrict__ WL,
    const uint16_t* __restrict__ XH, const uint16_t* __restrict__ XL,
    const float* __restrict__ bias, const float* __restrict__ bias2,
    const float* __restrict__ res,
    float* __restrict__ outF, uint16_t* __restrict__ outH, uint16_t* __restrict__ outL,
    int M, int Kp, int mtiles, int ntiles, int mode, int act, int nsp, size_t woff)
{
  __shared__ __align__(16) char smem[2][4][4096];
  int nwg = mtiles * ntiles;
  int wg = xcd_remap(blockIdx.x, nwg);
  int mtile = wg / ntiles, ntile = wg % ntiles;
  int m0 = mtile * 64, n0 = ntile * 64;
  int tid = threadIdx.x;
  int lane = tid & 63, w = tid >> 6;
  int wm = w >> 1, wn = w & 1;
  int rowg = Kp >> 3;
  int phases = Kp >> 5;

  const uint16_t* gb = (w == 0) ? WH : (w == 1) ? WL : (w == 2) ? XH : XL;
  if (w < 2 && ntile >= nsp) gb += woff;
  int row0 = (w < 2) ? m0 : n0;
  int sr = lane >> 2, scg = lane & 3;
  int sgsel = scg ^ ((sr >> 1) & 3);
  f32x4 acc[2][2];
#pragma unroll
  for (int i = 0; i < 2; ++i)
#pragma unroll
    for (int j = 0; j < 2; ++j) acc[i][j] = (f32x4){0.f, 0.f, 0.f, 0.f};

  auto stage = [&](int buf, int p) {
    int kg0 = p * 4;
#pragma unroll
    for (int i = 0; i < 4; ++i) {
      int r = i * 16 + sr;
      const uint16_t* src = gb + (size_t)(row0 + r) * rowg * 8 + (size_t)(kg0 + sgsel) * 8;
      __builtin_amdgcn_global_load_lds((glb_u32*)src, (lds_u32*)(&smem[buf][w][0] + i * 1024), 16, 0, 0);
    }
  };

  stage(0, 0);
  __syncthreads();
  int fr = lane & 15, fg = lane >> 4;
  int fsw = ((fr >> 1) & 3);
  int aoff0 = (wm * 32 + fr) * 64 + (fg ^ fsw) * 16;
  int aoff1 = (wm * 32 + 16 + fr) * 64 + (fg ^ fsw) * 16;
  int boff0 = (wn * 32 + fr) * 64 + (fg ^ fsw) * 16;
  int boff1 = (wn * 32 + 16 + fr) * 64 + (fg ^ fsw) * 16;

  for (int p = 0; p < phases; ++p) {
    int cur = p & 1;
    if (p + 1 < phases) stage(cur ^ 1, p + 1);
    short8v ah0 = *(const short8v*)(&smem[cur][0][0] + aoff0);
    short8v ah1 = *(const short8v*)(&smem[cur][0][0] + aoff1);
    short8v al0 = *(const short8v*)(&smem[cur][1][0] + aoff0);
    short8v al1 = *(const short8v*)(&smem[cur][1][0] + aoff1);
    short8v bh0 = *(const short8v*)(&smem[cur][2][0] + boff0);
    short8v bh1 = *(const short8v*)(&smem[cur][2][0] + boff1);
    short8v bl0 = *(const short8v*)(&smem[cur][3][0] + boff0);
    short8v bl1 = *(const short8v*)(&smem[cur][3][0] + boff1);
    acc[0][0] = __builtin_amdgcn_mfma_f32_16x16x32_bf16(ah0, bh0, acc[0][0], 0, 0, 0);
    acc[0][1] = __builtin_amdgcn_mfma_f32_16x16x32_bf16(ah0, bh1, acc[0][1], 0, 0, 0);
    acc[1][0] = __builtin_amdgcn_mfma_f32_16x16x32_bf16(ah1, bh0, acc[1][0], 0, 0, 0);
    acc[1][1] = __builtin_amdgcn_mfma_f32_16x16x32_bf16(ah1, bh1, acc[1][1], 0, 0, 0);
    acc[0][0] = __builtin_amdgcn_mfma_f32_16x16x32_bf16(ah0, bl0, acc[0][0], 0, 0, 0);
    acc[0][1] = __builtin_amdgcn_mfma_f32_16x16x32_bf16(ah0, bl1, acc[0][1], 0, 0, 0);
    acc[1][0] = __builtin_amdgcn_mfma_f32_16x16x32_bf16(ah1, bl0, acc[1][0], 0, 0, 0);
    acc[1][1] = __builtin_amdgcn_mfma_f32_16x16x32_bf16(ah1, bl1, acc[1][1], 0, 0, 0);
    acc[0][0] = __builtin_amdgcn_mfma_f32_16x16x32_bf16(al0, bh0, acc[0][0], 0, 0, 0);
    acc[0][1] = __builtin_amdgcn_mfma_f32_16x16x32_bf16(al0, bh1, acc[0][1], 0, 0, 0);
    acc[1][0] = __builtin_amdgcn_mfma_f32_16x16x32_bf16(al1, bh0, acc[1][0], 0, 0, 0);
    acc[1][1] = __builtin_amdgcn_mfma_f32_16x16x32_bf16(al1, bh1, acc[1][1], 0, 0, 0);
    __syncthreads();
  }

#pragma unroll
  for (int mi = 0; mi < 2; ++mi)
#pragma unroll
    for (int ni = 0; ni < 2; ++ni)
#pragma unroll
      for (int r = 0; r < 4; ++r) {
        int m = m0 + wm * 32 + mi * 16 + ((lane >> 4) << 2) + r;
        int n = n0 + wn * 32 + ni * 16 + (lane & 15);
        if (m >= M) continue;
        float v = acc[mi][ni][r];
        if (bias) v += (bias2 && n >= nsp * 64) ? bias2[m] : bias[m];
        if (act == 1)      v = 0.5f * v * (1.0f + erff(v * 0.7071067811865475f));
        else if (act == 2) v = (v > 0.f ? v : expm1f(v)) + 1.0f;
        if (mode == 0) {
          if (res) v += res[(size_t)n * M + m];
          outF[(size_t)n * M + m] = v;
        } else if (mode == 1) {
          unsigned short h = f2bf(v);
          outH[(size_t)n * M + m] = h;
          outL[(size_t)n * M + m] = f2bf(v - bf2f(h));
        } else {  // 2: KER bf16 (NFREQ row stride)
          outH[(size_t)n * NFREQ + m] = f2bf(v);
        }
      }
}

// ---------------- fwd DFT GEMM: 128x128 tile, 4 waves, wave-per-64x64-quadrant ----------------
__global__ __launch_bounds__(256) void gemm_fwd128(
    const uint16_t* __restrict__ AH, const uint16_t* __restrict__ AL,
    const uint16_t* __restrict__ TH, const uint16_t* __restrict__ TL,
    const uint16_t* __restrict__ KERH,
    uint16_t* __restrict__ SH, uint16_t* __restrict__ SL)
{
  __shared__ __align__(16) char smem[2][4][8192];
  int wg = xcd_remap(blockIdx.x, 13 * 31);
  int ntile = wg / 13, mtile = wg % 13;   // m-inner: T-tile L2-resident
  int m0 = mtile * 128, n0 = ntile * 128;
  int tid = threadIdx.x;
  int lane = tid & 63, w = tid >> 6;
  int wm = w >> 1, wn = w & 1;
  const uint16_t* gb = (w == 0) ? AH : (w == 1) ? AL : (w == 2) ? TH : TL;
  int row0 = (w < 2) ? m0 : n0;
  f32x4 acc[4][4];
#pragma unroll
  for (int i = 0; i < 4; ++i)
#pragma unroll
    for (int j = 0; j < 4; ++j) acc[i][j] = (f32x4){0.f, 0.f, 0.f, 0.f};

  auto stage = [&](int buf, int p) {
#pragma unroll
    for (int i = 0; i < 8; ++i) {
      int gl = i * 64 + lane;
      int row = gl >> 2, cg = gl & 3;
      int sg = cg ^ ((row >> 1) & 3);
      const uint16_t* src = gb + (size_t)(row0 + row) * 3840 + p * 32 + sg * 8;
      __builtin_amdgcn_global_load_lds((glb_u32*)src, (lds_u32*)(&smem[buf][w][0] + i * 1024), 16, 0, 0);
    }
  };

  stage(0, 0);
  __syncthreads();
  int fr = lane & 15, fg = lane >> 4;

  for (int p = 0; p < 120; ++p) {
    int cur = p & 1;
    if (p + 1 < 120) stage(cur ^ 1, p + 1);
    short8v a_h[4], a_l[4], b_h[4], b_l[4];
#pragma unroll
    for (int q = 0; q < 4; ++q) {
      int ra = wm * 64 + q * 16 + fr;
      int oa = ra * 64 + ((fg ^ ((ra >> 1) & 3)) << 4);
      a_h[q] = *(const short8v*)(&smem[cur][0][0] + oa);
      a_l[q] = *(const short8v*)(&smem[cur][1][0] + oa);
      int rb = wn * 64 + q * 16 + fr;
      int ob = rb * 64 + ((fg ^ ((rb >> 1) & 3)) << 4);
      b_h[q] = *(const short8v*)(&smem[cur][2][0] + ob);
      b_l[q] = *(const short8v*)(&smem[cur][3][0] + ob);
    }
#pragma unroll
    for (int mi = 0; mi < 4; ++mi)
#pragma unroll
      for (int ni = 0; ni < 4; ++ni) {
        acc[mi][ni] = __builtin_amdgcn_mfma_f32_16x16x32_bf16(a_h[mi], b_h[ni], acc[mi][ni], 0, 0, 0);
        acc[mi][ni] = __builtin_amdgcn_mfma_f32_16x16x32_bf16(a_h[mi], b_l[ni], acc[mi][ni], 0, 0, 0);
        acc[mi][ni] = __builtin_amdgcn_mfma_f32_16x16x32_bf16(a_l[mi], b_h[ni], acc[mi][ni], 0, 0, 0);
      }
    __syncthreads();
  }

#pragma unroll
  for (int mi = 0; mi < 4; ++mi)
#pragma unroll
    for (int ni = 0; ni < 4; ++ni)
#pragma unroll
      for (int r = 0; r < 4; ++r) {
        int m = m0 + wm * 64 + mi * 16 + ((lane >> 4) << 2) + r;
        int n = n0 + wn * 64 + ni * 16 + (lane & 15);
        if (m < MTOT) {
          float o = 0.f;
          if (n < NK2) {
            int k = n >> 1;
            float kv = bf2f(KERH[(size_t)m * NFREQ + k]);
            bool edge = (k == 0) || (k == 1920);
            float mult = edge ? (1.0f / NFFT) : (2.0f / NFFT);
            o = acc[mi][ni][r] * kv * mult;
            if ((n & 1) && edge) o = 0.f;
          }
          unsigned short h = f2bf(o);
          SH[(size_t)m * SWID + n] = h;
          SL[(size_t)m * SWID + n] = f2bf(o - bf2f(h));
        }
      }
}

// ---------------- transposed twiddle V[j][k2] = T[k2][j], row-major (3840 x 3968) ----------------
// Generated AFTER fwd completes, overwriting the T buffer (same byte size).
__global__ void twfill_v(uint32_t* __restrict__ VH, uint32_t* __restrict__ VL) {
  int idx = blockIdx.x * 256 + threadIdx.x;
  if (idx >= NFFT * (SWID / 2)) return;
  int j = idx / (SWID / 2), kp = idx % (SWID / 2);
  float v2[2] = {0.f, 0.f};
#pragma unroll
  for (int u = 0; u < 2; ++u) {
    int k2 = kp * 2 + u;
    if (k2 < NK2) {
      int k = k2 >> 1;
      int m = (j * k) % NFFT;
      float ang = (float)m * (6.283185307179586f / 3840.0f);
      v2[u] = (k2 & 1) ? -sinf(ang) : cosf(ang);
    }
  }
  VH[idx] = pack2(v2[0], v2[1], false);
  VL[idx] = pack2(v2[0], v2[1], true);
}

// ---------------- inverse DFT as pure NT GEMM (clone of fwd128): ft[t,j] = sum_k2 S[t,k2]*V[j,k2] ----------------
__global__ __launch_bounds__(256) void gemm_invNT(
    const uint16_t* __restrict__ SH, const uint16_t* __restrict__ SL,
    const uint16_t* __restrict__ VH, const uint16_t* __restrict__ VL,
    float* __restrict__ ft)
{
  __shared__ __align__(16) char smem[2][4][8192];
  int wg = xcd_remap(blockIdx.x, 30 * 13);
  int ntile = wg / 13, mtile = wg % 13;   // m-inner: V-tile L2-resident
  int m0 = mtile * 128, n0 = ntile * 128;
  int tid = threadIdx.x;
  int lane = tid & 63, w = tid >> 6;
  int wm = w >> 1, wn = w & 1;
  const uint16_t* gb = (w == 0) ? SH : (w == 1) ? SL : (w == 2) ? VH : VL;
  int row0 = (w < 2) ? m0 : n0;
  f32x4 acc[4][4];
#pragma unroll
  for (int i = 0; i < 4; ++i)
#pragma unroll
    for (int j = 0; j < 4; ++j) acc[i][j] = (f32x4){0.f, 0.f, 0.f, 0.f};

  auto stage = [&](int buf, int p) {
#pragma unroll
    for (int i = 0; i < 8; ++i) {
      int gl = i * 64 + lane;
      int row = gl >> 2, cg = gl & 3;
      int sg = cg ^ ((row >> 1) & 3);
      const uint16_t* src = gb + (size_t)(row0 + row) * SWID + p * 32 + sg * 8;
      __builtin_amdgcn_global_load_lds((glb_u32*)src, (lds_u32*)(&smem[buf][w][0] + i * 1024), 16, 0, 0);
    }
  };

  stage(0, 0);
  __syncthreads();
  int fr = lane & 15, fg = lane >> 4;

  for (int p = 0; p < 124; ++p) {
    int cur = p & 1;
    if (p + 1 < 124) stage(cur ^ 1, p + 1);
    short8v a_h[4], a_l[4], b_h[4], b_l[4];
#pragma unroll
    for (int q = 0; q < 4; ++q) {
      int ra = wm * 64 + q * 16 + fr;
      int oa = ra * 64 + ((fg ^ ((ra >> 1) & 3)) << 4);
      a_h[q] = *(const short8v*)(&smem[cur][0][0] + oa);
      a_l[q] = *(const short8v*)(&smem[cur][1][0] + oa);
      int rb = wn * 64 + q * 16 + fr;
      int ob = rb * 64 + ((fg ^ ((rb >> 1) & 3)) << 4);
      b_h[q] = *(const short8v*)(&smem[cur][2][0] + ob);
      b_l[q] = *(const short8v*)(&smem[cur][3][0] + ob);
    }
#pragma unroll
    for (int mi = 0; mi < 4; ++mi)
#pragma unroll
      for (int ni = 0; ni < 4; ++ni) {
        acc[mi][ni] = __builtin_amdgcn_mfma_f32_16x16x32_bf16(a_h[mi], b_h[ni], acc[mi][ni], 0, 0, 0);
        acc[mi][ni] = __builtin_amdgcn_mfma_f32_16x16x32_bf16(a_h[mi], b_l[ni], acc[mi][ni], 0, 0, 0);
        acc[mi][ni] = __builtin_amdgcn_mfma_f32_16x16x32_bf16(a_l[mi], b_h[ni], acc[mi][ni], 0, 0, 0);
      }
    __syncthreads();
  }

#pragma unroll
  for (int mi = 0; mi < 4; ++mi)
#pragma unroll
    for (int ni = 0; ni < 4; ++ni)
#pragma unroll
      for (int r = 0; r < 4; ++r) {
        int m = m0 + wm * 64 + mi * 16 + ((lane >> 4) << 2) + r;
        int n = n0 + wn * 64 + ni * 16 + (lane & 15);
        if (m < MTOT) ft[(size_t)m * NFFT + n] = acc[mi][ni][r] * winf(n);
      }
}

// ---------------- LayerNorm rows, optional packed out ----------------
__global__ __launch_bounds__(256) void ln2_kernel(float* __restrict__ x, const float* __restrict__ g,
                                                  const float* __restrict__ bta,
                                                  uint32_t* __restrict__ PH, uint32_t* __restrict__ PL) {
  int row = blockIdx.x * 4 + (threadIdx.x >> 6);
  int lane = threadIdx.x & 63;
  float* xr = x + (size_t)row * CI;
  int c0 = lane * 8;
  float4 v0 = *(float4*)&xr[c0], v1 = *(float4*)&xr[c0 + 4];
  float s = v0.x + v0.y + v0.z + v0.w + v1.x + v1.y + v1.z + v1.w;
#pragma unroll
  for (int m = 1; m < 64; m <<= 1) s += __shfl_xor(s, m, 64);
  float mean = s * (1.0f / CI);
  float d[8] = {v0.x - mean, v0.y - mean, v0.z - mean, v0.w - mean,
                v1.x - mean, v1.y - mean, v1.z - mean, v1.w - mean};
  float s2 = 0.f;
#pragma unroll
  for (int q = 0; q < 8; ++q) s2 += d[q] * d[q];
#pragma unroll
  for (int m = 1; m < 64; m <<= 1) s2 += __shfl_xor(s2, m, 64);
  float rs = rsqrtf(s2 * (1.0f / CI) + 1e-5f);
  float o[8];
#pragma unroll
  for (int q = 0; q < 8; ++q) o[q] = d[q] * rs * g[c0 + q] + bta[c0 + q];
  float4 w0 = {o[0], o[1], o[2], o[3]}, w1 = {o[4], o[5], o[6], o[7]};
  *(float4*)&xr[c0] = w0; *(float4*)&xr[c0 + 4] = w1;
  if (PH) {
    int base = (row * CI + c0) >> 1;
#pragma unroll
    for (int q = 0; q < 4; ++q) {
      PH[base + q] = pack2(o[2 * q], o[2 * q + 1], false);
      PL[base + q] = pack2(o[2 * q], o[2 * q + 1], true);
    }
  }
}

// ---------------- fused dwconv K=7 + LN -> packed, dual-trunk batched ----------------
__global__ __launch_bounds__(256) void dwln_kernel(const float* __restrict__ xs,
    const float* __restrict__ dws, const float* __restrict__ dbs,
    const float* __restrict__ gs, const float* __restrict__ bts,
    const float* __restrict__ dwf, const float* __restrict__ dbf,
    const float* __restrict__ gf, const float* __restrict__ btf,
    uint32_t* __restrict__ PH, uint32_t* __restrict__ PL) {
  int row = blockIdx.x;
  int half = row >= MTOT;
  const float* dw = half ? dwf : dws;
  const float* db = half ? dbf : dbs;
  const float* g  = half ? gf : gs;
  const float* bt = half ? btf : bts;
  int rb = row - half * MTOT;
  int b = rb / LF, l = rb % LF;
  int rbase = half * MTOT + b * LF;
  int c = threadIdx.x * 2;
  float ax = db[c], ay = db[c + 1];
#pragma unroll
  for (int tau = 0; tau < 7; ++tau) {
    int j = l + tau - 3;
    if (j < 0 || j >= LF) continue;
    float2 xv = *(const float2*)&xs[((size_t)(rbase + j)) * CI + c];
    ax = fmaf(xv.x, dw[c * 7 + tau], ax);
    ay = fmaf(xv.y, dw[(c + 1) * 7 + tau], ay);
  }
  __shared__ float red[4], red2[4];
  float s = ax + ay;
#pragma unroll
  for (int m = 1; m < 64; m <<= 1) s += __shfl_xor(s, m, 64);
  if ((threadIdx.x & 63) == 0) red[threadIdx.x >> 6] = s;
  __syncthreads();
  float mean = (red[0] + red[1] + red[2] + red[3]) * (1.0f / CI);
  float dx = ax - mean, dy = ay - mean;
  float s2 = dx * dx + dy * dy;
#pragma unroll
  for (int m = 1; m < 64; m <<= 1) s2 += __shfl_xor(s2, m, 64);
  if ((threadIdx.x & 63) == 0) red2[threadIdx.x >> 6] = s2;
  __syncthreads();
  float var = (red2[0] + red2[1] + red2[2] + red2[3]) * (1.0f / CI);
  float rs = rsqrtf(var + 1e-5f);
  float vx = dx * rs * g[c] + bt[c];
  float vy = dy * rs * g[c + 1] + bt[c + 1];
  PH[(size_t)row * 256 + threadIdx.x] = pack2(vx, vy, false);
  PL[(size_t)row * 256 + threadIdx.x] = pack2(vx, vy, true);
}

// ---------------- amps head ----------------
__global__ __launch_bounds__(256) void amps2_kernel(const float* __restrict__ x, const float* __restrict__ w,
                                                    const float* __restrict__ bias, float* __restrict__ amps) {
  int row = blockIdx.x * 4 + (threadIdx.x >> 6);
  int lane = threadIdx.x & 63;
  const float* xr = x + (size_t)row * CI;
  int c0 = lane * 8;
  float4 v0 = *(const float4*)&xr[c0], v1 = *(const float4*)&xr[c0 + 4];
  float4 w0 = *(const float4*)&w[c0], w1 = *(const float4*)&w[c0 + 4];
  float s = v0.x * w0.x + v0.y * w0.y + v0.z * w0.z + v0.w * w0.w
          + v1.x * w1.x + v1.y * w1.y + v1.z * w1.z + v1.w * w1.w;
#pragma unroll
  for (int m = 1; m < 64; m <<= 1) s += __shfl_xor(s, m, 64);
  if (lane == 0) {
    float a = s + bias[0];
    amps[row] = (a > 0.f ? a : expm1f(a)) + 1.0f;
  }
}

// ---------------- im2col packed (edge pad 3) ----------------
__global__ void im2col_pk(const float* __restrict__ x, uint32_t* __restrict__ PH, uint32_t* __restrict__ PL) {
  int idx = blockIdx.x * 256 + threadIdx.x;
  if (idx >= MTOT * 1792) return;
  int row = idx / 1792, kp = idx % 1792;
  int b = row / LF, l = row % LF;
  float v2[2];
#pragma unroll
  for (int u = 0; u < 2; ++u) {
    int kap = kp * 2 + u;
    int ch = kap / 7, tau = kap % 7;
    int j = l + tau - 3;
    j = j < 0 ? 0 : (j > LF - 1 ? LF - 1 : j);
    v2[u] = x[((size_t)b * LF + j) * CI + ch];
  }
  PH[idx] = pack2(v2[0], v2[1], false);
  PL[idx] = pack2(v2[0], v2[1], true);
}

// ---------------- noise*window packed A (1664 x 3840, rows>=1600 zero) ----------------
__global__ void pack_noise(uint32_t* __restrict__ AH, uint32_t* __restrict__ AL) {
  int idx = blockIdx.x * 256 + threadIdx.x;
  if (idx >= MPAD * 1920) return;
  int t = idx / 1920, jp = idx % 1920;
  float v0 = 0.f, v1 = 0.f;
  if (t < MTOT) {
    int b = t / LF, tt = t % LF;
    int j = jp * 2;
    v0 = noiseval(b, tt * 960 + j - 960) * winf(j);
    v1 = noiseval(b, tt * 960 + j - 959) * winf(j + 1);
  }
  AH[idx] = pack2(v0, v1, false);
  AL[idx] = pack2(v0, v1, true);
}

// ---------------- twiddle tables hi/lo T[k2][j] (3968 x 3840) for fwd ----------------
__global__ void twfill_pk(uint32_t* __restrict__ TH, uint32_t* __restrict__ TL) {
  int idx = blockIdx.x * 256 + threadIdx.x;
  if (idx >= SWID * 1920) return;
  int k2 = idx / 1920, jp = idx % 1920;
  float v2[2] = {0.f, 0.f};
  if (k2 < NK2) {
    int k = k2 >> 1;
#pragma unroll
    for (int u = 0; u < 2; ++u) {
      int j = jp * 2 + u;
      int m = (j * k) % NFFT;
      float ang = (float)m * (6.283185307179586f / 3840.0f);
      v2[u] = (k2 & 1) ? -sinf(ang) : cosf(ang);
    }
  }
  TH[idx] = pack2(v2[0], v2[1], false);
  TL[idx] = pack2(v2[0], v2[1], true);
}

// ---------------- harmonic path ----------------
__global__ void fs_kernel(const float* __restrict__ f0, float* __restrict__ fs) {
  int idx = blockIdx.x * 256 + threadIdx.x;
  if (idx >= NB * LW) return;
  int b = idx / LW, n = idx % LW;
  float pos = ((float)n + 0.5f) * (200.0f / 192000.0f) - 0.5f;
  pos = fminf(fmaxf(pos, 0.0f), 199.0f);
  int i0 = (int)pos;
  int i1 = min(i0 + 1, 199);
  float w = pos - (float)i0;
  fs[idx] = f0[b * LF + i0] * (1.0f - w) + f0[b * LF + i1] * w;
}

__global__ __launch_bounds__(256) void cumsum1(const float* __restrict__ fs, double* __restrict__ csum) {
  int b = blockIdx.y, ch = blockIdx.x;
  const float* fsb = fs + (size_t)b * LW;
  int base = ch * 1024;
  double s = 0.0;
  for (int q = 0; q < 4; ++q) {
    int n = base + threadIdx.x * 4 + q;
    if (n < LW) s += (double)((3.14159274101257324f * fsb[n]) / 48000.0f);
  }
  __shared__ double sh[256];
  sh[threadIdx.x] = s;
  __syncthreads();
  for (int o2 = 128; o2 > 0; o2 >>= 1) {
    if (threadIdx.x < o2) sh[threadIdx.x] += sh[threadIdx.x + o2];
    __syncthreads();
  }
  if (threadIdx.x == 0) csum[b * NCH + ch] = sh[0];
}

__global__ void cumsum2(double* __restrict__ csum) {
  int b = blockIdx.x;
  if (threadIdx.x == 0) {
    double acc = 0.0;
    for (int ch = 0; ch < NCH; ++ch) {
      double v = csum[b * NCH + ch];
      csum[b * NCH + ch] = acc;
      acc += v;
    }
  }
}

__global__ __launch_bounds__(256) void harm_kernel(
    const float* __restrict__ fs, const double* __restrict__ csum,
    const float* __restrict__ f0, const float* __restrict__ amps,
    float* __restrict__ harm) {
  int b = blockIdx.y, ch = blockIdx.x;
  const float* fsb = fs + (size_t)b * LW;
  int base = ch * 1024;
  int tid = threadIdx.x;
  double p[4]; double s = 0.0;
  int n0 = base + tid * 4;
  for (int q = 0; q < 4; ++q) {
    int n = n0 + q; float sm = 0.f;
    if (n < LW) sm = (3.14159274101257324f * fsb[n]) / 48000.0f;
    s += (double)sm; p[q] = s;
  }
  __shared__ double sh[256];
  sh[tid] = s; __syncthreads();
  for (int o2 = 1; o2 < 256; o2 <<= 1) {
    double v = (tid >= o2) ? sh[tid - o2] : 0.0;
    __syncthreads();
    sh[tid] += v;
    __syncthreads();
  }
  double excl = csum[b * NCH + ch] + (tid > 0 ? sh[tid - 1] : 0.0);
  const double PID = (double)3.14159274101257324f;
  for (int q = 0; q < 4; ++q) {
    int n = n0 + q; if (n >= LW) break;
    double S = excl + p[q];
    float pixf = (float)fmod(S, PID);
    float fsv = fsb[n];
    float a = rintf(48000.0f / fmaxf(fsv, 20.0f) * 0.5f) * 2.0f + 1.0f;
    float D = (pixf < 1e-8f) ? 1.0f : (sinf(a * pixf) / (a * sinf(pixf)));
    int ui = n / 960;
    float uv = (f0[b * LF + ui] > 20.0f) ? 1.0f : 0.0f;
    float posA = ((float)n + 0.5f) * (200.0f / 192000.0f) - 0.5f;
    posA = fminf(fmaxf(posA, 0.0f), 199.0f);
    int i0 = (int)posA;
    int i1 = min(i0 + 1, 199);
    float w = posA - (float)i0;
    float ampI = amps[b * LF + i0] * (1.0f - w) + amps[b * LF + i1] * w;
    harm[(size_t)b * LW + n] = (D * uv) * ampI;
  }
}

// ---------------- OLA + wn normalize + add to harm ----------------
__global__ void ola_kernel(const float* __restrict__ ft, float* __restrict__ dsp) {
  int idx = blockIdx.x * 256 + threadIdx.x;
  if (idx >= NB * LW) return;
  int b = idx / LW, n = idx % LW;
  int p = n + 1920;
  int t0 = (p > 3839) ? ((p - 2880) / 960) : 0;
  int t1 = p / FRAME; if (t1 > 200) t1 = 200;
  float y = 0.f, wn = 0.f;
  for (int t = t0; t <= t1; ++t) {
    int j = p - FRAME * t;
    float w = winf(j);
    wn += w * w;
    if (t >= 1) y += ft[((size_t)b * LF + (t - 1)) * NFFT + j];
  }
  float den = wn > 1e-11f ? wn : 1.0f;
  dsp[idx] = dsp[idx] + y / den;
}

// ---------------- per-frame FIR: sliding-window, 8 consecutive outputs/thread ----------------
__global__ __launch_bounds__(256) void fir3_kernel(const float* __restrict__ dsp,
                                                   const float* __restrict__ filt,
                                                   float* __restrict__ outf) {
  int t = blockIdx.x, b = blockIdx.y;
  __shared__ float frp[3456];
  __shared__ float fl[NWIN];
  int tid = threadIdx.x;
  for (int i = tid; i < 3456; i += 256) frp[i] = 0.f;
  __syncthreads();
  for (int i = tid; i < FRAME; i += 256) {
    int x = 1024 + i;
    frp[x + (x >> 3)] = dsp[(size_t)b * LW + (size_t)t * FRAME + i];
  }
  for (int i = tid; i < NWIN; i += 256) fl[i] = filt[((size_t)b * LF + t) * NWIN + i];
  __syncthreads();
  float a[8] = {0.f, 0.f, 0.f, 0.f, 0.f, 0.f, 0.f, 0.f};
  float wbuf[8];
  int base = 9 * tid;
#pragma unroll
  for (int r = 0; r < 8; ++r) wbuf[r] = frp[base + r];
  int nbase = base + 9;
  for (int tau8 = 0; tau8 < 128; ++tau8) {
    int nb = nbase + tau8 * 9;
#pragma unroll
    for (int r = 0; r < 8; ++r) {
      float fv = fl[tau8 * 8 + r];
#pragma unroll
      for (int q = 0; q < 8; ++q)
        a[q] = fmaf(wbuf[(r + q) & 7], fv, a[q]);
      wbuf[r] = frp[nb + r];
    }
  }
#pragma unroll
  for (int q = 0; q < 8; ++q) {
    int i = tid * 8 + q;
    if (i < 1984) outf[((size_t)b * LF + t) * 1984 + i] = a[q];
  }
}

// ---------------- fold ----------------
__global__ void fold_kernel(const float* __restrict__ outf, float* __restrict__ out) {
  int idx = blockIdx.x * 256 + threadIdx.x;
  if (idx >= NB * LW) return;
  int b = idx / LW, n = idx % LW;
  int t0 = (n >= 1984) ? ((n - 1024) / 960) : 0;
  int t1 = n / 960; if (t1 > 199) t1 = 199;
  float acc = 0.f;
  for (int t = t0; t <= t1; ++t)
    acc += outf[((size_t)b * LF + t) * 1984 + (n - 960 * t)];
  out[idx] = acc;
}

extern "C" void kernel_launch(void* const* d_in, const int* in_sizes, int n_in,
                              void* d_out, int out_size, void* d_ws, size_t ws_size,
                              hipStream_t stream) {
  const float* content    = (const float*)d_in[0];
  const float* f0         = (const float*)d_in[1];
  const float* energy     = (const float*)d_in[2];
  const float* spk        = (const float*)d_in[3];
  const float* s_in_w     = (const float*)d_in[4];
  const float* s_in_b     = (const float*)d_in[5];
  const float* s_dw_w     = (const float*)d_in[6];
  const float* s_dw_b     = (const float*)d_in[7];
  const float* s_ln       = (const float*)d_in[8];
  const float* s_pw1_w    = (const float*)d_in[9];
  const float* s_pw1_b    = (const float*)d_in[10];
  const float* s_pw2_w    = (const float*)d_in[11];
  const float* s_pw2_b    = (const float*)d_in[12];
  const float* s_out_norm = (const float*)d_in[13];
  const float* f_in_w     = (const float*)d_in[14];
  const float* f_in_b     = (const float*)d_in[15];
  const float* f_dw_w     = (const float*)d_in[16];
  const float* f_dw_b     = (const float*)d_in[17];
  const float* f_ln       = (const float*)d_in[18];
  const float* f_pw1_w    = (const float*)d_in[19];
  const float* f_pw1_b    = (const float*)d_in[20];
  const float* f_pw2_w    = (const float*)d_in[21];
  const float* f_pw2_b    = (const float*)d_in[22];
  const float* f_out_norm = (const float*)d_in[23];
  const float* s_in_norm  = (const float*)d_in[24];
  const float* s_amp_w    = (const float*)d_in[25];
  const float* s_amp_b    = (const float*)d_in[26];
  const float* s_ker_w    = (const float*)d_in[27];
  const float* s_ker_b    = (const float*)d_in[28];
  const float* f_out_w    = (const float*)d_in[29];
  const float* f_out_b    = (const float*)d_in[30];

  // ---- workspace layout (175.61 MB; proven ws >= 177.57 MB) ----
  char* W0 = (char*)d_ws;
  double*   CSUM  = (double*)W0;                         // 12,032
  uint32_t* XINPH = (uint32_t*)(W0 + 12032);             // 3,072,000
  uint32_t* XINPL = (uint32_t*)(W0 + 3084032);           // 3,072,000
  float*    XS    = (float*)   (W0 + 6156032);           // 6,553,600 (3200 x 512)
  uint32_t* TPH   = (uint32_t*)(W0 + 12709632);          // 3,276,800 (3200 x 256)
  uint32_t* TPL   = (uint32_t*)(W0 + 15986432);          // 3,276,800
  uint16_t* KERH  = (uint16_t*)(W0 + 19263232);          // 6,147,200
  float*    AMPS  = (float*)   (W0 + 25410432);          // 8,192
  float*    FILT  = (float*)   (W0 + 25418624);          // 6,553,600
  float*    HARM  = (float*)   (W0 + 31972224);          // 6,144,000
  char*     R2    = W0 + 38116224;                       // 26,411,008
  char*     FTR   = W0 + 64527232;                       // 24,576,000
  char*     U     = W0 + 89103232;                       // 25,559,040
  uint32_t* TH32  = (uint32_t*)(W0 + 114662272);         // 30,474,240  (T for fwd, then V for inv)
  uint32_t* TL32  = (uint32_t*)(W0 + 145136512);         // 30,474,240 -> ends 175,610,752
  // overlays
  uint32_t* XSPH = TPH;                                  // (after trunk, TP dead)
  uint32_t* XSPL = (uint32_t*)((char*)TPH + 1638400);
  uint32_t* H15PH = (uint32_t*)R2;                       // 9,830,400 (3200 x 768)
  uint32_t* H15PL = (uint32_t*)(R2 + 9830400);
  uint32_t* IMPH = (uint32_t*)R2;                        // 11,468,800 (after H15 dead)
  uint32_t* IMPL = (uint32_t*)(R2 + 11468800);
  uint16_t* SH   = (uint16_t*)R2;                        // 13,205,504 (1664 x 3968, after IMP dead)
  uint16_t* SL   = (uint16_t*)(R2 + 13205504);
  float*    OUTF = (float*)R2;                           // 12,697,600 (after SH/SL dead)
  float*    FS   = (float*)FTR;                          // 6,144,000
  float*    FT   = (float*)FTR;                          // 24,576,000 (after FS dead)
  uint32_t* WPH  = (uint32_t*)U;                         // 7,340,032
  uint32_t* WPL  = (uint32_t*)(U + 7340032);
  uint16_t* AH   = (uint16_t*)U;                         // 12,779,520 (after WP dead)
  uint16_t* AL   = (uint16_t*)(U + 12779520);

  (void)in_sizes; (void)n_in; (void)out_size; (void)ws_size;

  build_xin_pk<<<dim3((MB2 * 240 + 255) / 256), 256, 0, stream>>>(content, f0, energy, spk, XINPH, XINPL);

  auto pw1set = [&](const float* Wm, int M, int K, int Mp, int Kp) {
    int total = Mp * (Kp / 2);
    pack_w<<<dim3((total + 255) / 256), 256, 0, stream>>>(Wm, WPH, WPL, M, K, Kp / 2, total);
  };
  auto pw2sets = [&](const float* Ws, const float* Wf, int M, int K, int Mp, int Kp) {
    int total = Mp * (Kp / 2);
    pack_w<<<dim3((total + 255) / 256), 256, 0, stream>>>(Ws, WPH, WPL, M, K, Kp / 2, total);
    pack_w<<<dim3((total + 255) / 256), 256, 0, stream>>>(Wf, WPH + total, WPL + total, M, K, Kp / 2, total);
  };

  // ---- batched dual-trunk ----
  pw2sets(s_in_w, f_in_w, CI, CIN, CI, 480);
  gemm_pk<<<dim3(8 * 50), 256, 0, stream>>>((uint16_t*)WPH, (uint16_t*)WPL, (uint16_t*)XINPH, (uint16_t*)XINPL,
      s_in_b, f_in_b, nullptr, XS, nullptr, nullptr, CI, 480, 8, 50, 0, 0, 25, (size_t)512 * 480);
  ln2_kernel<<<dim3(MTOT / 4), 256, 0, stream>>>(XS, s_in_norm, s_in_norm + CI, nullptr, nullptr);
  for (int i = 0; i < NL; ++i) {
    dwln_kernel<<<dim3(MB2), 256, 0, stream>>>(XS,
        s_dw_w + (size_t)i * CI * 7, s_dw_b + (size_t)i * CI,
        s_ln + (size_t)(i * 2) * CI, s_ln + (size_t)(i * 2 + 1) * CI,
        f_dw_w + (size_t)i * CI * 7, f_dw_b + (size_t)i * CI,
        f_ln + (size_t)(i * 2) * CI, f_ln + (size_t)(i * 2 + 1) * CI,
        TPH, TPL);
    pw2sets(s_pw1_w + (size_t)i * HID * CI, f_pw1_w + (size_t)i * HID * CI, HID, CI, HID, 512);
    gemm_pk<<<dim3(24 * 50), 256, 0, stream>>>((uint16_t*)WPH, (uint16_t*)WPL, (uint16_t*)TPH, (uint16_t*)TPL,
        s_pw1_b + (size_t)i * HID, f_pw1_b + (size_t)i * HID, nullptr,
        nullptr, (uint16_t*)H15PH, (uint16_t*)H15PL, HID, 512, 24, 50, 1, 1, 25, (size_t)1536 * 512);
    pw2sets(s_pw2_w + (size_t)i * CI * HID, f_pw2_w + (size_t)i * CI * HID, CI, HID, CI, 1536);
    gemm_pk<<<dim3(8 * 50), 256, 0, stream>>>((uint16_t*)WPH, (uint16_t*)WPL, (uint16_t*)H15PH, (uint16_t*)H15PL,
        s_pw2_b + (size_t)i * CI, f_pw2_b + (size_t)i * CI, XS,
        XS, nullptr, nullptr, CI, 1536, 8, 50, 0, 0, 25, (size_t)512 * 1536);
  }

  // ---- heads ----
  ln2_kernel<<<dim3(MTOT / 4), 256, 0, stream>>>(XS, s_out_norm, s_out_norm + CI, XSPH, XSPL);
  amps2_kernel<<<dim3(MTOT / 4), 256, 0, stream>>>(XS, s_amp_w, s_amp_b, AMPS);
  pw1set(s_ker_w, NFREQ, CI, 1984, 512);
  gemm_pk<<<dim3(31 * 25), 256, 0, stream>>>((uint16_t*)WPH, (uint16_t*)WPL, (uint16_t*)XSPH, (uint16_t*)XSPL,
      s_ker_b, nullptr, nullptr, nullptr, KERH, nullptr, NFREQ, 512, 31, 25, 2, 2, 1000, 0);

  ln2_kernel<<<dim3(MTOT / 4), 256, 0, stream>>>(XS + (size_t)MTOT * CI, f_out_norm, f_out_norm + CI, nullptr, nullptr);
  im2col_pk<<<dim3((MTOT * 1792 + 255) / 256), 256, 0, stream>>>(XS + (size_t)MTOT * CI, IMPH, IMPL);
  pw1set(f_out_w, NWIN, 3584, NWIN, 3584);
  gemm_pk<<<dim3(16 * 25), 256, 0, stream>>>((uint16_t*)WPH, (uint16_t*)WPL, (uint16_t*)IMPH, (uint16_t*)IMPL,
      f_out_b, nullptr, nullptr, FILT, nullptr, nullptr, NWIN, 3584, 16, 25, 0, 0, 1000, 0);

  // ---- harmonic source (FS lives in FT region, dead before inv) ----
  fs_kernel<<<dim3((NB * LW + 255) / 256), 256, 0, stream>>>(f0, FS);
  cumsum1<<<dim3(NCH, NB), 256, 0, stream>>>(FS, CSUM);
  cumsum2<<<dim3(NB), 64, 0, stream>>>(CSUM);
  harm_kernel<<<dim3(NCH, NB), 256, 0, stream>>>(FS, CSUM, f0, AMPS, HARM);

  // ---- filtered noise: fwd (T table) then inv (V table overwrites T) ----
  pack_noise<<<dim3((MPAD * 1920 + 255) / 256), 256, 0, stream>>>((uint32_t*)AH, (uint32_t*)AL);
  twfill_pk<<<dim3((SWID * 1920 + 255) / 256), 256, 0, stream>>>(TH32, TL32);
  gemm_fwd128<<<dim3(13 * 31), 256, 0, stream>>>(AH, AL, (uint16_t*)TH32, (uint16_t*)TL32, KERH, SH, SL);
  twfill_v<<<dim3((NFFT * (SWID / 2) + 255) / 256), 256, 0, stream>>>(TH32, TL32);
  gemm_invNT<<<dim3(30 * 13), 256, 0, stream>>>(SH, SL, (uint16_t*)TH32, (uint16_t*)TL32, FT);
  ola_kernel<<<dim3((NB * LW + 255) / 256), 256, 0, stream>>>(FT, HARM);

  // ---- FIR + fold ----
  fir3_kernel<<<dim3(LF, NB), 256, 0, stream>>>(HARM, FILT, OUTF);
  fold_kernel<<<dim3((NB * LW + 255) / 256), 256, 0, stream>>>(OUTF, (float*)d_out);
}